// Round 1
// baseline (2292.143 us; speedup 1.0000x reference)
//
#include <hip/hip_runtime.h>
#include <math.h>

#define S_LEN 2048
#define B_SZ 4
#define NH 16
#define HD 64
#define C_DIM 1024
#define OUT_DIM 1024

static constexpr size_t BHSD = (size_t)B_SZ * NH * S_LEN * HD; // 8,388,608 floats

// ---------------- Kernel 1: QKV projection GEMM ----------------
// X: (S*B, C) row-major, row m = s*B+b. W: (3*OUT, C) row-major. NT GEMM.
// Epilogue: add bias, scatter into q/k/v [b][h][s][d] (each BHSD floats in ws).
__global__ __launch_bounds__(256)
void qkv_gemm_kernel(const float* __restrict__ X, const float* __restrict__ W,
                     const float* __restrict__ bias, float* __restrict__ qkv_ws)
{
    constexpr int BM = 128, BN = 128, BK = 16, K = C_DIM;
    __shared__ float As[BK][BM + 4];
    __shared__ float Bs[BK][BN + 4];
    const int t  = threadIdx.x;
    const int tx = t & 15, ty = t >> 4;
    const int row0 = blockIdx.x * BM;
    const int col0 = blockIdx.y * BN;

    float acc[8][8];
#pragma unroll
    for (int i = 0; i < 8; ++i)
#pragma unroll
        for (int j = 0; j < 8; ++j) acc[i][j] = 0.f;

    for (int k0 = 0; k0 < K; k0 += BK) {
#pragma unroll
        for (int r = 0; r < 2; ++r) {
            int idx = t + 256 * r;
            int kq = idx & 3, rr = idx >> 2;
            float4 a4 = *reinterpret_cast<const float4*>(X + (size_t)(row0 + rr) * K + k0 + kq * 4);
            As[kq*4+0][rr] = a4.x; As[kq*4+1][rr] = a4.y; As[kq*4+2][rr] = a4.z; As[kq*4+3][rr] = a4.w;
            float4 b4 = *reinterpret_cast<const float4*>(W + (size_t)(col0 + rr) * K + k0 + kq * 4);
            Bs[kq*4+0][rr] = b4.x; Bs[kq*4+1][rr] = b4.y; Bs[kq*4+2][rr] = b4.z; Bs[kq*4+3][rr] = b4.w;
        }
        __syncthreads();
#pragma unroll
        for (int kk = 0; kk < BK; ++kk) {
            float4 a0 = *reinterpret_cast<const float4*>(&As[kk][ty * 8]);
            float4 a1 = *reinterpret_cast<const float4*>(&As[kk][ty * 8 + 4]);
            float4 b0 = *reinterpret_cast<const float4*>(&Bs[kk][tx * 8]);
            float4 b1 = *reinterpret_cast<const float4*>(&Bs[kk][tx * 8 + 4]);
            float a[8] = {a0.x,a0.y,a0.z,a0.w,a1.x,a1.y,a1.z,a1.w};
            float b[8] = {b0.x,b0.y,b0.z,b0.w,b1.x,b1.y,b1.z,b1.w};
#pragma unroll
            for (int i = 0; i < 8; ++i)
#pragma unroll
                for (int j = 0; j < 8; ++j)
                    acc[i][j] = fmaf(a[i], b[j], acc[i][j]);
        }
        __syncthreads();
    }

    const int nbase = col0 + tx * 8;           // [0, 3072), multiple of 8 -> never crosses 64/1024 boundary
    const float4 bb0 = *reinterpret_cast<const float4*>(bias + nbase);
    const float4 bb1 = *reinterpret_cast<const float4*>(bias + nbase + 4);
    const int tsel = nbase >> 10;
    const int hh = (nbase & 1023) >> 6;
    const int dd = nbase & 63;
#pragma unroll
    for (int i = 0; i < 8; ++i) {
        int m = row0 + ty * 8 + i;
        int s = m >> 2, b = m & 3;
        float* dst = qkv_ws + (size_t)tsel * BHSD + (((size_t)(b * NH + hh) * S_LEN + s) * HD + dd);
        *reinterpret_cast<float4*>(dst)     = make_float4(acc[i][0]+bb0.x, acc[i][1]+bb0.y, acc[i][2]+bb0.z, acc[i][3]+bb0.w);
        *reinterpret_cast<float4*>(dst + 4) = make_float4(acc[i][4]+bb1.x, acc[i][5]+bb1.y, acc[i][6]+bb1.z, acc[i][7]+bb1.w);
    }
}

// ---------------- Kernel 2: flash attention (f32) ----------------
// One block = one (b,h) and a 64-row query tile. 256 threads, 4x4 per thread.
__global__ __launch_bounds__(256)
void attn_kernel(const float* __restrict__ ws_q, const float* __restrict__ ws_k,
                 const float* __restrict__ ws_v, float* __restrict__ av)
{
    __shared__ float QsT[HD][68];   // QsT[d][row], pre-scaled by 1/8
    __shared__ float KsT[HD][68];   // KsT[d][col]
    __shared__ float Vs[64][68];    // Vs[kv][d]
    __shared__ float PsT[64][68];   // PsT[kv][row]

    const int t  = threadIdx.x;
    const int tx = t & 15, ty = t >> 4;
    const int qt = blockIdx.x;           // query tile 0..31
    const int bh = blockIdx.y;           // 0..63
    const int b = bh >> 4, h = bh & 15;

    const float* Qg = ws_q + (size_t)bh * (S_LEN * HD) + (size_t)qt * 64 * HD;
    const float* Kg = ws_k + (size_t)bh * (S_LEN * HD);
    const float* Vg = ws_v + (size_t)bh * (S_LEN * HD);

    // load Q tile transposed, pre-scaled by 1/sqrt(D)=1/8
#pragma unroll
    for (int i = 0; i < 4; ++i) {
        int idx = t + 256 * i;           // 0..1023
        int r = idx >> 4, d4 = idx & 15;
        float4 v4 = *reinterpret_cast<const float4*>(Qg + (size_t)r * HD + d4 * 4);
        QsT[d4*4+0][r] = v4.x * 0.125f; QsT[d4*4+1][r] = v4.y * 0.125f;
        QsT[d4*4+2][r] = v4.z * 0.125f; QsT[d4*4+3][r] = v4.w * 0.125f;
    }

    float m_run[4], l_run[4], O[4][4];
#pragma unroll
    for (int i = 0; i < 4; ++i) {
        m_run[i] = -1e30f; l_run[i] = 0.f;
#pragma unroll
        for (int j = 0; j < 4; ++j) O[i][j] = 0.f;
    }

    for (int kt = 0; kt < S_LEN / 64; ++kt) {
        __syncthreads();   // protect KsT/Vs (and PsT) against previous iteration readers
#pragma unroll
        for (int i = 0; i < 4; ++i) {
            int idx = t + 256 * i;
            int r = idx >> 4, d4 = idx & 15;
            float4 k4 = *reinterpret_cast<const float4*>(Kg + (size_t)(kt * 64 + r) * HD + d4 * 4);
            KsT[d4*4+0][r] = k4.x; KsT[d4*4+1][r] = k4.y; KsT[d4*4+2][r] = k4.z; KsT[d4*4+3][r] = k4.w;
            float4 v4 = *reinterpret_cast<const float4*>(Vg + (size_t)(kt * 64 + r) * HD + d4 * 4);
            *reinterpret_cast<float4*>(&Vs[r][d4 * 4]) = v4;
        }
        __syncthreads();

        // S = (Q/8) K^T : 4x4 per thread, rows ty*4+i, cols tx*4+j
        float sc[4][4];
#pragma unroll
        for (int i = 0; i < 4; ++i)
#pragma unroll
            for (int j = 0; j < 4; ++j) sc[i][j] = 0.f;
#pragma unroll
        for (int d = 0; d < HD; ++d) {
            float4 a4 = *reinterpret_cast<const float4*>(&QsT[d][ty * 4]);
            float4 b4 = *reinterpret_cast<const float4*>(&KsT[d][tx * 4]);
            float a[4] = {a4.x, a4.y, a4.z, a4.w};
            float bb[4] = {b4.x, b4.y, b4.z, b4.w};
#pragma unroll
            for (int i = 0; i < 4; ++i)
#pragma unroll
                for (int j = 0; j < 4; ++j)
                    sc[i][j] = fmaf(a[i], bb[j], sc[i][j]);
        }

        // online softmax update (row = 16 lanes sharing ty)
#pragma unroll
        for (int i = 0; i < 4; ++i) {
            float rm = fmaxf(fmaxf(sc[i][0], sc[i][1]), fmaxf(sc[i][2], sc[i][3]));
            rm = fmaxf(rm, __shfl_xor(rm, 1));
            rm = fmaxf(rm, __shfl_xor(rm, 2));
            rm = fmaxf(rm, __shfl_xor(rm, 4));
            rm = fmaxf(rm, __shfl_xor(rm, 8));
            float nm = fmaxf(m_run[i], rm);
            float alpha = __expf(m_run[i] - nm);
            m_run[i] = nm;
            float rs = 0.f;
#pragma unroll
            for (int j = 0; j < 4; ++j) {
                float p = __expf(sc[i][j] - nm);
                sc[i][j] = p;
                rs += p;
            }
            rs += __shfl_xor(rs, 1);
            rs += __shfl_xor(rs, 2);
            rs += __shfl_xor(rs, 4);
            rs += __shfl_xor(rs, 8);
            l_run[i] = l_run[i] * alpha + rs;
#pragma unroll
            for (int j = 0; j < 4; ++j) O[i][j] *= alpha;
        }

        // stage P transposed for the PV product
#pragma unroll
        for (int i = 0; i < 4; ++i)
#pragma unroll
            for (int j = 0; j < 4; ++j)
                PsT[tx * 4 + j][ty * 4 + i] = sc[i][j];
        __syncthreads();

        // O += P V : rows ty*4+i (q), cols tx*4+j (d)
#pragma unroll
        for (int kk = 0; kk < 64; ++kk) {
            float4 a4 = *reinterpret_cast<const float4*>(&PsT[kk][ty * 4]);
            float4 b4 = *reinterpret_cast<const float4*>(&Vs[kk][tx * 4]);
            float a[4] = {a4.x, a4.y, a4.z, a4.w};
            float bb[4] = {b4.x, b4.y, b4.z, b4.w};
#pragma unroll
            for (int i = 0; i < 4; ++i)
#pragma unroll
                for (int j = 0; j < 4; ++j)
                    O[i][j] = fmaf(a[i], bb[j], O[i][j]);
        }
    }

    // normalize and store: av[(b*S+s)*1024 + h*64 + d]
#pragma unroll
    for (int i = 0; i < 4; ++i) {
        float inv = 1.0f / l_run[i];
        int srow = qt * 64 + ty * 4 + i;
        float4 o = make_float4(O[i][0] * inv, O[i][1] * inv, O[i][2] * inv, O[i][3] * inv);
        *reinterpret_cast<float4*>(av + ((size_t)(b * S_LEN + srow)) * OUT_DIM + h * HD + tx * 4) = o;
    }
}

// ---------------- Kernel 3: output projection GEMM ----------------
// av: (8192, 1024) rows r = b*S+s (== the reference's reshape rows). out = av @ Wo^T + bo.
__global__ __launch_bounds__(256)
void out_gemm_kernel(const float* __restrict__ A, const float* __restrict__ W,
                     const float* __restrict__ bias, float* __restrict__ out)
{
    constexpr int BM = 128, BN = 128, BK = 16, K = OUT_DIM;
    __shared__ float As[BK][BM + 4];
    __shared__ float Bs[BK][BN + 4];
    const int t  = threadIdx.x;
    const int tx = t & 15, ty = t >> 4;
    const int row0 = blockIdx.x * BM;
    const int col0 = blockIdx.y * BN;

    float acc[8][8];
#pragma unroll
    for (int i = 0; i < 8; ++i)
#pragma unroll
        for (int j = 0; j < 8; ++j) acc[i][j] = 0.f;

    for (int k0 = 0; k0 < K; k0 += BK) {
#pragma unroll
        for (int r = 0; r < 2; ++r) {
            int idx = t + 256 * r;
            int kq = idx & 3, rr = idx >> 2;
            float4 a4 = *reinterpret_cast<const float4*>(A + (size_t)(row0 + rr) * K + k0 + kq * 4);
            As[kq*4+0][rr] = a4.x; As[kq*4+1][rr] = a4.y; As[kq*4+2][rr] = a4.z; As[kq*4+3][rr] = a4.w;
            float4 b4 = *reinterpret_cast<const float4*>(W + (size_t)(col0 + rr) * K + k0 + kq * 4);
            Bs[kq*4+0][rr] = b4.x; Bs[kq*4+1][rr] = b4.y; Bs[kq*4+2][rr] = b4.z; Bs[kq*4+3][rr] = b4.w;
        }
        __syncthreads();
#pragma unroll
        for (int kk = 0; kk < BK; ++kk) {
            float4 a0 = *reinterpret_cast<const float4*>(&As[kk][ty * 8]);
            float4 a1 = *reinterpret_cast<const float4*>(&As[kk][ty * 8 + 4]);
            float4 b0 = *reinterpret_cast<const float4*>(&Bs[kk][tx * 8]);
            float4 b1 = *reinterpret_cast<const float4*>(&Bs[kk][tx * 8 + 4]);
            float a[8] = {a0.x,a0.y,a0.z,a0.w,a1.x,a1.y,a1.z,a1.w};
            float b[8] = {b0.x,b0.y,b0.z,b0.w,b1.x,b1.y,b1.z,b1.w};
#pragma unroll
            for (int i = 0; i < 8; ++i)
#pragma unroll
                for (int j = 0; j < 8; ++j)
                    acc[i][j] = fmaf(a[i], b[j], acc[i][j]);
        }
        __syncthreads();
    }

    const int nbase = col0 + tx * 8;
    const float4 bb0 = *reinterpret_cast<const float4*>(bias + nbase);
    const float4 bb1 = *reinterpret_cast<const float4*>(bias + nbase + 4);
#pragma unroll
    for (int i = 0; i < 8; ++i) {
        int m = row0 + ty * 8 + i;
        float* dst = out + (size_t)m * OUT_DIM + nbase;
        *reinterpret_cast<float4*>(dst)     = make_float4(acc[i][0]+bb0.x, acc[i][1]+bb0.y, acc[i][2]+bb0.z, acc[i][3]+bb0.w);
        *reinterpret_cast<float4*>(dst + 4) = make_float4(acc[i][4]+bb1.x, acc[i][5]+bb1.y, acc[i][6]+bb1.z, acc[i][7]+bb1.w);
    }
}

extern "C" void kernel_launch(void* const* d_in, const int* in_sizes, int n_in,
                              void* d_out, int out_size, void* d_ws, size_t ws_size,
                              hipStream_t stream)
{
    const float* x    = (const float*)d_in[0];   // (S,B,C)
    const float* Wqkv = (const float*)d_in[1];   // (3*OUT, C)
    const float* bqkv = (const float*)d_in[2];   // (3*OUT,)
    const float* Wo   = (const float*)d_in[3];   // (OUT, OUT)
    const float* bo   = (const float*)d_in[4];   // (OUT,)
    float* out = (float*)d_out;

    float* ws = (float*)d_ws;
    float* q  = ws;                  // [b][h][s][d]
    float* k  = ws + BHSD;
    float* v  = ws + 2 * BHSD;
    float* av = ws + 3 * BHSD;       // (B*S, H*D) rows r=b*S+s
    // needs 4*BHSD*4 = ~134 MB of workspace

    qkv_gemm_kernel<<<dim3(64, 24), 256, 0, stream>>>(x, Wqkv, bqkv, ws);
    attn_kernel<<<dim3(32, 64), 256, 0, stream>>>(q, k, v, av);
    out_gemm_kernel<<<dim3(64, 8), 256, 0, stream>>>(av, Wo, bo, out);
}

// Round 2
// 1180.826 us; speedup vs baseline: 1.9411x; 1.9411x over previous
//
#include <hip/hip_runtime.h>
#include <math.h>

#define S_LEN 2048
#define B_SZ 4
#define NH 16
#define HD 64
#define C_DIM 1024
#define OUT_DIM 1024

static constexpr size_t BHSD = (size_t)B_SZ * NH * S_LEN * HD; // 8,388,608

typedef __attribute__((ext_vector_type(8))) short v8bf;
typedef __attribute__((ext_vector_type(4))) float v4f;
typedef __attribute__((ext_vector_type(8))) unsigned short v8us;

__device__ inline unsigned short f2bf(float x) {
    unsigned u = __float_as_uint(x);
    return (unsigned short)((u + 0x7fffu + ((u >> 16) & 1u)) >> 16);  // RNE
}
__device__ inline float bf2f(unsigned short h) {
    return __uint_as_float(((unsigned)h) << 16);
}

// ---------------- Kernel 1: QKV projection GEMM (f32 math) ----------------
// X: (S*B, C) rows m = s*B+b. W: (3*OUT, C). Epilogue: bias, then
//   Q: *0.125, split hi/lo bf16 -> qhi/qlo [b][h][s][d]
//   K: split hi/lo bf16         -> khi/klo [b][h][s][d]
//   V: bf16                     -> vhi [b][h][d][s]  (TRANSPOSED for PV frags)
__global__ __launch_bounds__(256)
void qkv_gemm_kernel(const float* __restrict__ X, const float* __restrict__ W,
                     const float* __restrict__ bias,
                     unsigned short* __restrict__ qhi, unsigned short* __restrict__ qlo,
                     unsigned short* __restrict__ khi, unsigned short* __restrict__ klo,
                     unsigned short* __restrict__ vhi)
{
    constexpr int BM = 128, BN = 128, BK = 16, K = C_DIM;
    __shared__ float As[BK][BM + 4];
    __shared__ float Bs[BK][BN + 4];
    const int t  = threadIdx.x;
    const int tx = t & 15, ty = t >> 4;
    const int row0 = blockIdx.x * BM;
    const int col0 = blockIdx.y * BN;

    float acc[8][8];
#pragma unroll
    for (int i = 0; i < 8; ++i)
#pragma unroll
        for (int j = 0; j < 8; ++j) acc[i][j] = 0.f;

    for (int k0 = 0; k0 < K; k0 += BK) {
#pragma unroll
        for (int r = 0; r < 2; ++r) {
            int idx = t + 256 * r;
            int kq = idx & 3, rr = idx >> 2;
            float4 a4 = *reinterpret_cast<const float4*>(X + (size_t)(row0 + rr) * K + k0 + kq * 4);
            As[kq*4+0][rr] = a4.x; As[kq*4+1][rr] = a4.y; As[kq*4+2][rr] = a4.z; As[kq*4+3][rr] = a4.w;
            float4 b4 = *reinterpret_cast<const float4*>(W + (size_t)(col0 + rr) * K + k0 + kq * 4);
            Bs[kq*4+0][rr] = b4.x; Bs[kq*4+1][rr] = b4.y; Bs[kq*4+2][rr] = b4.z; Bs[kq*4+3][rr] = b4.w;
        }
        __syncthreads();
#pragma unroll
        for (int kk = 0; kk < BK; ++kk) {
            float4 a0 = *reinterpret_cast<const float4*>(&As[kk][ty * 8]);
            float4 a1 = *reinterpret_cast<const float4*>(&As[kk][ty * 8 + 4]);
            float4 b0 = *reinterpret_cast<const float4*>(&Bs[kk][tx * 8]);
            float4 b1 = *reinterpret_cast<const float4*>(&Bs[kk][tx * 8 + 4]);
            float a[8] = {a0.x,a0.y,a0.z,a0.w,a1.x,a1.y,a1.z,a1.w};
            float b[8] = {b0.x,b0.y,b0.z,b0.w,b1.x,b1.y,b1.z,b1.w};
#pragma unroll
            for (int i = 0; i < 8; ++i)
#pragma unroll
                for (int j = 0; j < 8; ++j)
                    acc[i][j] = fmaf(a[i], b[j], acc[i][j]);
        }
        __syncthreads();
    }

    const int nbase = col0 + tx * 8;   // [0,3072), multiple of 8
    const float4 bb0 = *reinterpret_cast<const float4*>(bias + nbase);
    const float4 bb1 = *reinterpret_cast<const float4*>(bias + nbase + 4);
    const float bv[8] = {bb0.x,bb0.y,bb0.z,bb0.w,bb1.x,bb1.y,bb1.z,bb1.w};
    const int tsel = nbase >> 10;
    const int hh = (nbase & 1023) >> 6;
    const int dd = nbase & 63;
#pragma unroll
    for (int i = 0; i < 8; ++i) {
        int m = row0 + ty * 8 + i;
        int s = m >> 2, b = m & 3;
        float vals[8];
#pragma unroll
        for (int j = 0; j < 8; ++j) vals[j] = acc[i][j] + bv[j];
        if (tsel == 0) {
            size_t base = ((size_t)(b * NH + hh) * S_LEN + s) * HD + dd;
            v8us h8, l8;
#pragma unroll
            for (int j = 0; j < 8; ++j) {
                float x = vals[j] * 0.125f;            // fold 1/sqrt(D)
                unsigned short hi = f2bf(x);
                h8[j] = hi;
                l8[j] = f2bf(x - bf2f(hi));
            }
            *reinterpret_cast<v8us*>(qhi + base) = h8;
            *reinterpret_cast<v8us*>(qlo + base) = l8;
        } else if (tsel == 1) {
            size_t base = ((size_t)(b * NH + hh) * S_LEN + s) * HD + dd;
            v8us h8, l8;
#pragma unroll
            for (int j = 0; j < 8; ++j) {
                unsigned short hi = f2bf(vals[j]);
                h8[j] = hi;
                l8[j] = f2bf(vals[j] - bf2f(hi));
            }
            *reinterpret_cast<v8us*>(khi + base) = h8;
            *reinterpret_cast<v8us*>(klo + base) = l8;
        } else {
            size_t base = ((size_t)(b * NH + hh) * HD + dd) * S_LEN + s;  // Vt[d][s]
#pragma unroll
            for (int j = 0; j < 8; ++j)
                vhi[base + (size_t)j * S_LEN] = f2bf(vals[j]);
        }
    }
}

// ---------------- Kernel 2: flash attention, bf16 MFMA ----------------
// Block = (q-tile of 128 rows) x (b,h). 4 waves; wave owns 32 q rows (2 m-tiles).
// KV block 64. Scores: split-bf16 (3 MFMA); PV: plain bf16.
// K/V staged fragment-major in LDS via global_load_lds (16B, pre-swizzled src).
__global__ __launch_bounds__(256, 3)
void attn_kernel(const unsigned short* __restrict__ qhi, const unsigned short* __restrict__ qlo,
                 const unsigned short* __restrict__ khi, const unsigned short* __restrict__ klo,
                 const unsigned short* __restrict__ vhi, float* __restrict__ av)
{
    __shared__ __align__(16) unsigned short KH[8 * 64 * 8];   // [nt*2+ks][lane][e] 8KB
    __shared__ __align__(16) unsigned short KL[8 * 64 * 8];
    __shared__ __align__(16) unsigned short VT[8 * 64 * 8];   // [ntd*2+ksv][lane][e]
    __shared__ __align__(16) unsigned short PL[4][32][72];    // per-wave P, stride 72

    const int t = threadIdx.x;
    const int lane = t & 63;
    const int w = t >> 6;
    const int lr = lane & 15;
    const int lg = lane >> 4;
    const int qt = blockIdx.x;       // 0..15
    const int bh = blockIdx.y;       // 0..63
    const int b = bh >> 4, h = bh & 15;
    const size_t bh_sd = (size_t)bh * (S_LEN * HD);
    const int q0 = qt * 128 + w * 32;

    // Q fragments (A-layout: row=lane&15, k=(lane>>4)*8+e), held in registers
    v8bf qh[2][2], ql[2][2];
#pragma unroll
    for (int mt = 0; mt < 2; ++mt)
#pragma unroll
        for (int ks = 0; ks < 2; ++ks) {
            size_t off = bh_sd + (size_t)(q0 + mt * 16 + lr) * HD + ks * 32 + lg * 8;
            qh[mt][ks] = *reinterpret_cast<const v8bf*>(qhi + off);
            ql[mt][ks] = *reinterpret_cast<const v8bf*>(qlo + off);
        }

    const v4f zero4 = {0.f, 0.f, 0.f, 0.f};
    v4f O[2][4];
    float m_run[2][4], l_run[2][4];
#pragma unroll
    for (int mt = 0; mt < 2; ++mt)
#pragma unroll
        for (int r = 0; r < 4; ++r) { m_run[mt][r] = -1e30f; l_run[mt][r] = 0.f; }
#pragma unroll
    for (int mt = 0; mt < 2; ++mt)
#pragma unroll
        for (int nt = 0; nt < 4; ++nt) O[mt][nt] = zero4;

    for (int kt = 0; kt < S_LEN / 64; ++kt) {
        __syncthreads();   // prev iter's LDS readers done
        // stage 24 x 1KB chunks (KH 8, KL 8, VT 8); 6 per wave, lane does 16B
#pragma unroll
        for (int u = 0; u < 6; ++u) {
            int id = w * 6 + u;
            int pl = id >> 3;
            int n = id & 7;
            int nt = n >> 1, kn = n & 1;
            const unsigned short* src;
            unsigned short* dst;
            if (pl == 0) {
                src = khi + bh_sd + (size_t)(kt * 64 + nt * 16 + lr) * HD + kn * 32 + lg * 8;
                dst = KH + n * 512;
            } else if (pl == 1) {
                src = klo + bh_sd + (size_t)(kt * 64 + nt * 16 + lr) * HD + kn * 32 + lg * 8;
                dst = KL + n * 512;
            } else {
                src = vhi + bh_sd + (size_t)(nt * 16 + lr) * S_LEN + kt * 64 + kn * 32 + lg * 8;
                dst = VT + n * 512;
            }
            __builtin_amdgcn_global_load_lds(
                (const __attribute__((address_space(1))) unsigned int*)src,
                (__attribute__((address_space(3))) unsigned int*)dst, 16, 0, 0);
        }
        __syncthreads();   // drains vmcnt -> tiles visible

        // ---- scores: S = Qs K^T, split-bf16 3-term ----
        v4f sc[2][4];
#pragma unroll
        for (int mt = 0; mt < 2; ++mt)
#pragma unroll
            for (int nt = 0; nt < 4; ++nt) sc[mt][nt] = zero4;
#pragma unroll
        for (int ks = 0; ks < 2; ++ks)
#pragma unroll
            for (int nt = 0; nt < 4; ++nt) {
                v8bf kh = *reinterpret_cast<const v8bf*>(KH + (nt * 2 + ks) * 512 + lane * 8);
                v8bf kl = *reinterpret_cast<const v8bf*>(KL + (nt * 2 + ks) * 512 + lane * 8);
#pragma unroll
                for (int mt = 0; mt < 2; ++mt) {
                    sc[mt][nt] = __builtin_amdgcn_mfma_f32_16x16x32_bf16(qh[mt][ks], kh, sc[mt][nt], 0, 0, 0);
                    sc[mt][nt] = __builtin_amdgcn_mfma_f32_16x16x32_bf16(ql[mt][ks], kh, sc[mt][nt], 0, 0, 0);
                    sc[mt][nt] = __builtin_amdgcn_mfma_f32_16x16x32_bf16(qh[mt][ks], kl, sc[mt][nt], 0, 0, 0);
                }
            }

        // ---- online softmax (row r lives in 16 lanes sharing lg) ----
#pragma unroll
        for (int mt = 0; mt < 2; ++mt)
#pragma unroll
            for (int r = 0; r < 4; ++r) {
                float rm = fmaxf(fmaxf(sc[mt][0][r], sc[mt][1][r]), fmaxf(sc[mt][2][r], sc[mt][3][r]));
                rm = fmaxf(rm, __shfl_xor(rm, 1));
                rm = fmaxf(rm, __shfl_xor(rm, 2));
                rm = fmaxf(rm, __shfl_xor(rm, 4));
                rm = fmaxf(rm, __shfl_xor(rm, 8));
                float nm = fmaxf(m_run[mt][r], rm);
                float alpha = __expf(m_run[mt][r] - nm);
                m_run[mt][r] = nm;
                float rs = 0.f;
#pragma unroll
                for (int nt = 0; nt < 4; ++nt) {
                    float p = __expf(sc[mt][nt][r] - nm);
                    rs += p;
                    PL[w][mt * 16 + lg * 4 + r][nt * 16 + lr] = f2bf(p);
                }
                rs += __shfl_xor(rs, 1);
                rs += __shfl_xor(rs, 2);
                rs += __shfl_xor(rs, 4);
                rs += __shfl_xor(rs, 8);
                l_run[mt][r] = l_run[mt][r] * alpha + rs;
#pragma unroll
                for (int nt = 0; nt < 4; ++nt) O[mt][nt][r] *= alpha;
            }
        __syncthreads();   // P writes -> frag reads ordering

        // ---- PV: O += P V ----
#pragma unroll
        for (int ks = 0; ks < 2; ++ks) {
            v8bf pa[2];
#pragma unroll
            for (int mt = 0; mt < 2; ++mt)
                pa[mt] = *reinterpret_cast<const v8bf*>(&PL[w][mt * 16 + lr][ks * 32 + lg * 8]);
#pragma unroll
            for (int nt = 0; nt < 4; ++nt) {
                v8bf vf = *reinterpret_cast<const v8bf*>(VT + (nt * 2 + ks) * 512 + lane * 8);
#pragma unroll
                for (int mt = 0; mt < 2; ++mt)
                    O[mt][nt] = __builtin_amdgcn_mfma_f32_16x16x32_bf16(pa[mt], vf, O[mt][nt], 0, 0, 0);
            }
        }
    }

    // epilogue: normalize, store av[(b*S+s)*1024 + h*64 + d] (f32)
#pragma unroll
    for (int mt = 0; mt < 2; ++mt)
#pragma unroll
        for (int r = 0; r < 4; ++r) {
            float inv = 1.f / l_run[mt][r];
            int s = q0 + mt * 16 + lg * 4 + r;
            float* dst = av + (size_t)(b * S_LEN + s) * OUT_DIM + h * HD;
#pragma unroll
            for (int nt = 0; nt < 4; ++nt)
                dst[nt * 16 + lr] = O[mt][nt][r] * inv;
        }
}

// ---------------- Kernel 3: output projection GEMM (f32) ----------------
__global__ __launch_bounds__(256)
void out_gemm_kernel(const float* __restrict__ A, const float* __restrict__ W,
                     const float* __restrict__ bias, float* __restrict__ out)
{
    constexpr int BM = 128, BN = 128, BK = 16, K = OUT_DIM;
    __shared__ float As[BK][BM + 4];
    __shared__ float Bs[BK][BN + 4];
    const int t  = threadIdx.x;
    const int tx = t & 15, ty = t >> 4;
    const int row0 = blockIdx.x * BM;
    const int col0 = blockIdx.y * BN;

    float acc[8][8];
#pragma unroll
    for (int i = 0; i < 8; ++i)
#pragma unroll
        for (int j = 0; j < 8; ++j) acc[i][j] = 0.f;

    for (int k0 = 0; k0 < K; k0 += BK) {
#pragma unroll
        for (int r = 0; r < 2; ++r) {
            int idx = t + 256 * r;
            int kq = idx & 3, rr = idx >> 2;
            float4 a4 = *reinterpret_cast<const float4*>(A + (size_t)(row0 + rr) * K + k0 + kq * 4);
            As[kq*4+0][rr] = a4.x; As[kq*4+1][rr] = a4.y; As[kq*4+2][rr] = a4.z; As[kq*4+3][rr] = a4.w;
            float4 b4 = *reinterpret_cast<const float4*>(W + (size_t)(col0 + rr) * K + k0 + kq * 4);
            Bs[kq*4+0][rr] = b4.x; Bs[kq*4+1][rr] = b4.y; Bs[kq*4+2][rr] = b4.z; Bs[kq*4+3][rr] = b4.w;
        }
        __syncthreads();
#pragma unroll
        for (int kk = 0; kk < BK; ++kk) {
            float4 a0 = *reinterpret_cast<const float4*>(&As[kk][ty * 8]);
            float4 a1 = *reinterpret_cast<const float4*>(&As[kk][ty * 8 + 4]);
            float4 b0 = *reinterpret_cast<const float4*>(&Bs[kk][tx * 8]);
            float4 b1 = *reinterpret_cast<const float4*>(&Bs[kk][tx * 8 + 4]);
            float a[8] = {a0.x,a0.y,a0.z,a0.w,a1.x,a1.y,a1.z,a1.w};
            float b[8] = {b0.x,b0.y,b0.z,b0.w,b1.x,b1.y,b1.z,b1.w};
#pragma unroll
            for (int i = 0; i < 8; ++i)
#pragma unroll
                for (int j = 0; j < 8; ++j)
                    acc[i][j] = fmaf(a[i], b[j], acc[i][j]);
        }
        __syncthreads();
    }

    const int nbase = col0 + tx * 8;
    const float4 bb0 = *reinterpret_cast<const float4*>(bias + nbase);
    const float4 bb1 = *reinterpret_cast<const float4*>(bias + nbase + 4);
#pragma unroll
    for (int i = 0; i < 8; ++i) {
        int m = row0 + ty * 8 + i;
        float* dst = out + (size_t)m * OUT_DIM + nbase;
        *reinterpret_cast<float4*>(dst)     = make_float4(acc[i][0]+bb0.x, acc[i][1]+bb0.y, acc[i][2]+bb0.z, acc[i][3]+bb0.w);
        *reinterpret_cast<float4*>(dst + 4) = make_float4(acc[i][4]+bb1.x, acc[i][5]+bb1.y, acc[i][6]+bb1.z, acc[i][7]+bb1.w);
    }
}

extern "C" void kernel_launch(void* const* d_in, const int* in_sizes, int n_in,
                              void* d_out, int out_size, void* d_ws, size_t ws_size,
                              hipStream_t stream)
{
    const float* x    = (const float*)d_in[0];
    const float* Wqkv = (const float*)d_in[1];
    const float* bqkv = (const float*)d_in[2];
    const float* Wo   = (const float*)d_in[3];
    const float* bo   = (const float*)d_in[4];
    float* out = (float*)d_out;

    unsigned short* qhi = (unsigned short*)d_ws;
    unsigned short* qlo = qhi + BHSD;
    unsigned short* khi = qlo + BHSD;
    unsigned short* klo = khi + BHSD;
    unsigned short* vhi = klo + BHSD;
    float* av = (float*)(vhi + BHSD);   // 8192 x 1024 f32
    // total ws: 5*BHSD*2 + 8192*1024*4 = ~117 MB

    qkv_gemm_kernel<<<dim3(64, 24), 256, 0, stream>>>(x, Wqkv, bqkv, qhi, qlo, khi, klo, vhi);
    attn_kernel<<<dim3(16, 64), 256, 0, stream>>>(qhi, qlo, khi, klo, vhi, av);
    out_gemm_kernel<<<dim3(64, 8), 256, 0, stream>>>(av, Wo, bo, out);
}

// Round 3
// 715.786 us; speedup vs baseline: 3.2023x; 1.6497x over previous
//
#include <hip/hip_runtime.h>
#include <math.h>

#define S_LEN 2048
#define B_SZ 4
#define NH 16
#define HD 64
#define C_DIM 1024
#define OUT_DIM 1024

static constexpr size_t BHSD = (size_t)B_SZ * NH * S_LEN * HD; // 8,388,608

typedef __attribute__((ext_vector_type(8))) short v8bf;
typedef __attribute__((ext_vector_type(4))) float v4f;
typedef __attribute__((ext_vector_type(8))) unsigned short v8us;
typedef __attribute__((ext_vector_type(4))) unsigned short v4us;

__device__ inline unsigned short f2bf(float x) {
    unsigned u = __float_as_uint(x);
    return (unsigned short)((u + 0x7fffu + ((u >> 16) & 1u)) >> 16);  // RNE
}
__device__ inline float bf2f(unsigned short h) {
    return __uint_as_float(((unsigned)h) << 16);
}

// ---------------- Kernel 0: f32 -> (hi,lo) bf16 split ----------------
__global__ __launch_bounds__(256)
void cvt_hl_kernel(const float* __restrict__ src, unsigned short* __restrict__ hi,
                   unsigned short* __restrict__ lo, int n4)
{
    int i = blockIdx.x * 256 + threadIdx.x;
    if (i >= n4) return;
    float4 v = reinterpret_cast<const float4*>(src)[i];
    float x[4] = {v.x, v.y, v.z, v.w};
    v4us h, l;
#pragma unroll
    for (int j = 0; j < 4; ++j) {
        unsigned short hh = f2bf(x[j]);
        h[j] = hh;
        l[j] = f2bf(x[j] - bf2f(hh));
    }
    reinterpret_cast<v4us*>(hi)[i] = h;
    reinterpret_cast<v4us*>(lo)[i] = l;
}

// ---------------- shared split-bf16 MFMA mainloop ----------------
// Computes C^T tile: A = weights rows n (an0..+128), B = activations rows m
// (bm0..+128), K=1024. acc[mt][nt] D-frag: row=n within tile (lg*4+reg),
// col=m within tile (lr). Fragment-major LDS subtiles, global_load_lds 16B.
__device__ __forceinline__ void splitbf16_mainloop(
    const unsigned short* __restrict__ Ahi, const unsigned short* __restrict__ Alo,
    const unsigned short* __restrict__ Bhi, const unsigned short* __restrict__ Blo,
    int an0, int bm0, unsigned short* SA, unsigned short* SB, v4f acc[4][4])
{
    constexpr int K = 1024;
    const int t = threadIdx.x;
    const int lane = t & 63;
    const int w = t >> 6;
    const int wn = w >> 1, wm = w & 1;
    const int lr = lane & 15, lg = lane >> 4;

    for (int k0 = 0; k0 < K; k0 += 32) {
        __syncthreads();   // all waves done reading previous tiles
#pragma unroll
        for (int u = 0; u < 8; ++u) {
            int id = w * 8 + u;          // 0..31
            int rt = id & 7;
            int sel = id >> 3;           // 0:Ahi 1:Alo 2:Bhi 3:Blo
            const unsigned short* src;
            unsigned short* dst;
            if (sel == 0)      { src = Ahi + (size_t)(an0 + rt * 16 + lr) * K + k0 + lg * 8; dst = SA + rt * 512; }
            else if (sel == 1) { src = Alo + (size_t)(an0 + rt * 16 + lr) * K + k0 + lg * 8; dst = SA + 4096 + rt * 512; }
            else if (sel == 2) { src = Bhi + (size_t)(bm0 + rt * 16 + lr) * K + k0 + lg * 8; dst = SB + rt * 512; }
            else               { src = Blo + (size_t)(bm0 + rt * 16 + lr) * K + k0 + lg * 8; dst = SB + 4096 + rt * 512; }
            __builtin_amdgcn_global_load_lds(
                (const __attribute__((address_space(1))) unsigned int*)src,
                (__attribute__((address_space(3))) unsigned int*)dst, 16, 0, 0);
        }
        __syncthreads();   // compiler drains vmcnt before barrier -> tiles visible

        v8bf ah[4], al[4], bh[4], bl[4];
#pragma unroll
        for (int i = 0; i < 4; ++i) {
            ah[i] = *reinterpret_cast<const v8bf*>(SA + (wn * 4 + i) * 512 + lane * 8);
            al[i] = *reinterpret_cast<const v8bf*>(SA + 4096 + (wn * 4 + i) * 512 + lane * 8);
            bh[i] = *reinterpret_cast<const v8bf*>(SB + (wm * 4 + i) * 512 + lane * 8);
            bl[i] = *reinterpret_cast<const v8bf*>(SB + 4096 + (wm * 4 + i) * 512 + lane * 8);
        }
#pragma unroll
        for (int mt = 0; mt < 4; ++mt)
#pragma unroll
            for (int nt = 0; nt < 4; ++nt) {
                acc[mt][nt] = __builtin_amdgcn_mfma_f32_16x16x32_bf16(ah[nt], bh[mt], acc[mt][nt], 0, 0, 0);
                acc[mt][nt] = __builtin_amdgcn_mfma_f32_16x16x32_bf16(al[nt], bh[mt], acc[mt][nt], 0, 0, 0);
                acc[mt][nt] = __builtin_amdgcn_mfma_f32_16x16x32_bf16(ah[nt], bl[mt], acc[mt][nt], 0, 0, 0);
            }
    }
}

// ---------------- Kernel 1: QKV projection (split-bf16 MFMA) ----------------
// n = output feature (0..3072), m = token row (s*B+b). Epilogue: bias, then
// Q:*0.125 hi/lo -> [b][h][s][d]; K: hi/lo -> [b][h][s][d]; V: bf16 -> [b][h][d][s].
__global__ __launch_bounds__(256)
void qkv_gemm_mfma(const unsigned short* __restrict__ Whi, const unsigned short* __restrict__ Wlo,
                   const unsigned short* __restrict__ Xhi, const unsigned short* __restrict__ Xlo,
                   const float* __restrict__ bias,
                   unsigned short* __restrict__ qhi, unsigned short* __restrict__ qlo,
                   unsigned short* __restrict__ khi, unsigned short* __restrict__ klo,
                   unsigned short* __restrict__ vhi)
{
    __shared__ __align__(16) unsigned short SA[2 * 8 * 512];   // 16 KB
    __shared__ __align__(16) unsigned short SB[2 * 8 * 512];
    const v4f zero4 = {0.f, 0.f, 0.f, 0.f};
    v4f acc[4][4];
#pragma unroll
    for (int i = 0; i < 4; ++i)
#pragma unroll
        for (int j = 0; j < 4; ++j) acc[i][j] = zero4;

    const int bm0 = blockIdx.x * 128;
    const int an0 = blockIdx.y * 128;
    splitbf16_mainloop(Whi, Wlo, Xhi, Xlo, an0, bm0, SA, SB, acc);

    const int t = threadIdx.x;
    const int lane = t & 63;
    const int w = t >> 6;
    const int wn = w >> 1, wm = w & 1;
    const int lr = lane & 15, lg = lane >> 4;
    const int nbase = an0 + wn * 64;
    const int mbase = bm0 + wm * 64;

#pragma unroll
    for (int nt = 0; nt < 4; ++nt) {
        const int n0 = nbase + nt * 16 + lg * 4;         // 4 consecutive features
        const float4 b4 = *reinterpret_cast<const float4*>(bias + n0);
        const float bv[4] = {b4.x, b4.y, b4.z, b4.w};
        const int tsel = n0 >> 10;
        const int np = n0 & 1023;
        const int hh = np >> 6;
        const int dd = np & 63;                           // multiple of 4
#pragma unroll
        for (int mt = 0; mt < 4; ++mt) {
            const int m = mbase + mt * 16 + lr;
            const int s = m >> 2, b = m & 3;
            float vals[4];
#pragma unroll
            for (int r = 0; r < 4; ++r) vals[r] = acc[mt][nt][r] + bv[r];
            if (tsel == 0) {
                v4us h, l;
#pragma unroll
                for (int r = 0; r < 4; ++r) {
                    float x = vals[r] * 0.125f;           // fold 1/sqrt(D)
                    unsigned short hi = f2bf(x);
                    h[r] = hi; l[r] = f2bf(x - bf2f(hi));
                }
                size_t base = ((size_t)(b * NH + hh) * S_LEN + s) * HD + dd;
                *reinterpret_cast<v4us*>(qhi + base) = h;
                *reinterpret_cast<v4us*>(qlo + base) = l;
            } else if (tsel == 1) {
                v4us h, l;
#pragma unroll
                for (int r = 0; r < 4; ++r) {
                    unsigned short hi = f2bf(vals[r]);
                    h[r] = hi; l[r] = f2bf(vals[r] - bf2f(hi));
                }
                size_t base = ((size_t)(b * NH + hh) * S_LEN + s) * HD + dd;
                *reinterpret_cast<v4us*>(khi + base) = h;
                *reinterpret_cast<v4us*>(klo + base) = l;
            } else {
#pragma unroll
                for (int r = 0; r < 4; ++r)
                    vhi[((size_t)(b * NH + hh) * HD + dd + r) * S_LEN + s] = f2bf(vals[r]);
            }
        }
    }
}

// ---------------- Kernel 2: flash attention, bf16 MFMA ----------------
__global__ __launch_bounds__(256, 3)
void attn_kernel(const unsigned short* __restrict__ qhi, const unsigned short* __restrict__ qlo,
                 const unsigned short* __restrict__ khi, const unsigned short* __restrict__ klo,
                 const unsigned short* __restrict__ vhi,
                 unsigned short* __restrict__ avhi, unsigned short* __restrict__ avlo)
{
    __shared__ __align__(16) unsigned short KH[8 * 64 * 8];
    __shared__ __align__(16) unsigned short KL[8 * 64 * 8];
    __shared__ __align__(16) unsigned short VT[8 * 64 * 8];
    __shared__ __align__(16) unsigned short PL[4][32][72];

    const int t = threadIdx.x;
    const int lane = t & 63;
    const int w = t >> 6;
    const int lr = lane & 15;
    const int lg = lane >> 4;
    const int qt = blockIdx.x;
    const int bh = blockIdx.y;
    const int b = bh >> 4, h = bh & 15;
    const size_t bh_sd = (size_t)bh * (S_LEN * HD);
    const int q0 = qt * 128 + w * 32;

    v8bf qh[2][2], ql[2][2];
#pragma unroll
    for (int mt = 0; mt < 2; ++mt)
#pragma unroll
        for (int ks = 0; ks < 2; ++ks) {
            size_t off = bh_sd + (size_t)(q0 + mt * 16 + lr) * HD + ks * 32 + lg * 8;
            qh[mt][ks] = *reinterpret_cast<const v8bf*>(qhi + off);
            ql[mt][ks] = *reinterpret_cast<const v8bf*>(qlo + off);
        }

    const v4f zero4 = {0.f, 0.f, 0.f, 0.f};
    v4f O[2][4];
    float m_run[2][4], l_run[2][4];
#pragma unroll
    for (int mt = 0; mt < 2; ++mt)
#pragma unroll
        for (int r = 0; r < 4; ++r) { m_run[mt][r] = -1e30f; l_run[mt][r] = 0.f; }
#pragma unroll
    for (int mt = 0; mt < 2; ++mt)
#pragma unroll
        for (int nt = 0; nt < 4; ++nt) O[mt][nt] = zero4;

    for (int kt = 0; kt < S_LEN / 64; ++kt) {
        __syncthreads();
#pragma unroll
        for (int u = 0; u < 6; ++u) {
            int id = w * 6 + u;
            int pl = id >> 3;
            int n = id & 7;
            int nt = n >> 1, kn = n & 1;
            const unsigned short* src;
            unsigned short* dst;
            if (pl == 0) {
                src = khi + bh_sd + (size_t)(kt * 64 + nt * 16 + lr) * HD + kn * 32 + lg * 8;
                dst = KH + n * 512;
            } else if (pl == 1) {
                src = klo + bh_sd + (size_t)(kt * 64 + nt * 16 + lr) * HD + kn * 32 + lg * 8;
                dst = KL + n * 512;
            } else {
                src = vhi + bh_sd + (size_t)(nt * 16 + lr) * S_LEN + kt * 64 + kn * 32 + lg * 8;
                dst = VT + n * 512;
            }
            __builtin_amdgcn_global_load_lds(
                (const __attribute__((address_space(1))) unsigned int*)src,
                (__attribute__((address_space(3))) unsigned int*)dst, 16, 0, 0);
        }
        __syncthreads();

        v4f sc[2][4];
#pragma unroll
        for (int mt = 0; mt < 2; ++mt)
#pragma unroll
            for (int nt = 0; nt < 4; ++nt) sc[mt][nt] = zero4;
#pragma unroll
        for (int ks = 0; ks < 2; ++ks)
#pragma unroll
            for (int nt = 0; nt < 4; ++nt) {
                v8bf kh = *reinterpret_cast<const v8bf*>(KH + (nt * 2 + ks) * 512 + lane * 8);
                v8bf kl = *reinterpret_cast<const v8bf*>(KL + (nt * 2 + ks) * 512 + lane * 8);
#pragma unroll
                for (int mt = 0; mt < 2; ++mt) {
                    sc[mt][nt] = __builtin_amdgcn_mfma_f32_16x16x32_bf16(qh[mt][ks], kh, sc[mt][nt], 0, 0, 0);
                    sc[mt][nt] = __builtin_amdgcn_mfma_f32_16x16x32_bf16(ql[mt][ks], kh, sc[mt][nt], 0, 0, 0);
                    sc[mt][nt] = __builtin_amdgcn_mfma_f32_16x16x32_bf16(qh[mt][ks], kl, sc[mt][nt], 0, 0, 0);
                }
            }

#pragma unroll
        for (int mt = 0; mt < 2; ++mt)
#pragma unroll
            for (int r = 0; r < 4; ++r) {
                float rm = fmaxf(fmaxf(sc[mt][0][r], sc[mt][1][r]), fmaxf(sc[mt][2][r], sc[mt][3][r]));
                rm = fmaxf(rm, __shfl_xor(rm, 1));
                rm = fmaxf(rm, __shfl_xor(rm, 2));
                rm = fmaxf(rm, __shfl_xor(rm, 4));
                rm = fmaxf(rm, __shfl_xor(rm, 8));
                float nm = fmaxf(m_run[mt][r], rm);
                float alpha = __expf(m_run[mt][r] - nm);
                m_run[mt][r] = nm;
                float rs = 0.f;
#pragma unroll
                for (int nt = 0; nt < 4; ++nt) {
                    float p = __expf(sc[mt][nt][r] - nm);
                    rs += p;
                    PL[w][mt * 16 + lg * 4 + r][nt * 16 + lr] = f2bf(p);
                }
                rs += __shfl_xor(rs, 1);
                rs += __shfl_xor(rs, 2);
                rs += __shfl_xor(rs, 4);
                rs += __shfl_xor(rs, 8);
                l_run[mt][r] = l_run[mt][r] * alpha + rs;
#pragma unroll
                for (int nt = 0; nt < 4; ++nt) O[mt][nt][r] *= alpha;
            }
        __syncthreads();

#pragma unroll
        for (int ks = 0; ks < 2; ++ks) {
            v8bf pa[2];
#pragma unroll
            for (int mt = 0; mt < 2; ++mt)
                pa[mt] = *reinterpret_cast<const v8bf*>(&PL[w][mt * 16 + lr][ks * 32 + lg * 8]);
#pragma unroll
            for (int nt = 0; nt < 4; ++nt) {
                v8bf vf = *reinterpret_cast<const v8bf*>(VT + (nt * 2 + ks) * 512 + lane * 8);
#pragma unroll
                for (int mt = 0; mt < 2; ++mt)
                    O[mt][nt] = __builtin_amdgcn_mfma_f32_16x16x32_bf16(pa[mt], vf, O[mt][nt], 0, 0, 0);
            }
        }
    }

    // epilogue: normalize, split hi/lo bf16 into av[(b*S+s)*1024 + h*64 + d]
#pragma unroll
    for (int mt = 0; mt < 2; ++mt)
#pragma unroll
        for (int r = 0; r < 4; ++r) {
            float inv = 1.f / l_run[mt][r];
            int s = q0 + mt * 16 + lg * 4 + r;
            size_t base = (size_t)(b * S_LEN + s) * OUT_DIM + h * HD;
#pragma unroll
            for (int nt = 0; nt < 4; ++nt) {
                float val = O[mt][nt][r] * inv;
                unsigned short hi = f2bf(val);
                avhi[base + nt * 16 + lr] = hi;
                avlo[base + nt * 16 + lr] = f2bf(val - bf2f(hi));
            }
        }
}

// ---------------- Kernel 3: output projection (split-bf16 MFMA) ----------------
__global__ __launch_bounds__(256)
void out_gemm_mfma(const unsigned short* __restrict__ Whi, const unsigned short* __restrict__ Wlo,
                   const unsigned short* __restrict__ Bhi, const unsigned short* __restrict__ Blo,
                   const float* __restrict__ bias, float* __restrict__ out)
{
    __shared__ __align__(16) unsigned short SA[2 * 8 * 512];
    __shared__ __align__(16) unsigned short SB[2 * 8 * 512];
    const v4f zero4 = {0.f, 0.f, 0.f, 0.f};
    v4f acc[4][4];
#pragma unroll
    for (int i = 0; i < 4; ++i)
#pragma unroll
        for (int j = 0; j < 4; ++j) acc[i][j] = zero4;

    const int bm0 = blockIdx.x * 128;
    const int an0 = blockIdx.y * 128;
    splitbf16_mainloop(Whi, Wlo, Bhi, Blo, an0, bm0, SA, SB, acc);

    const int t = threadIdx.x;
    const int lane = t & 63;
    const int w = t >> 6;
    const int wn = w >> 1, wm = w & 1;
    const int lr = lane & 15, lg = lane >> 4;
    const int nbase = an0 + wn * 64;
    const int mbase = bm0 + wm * 64;

#pragma unroll
    for (int nt = 0; nt < 4; ++nt) {
        const int n0 = nbase + nt * 16 + lg * 4;
        const float4 b4 = *reinterpret_cast<const float4*>(bias + n0);
#pragma unroll
        for (int mt = 0; mt < 4; ++mt) {
            const int m = mbase + mt * 16 + lr;
            float4 o = make_float4(acc[mt][nt][0] + b4.x, acc[mt][nt][1] + b4.y,
                                   acc[mt][nt][2] + b4.z, acc[mt][nt][3] + b4.w);
            *reinterpret_cast<float4*>(out + (size_t)m * OUT_DIM + n0) = o;
        }
    }
}

extern "C" void kernel_launch(void* const* d_in, const int* in_sizes, int n_in,
                              void* d_out, int out_size, void* d_ws, size_t ws_size,
                              hipStream_t stream)
{
    const float* x    = (const float*)d_in[0];   // (S,B,C) rows m=s*B+b
    const float* Wqkv = (const float*)d_in[1];   // (3*OUT, C)
    const float* bqkv = (const float*)d_in[2];
    const float* Wo   = (const float*)d_in[3];   // (OUT, OUT)
    const float* bo   = (const float*)d_in[4];
    float* out = (float*)d_out;

    unsigned short* p = (unsigned short*)d_ws;
    unsigned short* xhi = p;            p += BHSD;          // 8192x1024
    unsigned short* xlo = p;            p += BHSD;
    unsigned short* wqh = p;            p += 3 * OUT_DIM * C_DIM;
    unsigned short* wql = p;            p += 3 * OUT_DIM * C_DIM;
    unsigned short* woh = p;            p += OUT_DIM * OUT_DIM;
    unsigned short* wol = p;            p += OUT_DIM * OUT_DIM;
    unsigned short* qhi = p;            p += BHSD;
    unsigned short* qlo = p;            p += BHSD;
    unsigned short* khi = p;            p += BHSD;
    unsigned short* klo = p;            p += BHSD;
    unsigned short* vhi = p;            p += BHSD;
    unsigned short* avhi = xhi;         // x dead after qkv_gemm -> reuse
    unsigned short* avlo = xlo;
    // total: 134.2 MB

    cvt_hl_kernel<<<dim3((int)(BHSD / 4 / 256)), 256, 0, stream>>>(x, xhi, xlo, (int)(BHSD / 4));
    cvt_hl_kernel<<<dim3(3 * OUT_DIM * C_DIM / 4 / 256), 256, 0, stream>>>(Wqkv, wqh, wql, 3 * OUT_DIM * C_DIM / 4);
    cvt_hl_kernel<<<dim3(OUT_DIM * C_DIM / 4 / 256), 256, 0, stream>>>(Wo, woh, wol, OUT_DIM * C_DIM / 4);

    qkv_gemm_mfma<<<dim3(64, 24), 256, 0, stream>>>(wqh, wql, xhi, xlo, bqkv,
                                                    qhi, qlo, khi, klo, vhi);
    attn_kernel<<<dim3(16, 64), 256, 0, stream>>>(qhi, qlo, khi, klo, vhi, avhi, avlo);
    out_gemm_mfma<<<dim3(64, 8), 256, 0, stream>>>(woh, wol, avhi, avlo, bo, out);
}

// Round 4
// 575.758 us; speedup vs baseline: 3.9811x; 1.2432x over previous
//
#include <hip/hip_runtime.h>
#include <math.h>

#define S_LEN 2048
#define B_SZ 4
#define NH 16
#define HD 64
#define C_DIM 1024
#define OUT_DIM 1024

static constexpr size_t BHSD = (size_t)B_SZ * NH * S_LEN * HD; // 8,388,608

typedef __attribute__((ext_vector_type(8))) short v8bf;
typedef __attribute__((ext_vector_type(4))) float v4f;
typedef __attribute__((ext_vector_type(8))) unsigned short v8us;
typedef __attribute__((ext_vector_type(4))) unsigned short v4us;

__device__ inline unsigned short f2bf(float x) {
    unsigned u = __float_as_uint(x);
    return (unsigned short)((u + 0x7fffu + ((u >> 16) & 1u)) >> 16);  // RNE
}
__device__ inline float bf2f(unsigned short h) {
    return __uint_as_float(((unsigned)h) << 16);
}

// ---------------- Kernel 0: f32 -> (hi,lo) bf16 split ----------------
__global__ __launch_bounds__(256)
void cvt_hl_kernel(const float* __restrict__ src, unsigned short* __restrict__ hi,
                   unsigned short* __restrict__ lo, int n4)
{
    int i = blockIdx.x * 256 + threadIdx.x;
    if (i >= n4) return;
    float4 v = reinterpret_cast<const float4*>(src)[i];
    float x[4] = {v.x, v.y, v.z, v.w};
    v4us h, l;
#pragma unroll
    for (int j = 0; j < 4; ++j) {
        unsigned short hh = f2bf(x[j]);
        h[j] = hh;
        l[j] = f2bf(x[j] - bf2f(hh));
    }
    reinterpret_cast<v4us*>(hi)[i] = h;
    reinterpret_cast<v4us*>(lo)[i] = l;
}

// ---------------- shared split-bf16 MFMA mainloop ----------------
__device__ __forceinline__ void splitbf16_mainloop(
    const unsigned short* __restrict__ Ahi, const unsigned short* __restrict__ Alo,
    const unsigned short* __restrict__ Bhi, const unsigned short* __restrict__ Blo,
    int an0, int bm0, unsigned short* SA, unsigned short* SB, v4f acc[4][4])
{
    constexpr int K = 1024;
    const int t = threadIdx.x;
    const int lane = t & 63;
    const int w = t >> 6;
    const int wn = w >> 1, wm = w & 1;
    const int lr = lane & 15, lg = lane >> 4;

    for (int k0 = 0; k0 < K; k0 += 32) {
        __syncthreads();
#pragma unroll
        for (int u = 0; u < 8; ++u) {
            int id = w * 8 + u;
            int rt = id & 7;
            int sel = id >> 3;
            const unsigned short* src;
            unsigned short* dst;
            if (sel == 0)      { src = Ahi + (size_t)(an0 + rt * 16 + lr) * K + k0 + lg * 8; dst = SA + rt * 512; }
            else if (sel == 1) { src = Alo + (size_t)(an0 + rt * 16 + lr) * K + k0 + lg * 8; dst = SA + 4096 + rt * 512; }
            else if (sel == 2) { src = Bhi + (size_t)(bm0 + rt * 16 + lr) * K + k0 + lg * 8; dst = SB + rt * 512; }
            else               { src = Blo + (size_t)(bm0 + rt * 16 + lr) * K + k0 + lg * 8; dst = SB + 4096 + rt * 512; }
            __builtin_amdgcn_global_load_lds(
                (const __attribute__((address_space(1))) unsigned int*)src,
                (__attribute__((address_space(3))) unsigned int*)dst, 16, 0, 0);
        }
        __syncthreads();

        v8bf ah[4], al[4], bh[4], bl[4];
#pragma unroll
        for (int i = 0; i < 4; ++i) {
            ah[i] = *reinterpret_cast<const v8bf*>(SA + (wn * 4 + i) * 512 + lane * 8);
            al[i] = *reinterpret_cast<const v8bf*>(SA + 4096 + (wn * 4 + i) * 512 + lane * 8);
            bh[i] = *reinterpret_cast<const v8bf*>(SB + (wm * 4 + i) * 512 + lane * 8);
            bl[i] = *reinterpret_cast<const v8bf*>(SB + 4096 + (wm * 4 + i) * 512 + lane * 8);
        }
#pragma unroll
        for (int mt = 0; mt < 4; ++mt)
#pragma unroll
            for (int nt = 0; nt < 4; ++nt) {
                acc[mt][nt] = __builtin_amdgcn_mfma_f32_16x16x32_bf16(ah[nt], bh[mt], acc[mt][nt], 0, 0, 0);
                acc[mt][nt] = __builtin_amdgcn_mfma_f32_16x16x32_bf16(al[nt], bh[mt], acc[mt][nt], 0, 0, 0);
                acc[mt][nt] = __builtin_amdgcn_mfma_f32_16x16x32_bf16(ah[nt], bl[mt], acc[mt][nt], 0, 0, 0);
            }
    }
}

// ---------------- Kernel 1: QKV projection (split-bf16 MFMA) ----------------
__global__ __launch_bounds__(256)
void qkv_gemm_mfma(const unsigned short* __restrict__ Whi, const unsigned short* __restrict__ Wlo,
                   const unsigned short* __restrict__ Xhi, const unsigned short* __restrict__ Xlo,
                   const float* __restrict__ bias,
                   unsigned short* __restrict__ qhi, unsigned short* __restrict__ qlo,
                   unsigned short* __restrict__ khi, unsigned short* __restrict__ klo,
                   unsigned short* __restrict__ vhi)
{
    __shared__ __align__(16) unsigned short SA[2 * 8 * 512];
    __shared__ __align__(16) unsigned short SB[2 * 8 * 512];
    const v4f zero4 = {0.f, 0.f, 0.f, 0.f};
    v4f acc[4][4];
#pragma unroll
    for (int i = 0; i < 4; ++i)
#pragma unroll
        for (int j = 0; j < 4; ++j) acc[i][j] = zero4;

    const int bm0 = blockIdx.x * 128;
    const int an0 = blockIdx.y * 128;
    splitbf16_mainloop(Whi, Wlo, Xhi, Xlo, an0, bm0, SA, SB, acc);

    const int t = threadIdx.x;
    const int lane = t & 63;
    const int w = t >> 6;
    const int wn = w >> 1, wm = w & 1;
    const int lr = lane & 15, lg = lane >> 4;
    const int nbase = an0 + wn * 64;
    const int mbase = bm0 + wm * 64;

#pragma unroll
    for (int nt = 0; nt < 4; ++nt) {
        const int n0 = nbase + nt * 16 + lg * 4;
        const float4 b4 = *reinterpret_cast<const float4*>(bias + n0);
        const float bv[4] = {b4.x, b4.y, b4.z, b4.w};
        const int tsel = n0 >> 10;
        const int np = n0 & 1023;
        const int hh = np >> 6;
        const int dd = np & 63;
#pragma unroll
        for (int mt = 0; mt < 4; ++mt) {
            const int m = mbase + mt * 16 + lr;
            const int s = m >> 2, b = m & 3;
            float vals[4];
#pragma unroll
            for (int r = 0; r < 4; ++r) vals[r] = acc[mt][nt][r] + bv[r];
            if (tsel == 0) {
                v4us h, l;
#pragma unroll
                for (int r = 0; r < 4; ++r) {
                    float x = vals[r] * 0.125f;
                    unsigned short hi = f2bf(x);
                    h[r] = hi; l[r] = f2bf(x - bf2f(hi));
                }
                size_t base = ((size_t)(b * NH + hh) * S_LEN + s) * HD + dd;
                *reinterpret_cast<v4us*>(qhi + base) = h;
                *reinterpret_cast<v4us*>(qlo + base) = l;
            } else if (tsel == 1) {
                v4us h, l;
#pragma unroll
                for (int r = 0; r < 4; ++r) {
                    unsigned short hi = f2bf(vals[r]);
                    h[r] = hi; l[r] = f2bf(vals[r] - bf2f(hi));
                }
                size_t base = ((size_t)(b * NH + hh) * S_LEN + s) * HD + dd;
                *reinterpret_cast<v4us*>(khi + base) = h;
                *reinterpret_cast<v4us*>(klo + base) = l;
            } else {
#pragma unroll
                for (int r = 0; r < 4; ++r)
                    vhi[((size_t)(b * NH + hh) * HD + dd + r) * S_LEN + s] = f2bf(vals[r]);
            }
        }
    }
}

// ---------------- Kernel 2: flash attention, bf16 MFMA, double-buffered ----------------
// Grid: 1024 flat blocks; bh = id & 63 so all 16 q-tiles of a head land on one XCD.
// Per kt: STAGE(next buf) -> compute(cur) -> vmcnt(0) -> raw s_barrier (T3 2-phase).
// PL is per-wave: no block barrier between softmax and PV, just lgkmcnt(0).
__global__ __launch_bounds__(256, 2)
void attn_kernel(const unsigned short* __restrict__ qhi, const unsigned short* __restrict__ qlo,
                 const unsigned short* __restrict__ khi, const unsigned short* __restrict__ klo,
                 const unsigned short* __restrict__ vhi,
                 unsigned short* __restrict__ avhi, unsigned short* __restrict__ avlo)
{
    // per buffer (12288 u16 = 24KB): KH @0, KL @4096, VT @8192 (each 8 frags x 512)
    __shared__ __align__(16) unsigned short SM[2][12288];
    __shared__ __align__(16) unsigned short PL[4][32][72];

    const int t = threadIdx.x;
    const int lane = t & 63;
    const int w = t >> 6;
    const int lr = lane & 15;
    const int lg = lane >> 4;
    const int id = blockIdx.x;
    const int bh = id & 63;           // same-bh blocks share XCD (64 % 8 == 0)
    const int qt = id >> 6;
    const int b = bh >> 4, h = bh & 15;
    const size_t bh_sd = (size_t)bh * (S_LEN * HD);
    const int q0 = qt * 128 + w * 32;

    // Q fragments in registers
    v8bf qh[2][2], ql[2][2];
#pragma unroll
    for (int mt = 0; mt < 2; ++mt)
#pragma unroll
        for (int ks = 0; ks < 2; ++ks) {
            size_t off = bh_sd + (size_t)(q0 + mt * 16 + lr) * HD + ks * 32 + lg * 8;
            qh[mt][ks] = *reinterpret_cast<const v8bf*>(qhi + off);
            ql[mt][ks] = *reinterpret_cast<const v8bf*>(qlo + off);
        }

    // stage one 64-KV tile into SM[bf]: 24 chunks of 1KB, 6 per wave
    auto STAGE = [&](int kt, int bf) {
#pragma unroll
        for (int u = 0; u < 6; ++u) {
            int cid = w * 6 + u;
            int pl_ = cid >> 3;
            int n = cid & 7;
            int nt = n >> 1, kn = n & 1;
            const unsigned short* src;
            if (pl_ == 0)
                src = khi + bh_sd + (size_t)(kt * 64 + nt * 16 + lr) * HD + kn * 32 + lg * 8;
            else if (pl_ == 1)
                src = klo + bh_sd + (size_t)(kt * 64 + nt * 16 + lr) * HD + kn * 32 + lg * 8;
            else
                src = vhi + bh_sd + (size_t)(nt * 16 + lr) * S_LEN + kt * 64 + kn * 32 + lg * 8;
            unsigned short* dst = &SM[bf][pl_ * 4096 + n * 512];   // wave-uniform base
            __builtin_amdgcn_global_load_lds(
                (const __attribute__((address_space(1))) unsigned int*)src,
                (__attribute__((address_space(3))) unsigned int*)dst, 16, 0, 0);
        }
    };

    const v4f zero4 = {0.f, 0.f, 0.f, 0.f};
    v4f O[2][4];
    float m_run[2][4], l_run[2][4];
#pragma unroll
    for (int mt = 0; mt < 2; ++mt)
#pragma unroll
        for (int r = 0; r < 4; ++r) { m_run[mt][r] = -1e30f; l_run[mt][r] = 0.f; }
#pragma unroll
    for (int mt = 0; mt < 2; ++mt)
#pragma unroll
        for (int nt = 0; nt < 4; ++nt) O[mt][nt] = zero4;

    constexpr int NT = S_LEN / 64;

    // prologue: fill buf0
    STAGE(0, 0);
    asm volatile("s_waitcnt vmcnt(0)" ::: "memory");
    __builtin_amdgcn_s_barrier();
    __builtin_amdgcn_sched_barrier(0);

    for (int kt = 0; kt < NT; ++kt) {
        const int cur = kt & 1;
        if (kt + 1 < NT) STAGE(kt + 1, cur ^ 1);   // prefetch overlaps compute below

        const unsigned short* KH = &SM[cur][0];
        const unsigned short* KL = &SM[cur][4096];
        const unsigned short* VT = &SM[cur][8192];

        // ---- QK^T (split-bf16, 3 MFMA per frag pair) ----
        v4f sc[2][4];
#pragma unroll
        for (int mt = 0; mt < 2; ++mt)
#pragma unroll
            for (int nt = 0; nt < 4; ++nt) sc[mt][nt] = zero4;
#pragma unroll
        for (int ks = 0; ks < 2; ++ks)
#pragma unroll
            for (int nt = 0; nt < 4; ++nt) {
                v8bf kh = *reinterpret_cast<const v8bf*>(KH + (nt * 2 + ks) * 512 + lane * 8);
                v8bf kl = *reinterpret_cast<const v8bf*>(KL + (nt * 2 + ks) * 512 + lane * 8);
#pragma unroll
                for (int mt = 0; mt < 2; ++mt) {
                    sc[mt][nt] = __builtin_amdgcn_mfma_f32_16x16x32_bf16(qh[mt][ks], kh, sc[mt][nt], 0, 0, 0);
                    sc[mt][nt] = __builtin_amdgcn_mfma_f32_16x16x32_bf16(ql[mt][ks], kh, sc[mt][nt], 0, 0, 0);
                    sc[mt][nt] = __builtin_amdgcn_mfma_f32_16x16x32_bf16(qh[mt][ks], kl, sc[mt][nt], 0, 0, 0);
                }
            }

        // ---- online softmax; P -> per-wave LDS ----
#pragma unroll
        for (int mt = 0; mt < 2; ++mt)
#pragma unroll
            for (int r = 0; r < 4; ++r) {
                float rm = fmaxf(fmaxf(sc[mt][0][r], sc[mt][1][r]), fmaxf(sc[mt][2][r], sc[mt][3][r]));
                rm = fmaxf(rm, __shfl_xor(rm, 1));
                rm = fmaxf(rm, __shfl_xor(rm, 2));
                rm = fmaxf(rm, __shfl_xor(rm, 4));
                rm = fmaxf(rm, __shfl_xor(rm, 8));
                float nm = fmaxf(m_run[mt][r], rm);
                float alpha = __expf(m_run[mt][r] - nm);
                m_run[mt][r] = nm;
                float rs = 0.f;
#pragma unroll
                for (int nt = 0; nt < 4; ++nt) {
                    float p = __expf(sc[mt][nt][r] - nm);
                    rs += p;
                    PL[w][mt * 16 + lg * 4 + r][nt * 16 + lr] = f2bf(p);
                }
                rs += __shfl_xor(rs, 1);
                rs += __shfl_xor(rs, 2);
                rs += __shfl_xor(rs, 4);
                rs += __shfl_xor(rs, 8);
                l_run[mt][r] = l_run[mt][r] * alpha + rs;
#pragma unroll
                for (int nt = 0; nt < 4; ++nt) O[mt][nt][r] *= alpha;
            }
        // PL[w] is wave-private: within-wave ds_write -> ds_read needs only lgkmcnt
        asm volatile("s_waitcnt lgkmcnt(0)" ::: "memory");
        __builtin_amdgcn_sched_barrier(0);

        // ---- PV ----
#pragma unroll
        for (int ks = 0; ks < 2; ++ks) {
            v8bf pa[2];
#pragma unroll
            for (int mt = 0; mt < 2; ++mt)
                pa[mt] = *reinterpret_cast<const v8bf*>(&PL[w][mt * 16 + lr][ks * 32 + lg * 8]);
#pragma unroll
            for (int nt = 0; nt < 4; ++nt) {
                v8bf vf = *reinterpret_cast<const v8bf*>(VT + (nt * 2 + ks) * 512 + lane * 8);
#pragma unroll
                for (int mt = 0; mt < 2; ++mt)
                    O[mt][nt] = __builtin_amdgcn_mfma_f32_16x16x32_bf16(pa[mt], vf, O[mt][nt], 0, 0, 0);
            }
        }

        // end-of-iter: this wave's prefetch landed; all waves done reading SM[cur]
        asm volatile("s_waitcnt vmcnt(0)" ::: "memory");
        __builtin_amdgcn_s_barrier();
        __builtin_amdgcn_sched_barrier(0);
    }

    // epilogue: normalize, split hi/lo bf16 into av[(b*S+s)*1024 + h*64 + d]
#pragma unroll
    for (int mt = 0; mt < 2; ++mt)
#pragma unroll
        for (int r = 0; r < 4; ++r) {
            float inv = 1.f / l_run[mt][r];
            int s = q0 + mt * 16 + lg * 4 + r;
            size_t base = (size_t)(b * S_LEN + s) * OUT_DIM + h * HD;
#pragma unroll
            for (int nt = 0; nt < 4; ++nt) {
                float val = O[mt][nt][r] * inv;
                unsigned short hi = f2bf(val);
                avhi[base + nt * 16 + lr] = hi;
                avlo[base + nt * 16 + lr] = f2bf(val - bf2f(hi));
            }
        }
}

// ---------------- Kernel 3: output projection (split-bf16 MFMA) ----------------
__global__ __launch_bounds__(256)
void out_gemm_mfma(const unsigned short* __restrict__ Whi, const unsigned short* __restrict__ Wlo,
                   const unsigned short* __restrict__ Bhi, const unsigned short* __restrict__ Blo,
                   const float* __restrict__ bias, float* __restrict__ out)
{
    __shared__ __align__(16) unsigned short SA[2 * 8 * 512];
    __shared__ __align__(16) unsigned short SB[2 * 8 * 512];
    const v4f zero4 = {0.f, 0.f, 0.f, 0.f};
    v4f acc[4][4];
#pragma unroll
    for (int i = 0; i < 4; ++i)
#pragma unroll
        for (int j = 0; j < 4; ++j) acc[i][j] = zero4;

    const int bm0 = blockIdx.x * 128;
    const int an0 = blockIdx.y * 128;
    splitbf16_mainloop(Whi, Wlo, Bhi, Blo, an0, bm0, SA, SB, acc);

    const int t = threadIdx.x;
    const int lane = t & 63;
    const int w = t >> 6;
    const int wn = w >> 1, wm = w & 1;
    const int lr = lane & 15, lg = lane >> 4;
    const int nbase = an0 + wn * 64;
    const int mbase = bm0 + wm * 64;

#pragma unroll
    for (int nt = 0; nt < 4; ++nt) {
        const int n0 = nbase + nt * 16 + lg * 4;
        const float4 b4 = *reinterpret_cast<const float4*>(bias + n0);
#pragma unroll
        for (int mt = 0; mt < 4; ++mt) {
            const int m = mbase + mt * 16 + lr;
            float4 o = make_float4(acc[mt][nt][0] + b4.x, acc[mt][nt][1] + b4.y,
                                   acc[mt][nt][2] + b4.z, acc[mt][nt][3] + b4.w);
            *reinterpret_cast<float4*>(out + (size_t)m * OUT_DIM + n0) = o;
        }
    }
}

extern "C" void kernel_launch(void* const* d_in, const int* in_sizes, int n_in,
                              void* d_out, int out_size, void* d_ws, size_t ws_size,
                              hipStream_t stream)
{
    const float* x    = (const float*)d_in[0];
    const float* Wqkv = (const float*)d_in[1];
    const float* bqkv = (const float*)d_in[2];
    const float* Wo   = (const float*)d_in[3];
    const float* bo   = (const float*)d_in[4];
    float* out = (float*)d_out;

    unsigned short* p = (unsigned short*)d_ws;
    unsigned short* xhi = p;            p += BHSD;
    unsigned short* xlo = p;            p += BHSD;
    unsigned short* wqh = p;            p += 3 * OUT_DIM * C_DIM;
    unsigned short* wql = p;            p += 3 * OUT_DIM * C_DIM;
    unsigned short* woh = p;            p += OUT_DIM * OUT_DIM;
    unsigned short* wol = p;            p += OUT_DIM * OUT_DIM;
    unsigned short* qhi = p;            p += BHSD;
    unsigned short* qlo = p;            p += BHSD;
    unsigned short* khi = p;            p += BHSD;
    unsigned short* klo = p;            p += BHSD;
    unsigned short* vhi = p;            p += BHSD;
    unsigned short* avhi = xhi;         // x dead after qkv_gemm -> reuse
    unsigned short* avlo = xlo;

    cvt_hl_kernel<<<dim3((int)(BHSD / 4 / 256)), 256, 0, stream>>>(x, xhi, xlo, (int)(BHSD / 4));
    cvt_hl_kernel<<<dim3(3 * OUT_DIM * C_DIM / 4 / 256), 256, 0, stream>>>(Wqkv, wqh, wql, 3 * OUT_DIM * C_DIM / 4);
    cvt_hl_kernel<<<dim3(OUT_DIM * C_DIM / 4 / 256), 256, 0, stream>>>(Wo, woh, wol, OUT_DIM * C_DIM / 4);

    qkv_gemm_mfma<<<dim3(64, 24), 256, 0, stream>>>(wqh, wql, xhi, xlo, bqkv,
                                                    qhi, qlo, khi, klo, vhi);
    attn_kernel<<<dim3(1024), 256, 0, stream>>>(qhi, qlo, khi, klo, vhi, avhi, avlo);
    out_gemm_mfma<<<dim3(64, 8), 256, 0, stream>>>(woh, wol, avhi, avlo, bo, out);
}

// Round 5
// 564.393 us; speedup vs baseline: 4.0613x; 1.0201x over previous
//
#include <hip/hip_runtime.h>
#include <hip/hip_bf16.h>
#include <math.h>

#define S_LEN 2048
#define B_SZ 4
#define NH 16
#define HD 64
#define C_DIM 1024
#define OUT_DIM 1024

static constexpr size_t BHSD = (size_t)B_SZ * NH * S_LEN * HD; // 8,388,608
#define QSCALE 0.18033688011112042f   /* 0.125 * log2(e): scores land in log2 domain */

typedef __attribute__((ext_vector_type(8))) short v8bf;
typedef __attribute__((ext_vector_type(4))) float v4f;
typedef __attribute__((ext_vector_type(4))) unsigned short v4us;

__device__ inline unsigned short f2bf(float x) {
    unsigned u = __float_as_uint(x);
    return (unsigned short)((u + 0x7fffu + ((u >> 16) & 1u)) >> 16);  // RNE
}
__device__ inline float bf2f(unsigned short h) {
    return __uint_as_float(((unsigned)h) << 16);
}
__device__ inline unsigned short cvt_bf(float x) {     // compiler-fusable (v_cvt_pk_bf16_f32)
    __hip_bfloat16 hb = __float2bfloat16(x);
    return reinterpret_cast<unsigned short&>(hb);
}

// ---------------- Kernel 0: f32 -> (hi,lo) bf16 split ----------------
__global__ __launch_bounds__(256)
void cvt_hl_kernel(const float* __restrict__ src, unsigned short* __restrict__ hi,
                   unsigned short* __restrict__ lo, int n4)
{
    int i = blockIdx.x * 256 + threadIdx.x;
    if (i >= n4) return;
    float4 v = reinterpret_cast<const float4*>(src)[i];
    float x[4] = {v.x, v.y, v.z, v.w};
    v4us h, l;
#pragma unroll
    for (int j = 0; j < 4; ++j) {
        unsigned short hh = f2bf(x[j]);
        h[j] = hh;
        l[j] = f2bf(x[j] - bf2f(hh));
    }
    reinterpret_cast<v4us*>(hi)[i] = h;
    reinterpret_cast<v4us*>(lo)[i] = l;
}

// ---------------- shared split-bf16 MFMA mainloop (2-phase dbuf) ----------------
// SA/SB each: [2 bufs][hi 4096 | lo 4096] u16 = 32 KB. Per iter: STAGE(next) ->
// ds_read+MFMA(cur) -> vmcnt(0) -> s_barrier. One barrier per K-step.
__device__ __forceinline__ void splitbf16_mainloop(
    const unsigned short* __restrict__ Ahi, const unsigned short* __restrict__ Alo,
    const unsigned short* __restrict__ Bhi, const unsigned short* __restrict__ Blo,
    int an0, int bm0, unsigned short* SA, unsigned short* SB, v4f acc[4][4])
{
    constexpr int K = 1024;
    const int t = threadIdx.x;
    const int lane = t & 63;
    const int w = t >> 6;
    const int wn = w >> 1, wm = w & 1;
    const int lr = lane & 15, lg = lane >> 4;

    auto STAGE = [&](int k0, int bf) {
#pragma unroll
        for (int u = 0; u < 8; ++u) {
            int id = w * 8 + u;
            int rt = id & 7;
            int sel = id >> 3;
            const unsigned short* src;
            unsigned short* dst;
            if (sel == 0)      { src = Ahi + (size_t)(an0 + rt * 16 + lr) * K + k0 + lg * 8; dst = SA + bf * 8192 + rt * 512; }
            else if (sel == 1) { src = Alo + (size_t)(an0 + rt * 16 + lr) * K + k0 + lg * 8; dst = SA + bf * 8192 + 4096 + rt * 512; }
            else if (sel == 2) { src = Bhi + (size_t)(bm0 + rt * 16 + lr) * K + k0 + lg * 8; dst = SB + bf * 8192 + rt * 512; }
            else               { src = Blo + (size_t)(bm0 + rt * 16 + lr) * K + k0 + lg * 8; dst = SB + bf * 8192 + 4096 + rt * 512; }
            __builtin_amdgcn_global_load_lds(
                (const __attribute__((address_space(1))) unsigned int*)src,
                (__attribute__((address_space(3))) unsigned int*)dst, 16, 0, 0);
        }
    };

    STAGE(0, 0);
    asm volatile("s_waitcnt vmcnt(0)" ::: "memory");
    __builtin_amdgcn_s_barrier();
    __builtin_amdgcn_sched_barrier(0);

    for (int k0 = 0; k0 < K; k0 += 32) {
        const int bf = (k0 >> 5) & 1;
        if (k0 + 32 < K) STAGE(k0 + 32, bf ^ 1);   // prefetch hides under compute

        v8bf ah[4], al[4], bh[4], bl[4];
#pragma unroll
        for (int i = 0; i < 4; ++i) {
            ah[i] = *reinterpret_cast<const v8bf*>(SA + bf * 8192 + (wn * 4 + i) * 512 + lane * 8);
            al[i] = *reinterpret_cast<const v8bf*>(SA + bf * 8192 + 4096 + (wn * 4 + i) * 512 + lane * 8);
            bh[i] = *reinterpret_cast<const v8bf*>(SB + bf * 8192 + (wm * 4 + i) * 512 + lane * 8);
            bl[i] = *reinterpret_cast<const v8bf*>(SB + bf * 8192 + 4096 + (wm * 4 + i) * 512 + lane * 8);
        }
#pragma unroll
        for (int mt = 0; mt < 4; ++mt)
#pragma unroll
            for (int nt = 0; nt < 4; ++nt) {
                acc[mt][nt] = __builtin_amdgcn_mfma_f32_16x16x32_bf16(ah[nt], bh[mt], acc[mt][nt], 0, 0, 0);
                acc[mt][nt] = __builtin_amdgcn_mfma_f32_16x16x32_bf16(al[nt], bh[mt], acc[mt][nt], 0, 0, 0);
                acc[mt][nt] = __builtin_amdgcn_mfma_f32_16x16x32_bf16(ah[nt], bl[mt], acc[mt][nt], 0, 0, 0);
            }

        asm volatile("s_waitcnt vmcnt(0)" ::: "memory");
        __builtin_amdgcn_s_barrier();
        __builtin_amdgcn_sched_barrier(0);
    }
}

// ---------------- Kernel 1: QKV projection (split-bf16 MFMA) ----------------
__global__ __launch_bounds__(256)
void qkv_gemm_mfma(const unsigned short* __restrict__ Whi, const unsigned short* __restrict__ Wlo,
                   const unsigned short* __restrict__ Xhi, const unsigned short* __restrict__ Xlo,
                   const float* __restrict__ bias,
                   unsigned short* __restrict__ qhi, unsigned short* __restrict__ qlo,
                   unsigned short* __restrict__ khi, unsigned short* __restrict__ klo,
                   unsigned short* __restrict__ vhi)
{
    __shared__ __align__(16) unsigned short SA[2 * 8192];   // 32 KB
    __shared__ __align__(16) unsigned short SB[2 * 8192];
    const v4f zero4 = {0.f, 0.f, 0.f, 0.f};
    v4f acc[4][4];
#pragma unroll
    for (int i = 0; i < 4; ++i)
#pragma unroll
        for (int j = 0; j < 4; ++j) acc[i][j] = zero4;

    const int bm0 = blockIdx.x * 128;
    const int an0 = blockIdx.y * 128;
    splitbf16_mainloop(Whi, Wlo, Xhi, Xlo, an0, bm0, SA, SB, acc);

    const int t = threadIdx.x;
    const int lane = t & 63;
    const int w = t >> 6;
    const int wn = w >> 1, wm = w & 1;
    const int lr = lane & 15, lg = lane >> 4;
    const int nbase = an0 + wn * 64;
    const int mbase = bm0 + wm * 64;

#pragma unroll
    for (int nt = 0; nt < 4; ++nt) {
        const int n0 = nbase + nt * 16 + lg * 4;
        const float4 b4 = *reinterpret_cast<const float4*>(bias + n0);
        const float bv[4] = {b4.x, b4.y, b4.z, b4.w};
        const int tsel = n0 >> 10;
        const int np = n0 & 1023;
        const int hh = np >> 6;
        const int dd = np & 63;
#pragma unroll
        for (int mt = 0; mt < 4; ++mt) {
            const int m = mbase + mt * 16 + lr;
            const int s = m >> 2, b = m & 3;
            float vals[4];
#pragma unroll
            for (int r = 0; r < 4; ++r) vals[r] = acc[mt][nt][r] + bv[r];
            if (tsel == 0) {
                v4us h, l;
#pragma unroll
                for (int r = 0; r < 4; ++r) {
                    float x = vals[r] * QSCALE;          // fold 1/sqrt(D) * log2(e)
                    unsigned short hi = f2bf(x);
                    h[r] = hi; l[r] = f2bf(x - bf2f(hi));
                }
                size_t base = ((size_t)(b * NH + hh) * S_LEN + s) * HD + dd;
                *reinterpret_cast<v4us*>(qhi + base) = h;
                *reinterpret_cast<v4us*>(qlo + base) = l;
            } else if (tsel == 1) {
                v4us h, l;
#pragma unroll
                for (int r = 0; r < 4; ++r) {
                    unsigned short hi = f2bf(vals[r]);
                    h[r] = hi; l[r] = f2bf(vals[r] - bf2f(hi));
                }
                size_t base = ((size_t)(b * NH + hh) * S_LEN + s) * HD + dd;
                *reinterpret_cast<v4us*>(khi + base) = h;
                *reinterpret_cast<v4us*>(klo + base) = l;
            } else {
#pragma unroll
                for (int r = 0; r < 4; ++r)
                    vhi[((size_t)(b * NH + hh) * HD + dd + r) * S_LEN + s] = f2bf(vals[r]);
            }
        }
    }
}

// ---------------- Kernel 2: flash attention, bf16 MFMA, dbuf + defer-max ----------------
__global__ __launch_bounds__(256, 2)
void attn_kernel(const unsigned short* __restrict__ qhi, const unsigned short* __restrict__ qlo,
                 const unsigned short* __restrict__ khi, const unsigned short* __restrict__ klo,
                 const unsigned short* __restrict__ vhi,
                 unsigned short* __restrict__ avhi, unsigned short* __restrict__ avlo)
{
    __shared__ __align__(16) unsigned short SM[2][12288];  // KH@0 KL@4096 VT@8192
    __shared__ __align__(16) unsigned short PL[4][32][72];

    const int t = threadIdx.x;
    const int lane = t & 63;
    const int w = t >> 6;
    const int lr = lane & 15;
    const int lg = lane >> 4;
    const int id = blockIdx.x;
    const int bh = id & 63;           // same-bh blocks share XCD (64 % 8 == 0)
    const int qt = id >> 6;
    const int b = bh >> 4, h = bh & 15;
    const size_t bh_sd = (size_t)bh * (S_LEN * HD);
    const int q0 = qt * 128 + w * 32;

    v8bf qh[2][2], ql[2][2];
#pragma unroll
    for (int mt = 0; mt < 2; ++mt)
#pragma unroll
        for (int ks = 0; ks < 2; ++ks) {
            size_t off = bh_sd + (size_t)(q0 + mt * 16 + lr) * HD + ks * 32 + lg * 8;
            qh[mt][ks] = *reinterpret_cast<const v8bf*>(qhi + off);
            ql[mt][ks] = *reinterpret_cast<const v8bf*>(qlo + off);
        }

    auto STAGE = [&](int kt, int bf) {
#pragma unroll
        for (int u = 0; u < 6; ++u) {
            int cid = w * 6 + u;
            int pl_ = cid >> 3;
            int n = cid & 7;
            int nt = n >> 1, kn = n & 1;
            const unsigned short* src;
            if (pl_ == 0)
                src = khi + bh_sd + (size_t)(kt * 64 + nt * 16 + lr) * HD + kn * 32 + lg * 8;
            else if (pl_ == 1)
                src = klo + bh_sd + (size_t)(kt * 64 + nt * 16 + lr) * HD + kn * 32 + lg * 8;
            else
                src = vhi + bh_sd + (size_t)(nt * 16 + lr) * S_LEN + kt * 64 + kn * 32 + lg * 8;
            unsigned short* dst = &SM[bf][pl_ * 4096 + n * 512];
            __builtin_amdgcn_global_load_lds(
                (const __attribute__((address_space(1))) unsigned int*)src,
                (__attribute__((address_space(3))) unsigned int*)dst, 16, 0, 0);
        }
    };

    const v4f zero4 = {0.f, 0.f, 0.f, 0.f};
    v4f O[2][4];
    float m_run[2][4], l_run[2][4];
#pragma unroll
    for (int mt = 0; mt < 2; ++mt)
#pragma unroll
        for (int r = 0; r < 4; ++r) { m_run[mt][r] = -1e30f; l_run[mt][r] = 0.f; }
#pragma unroll
    for (int mt = 0; mt < 2; ++mt)
#pragma unroll
        for (int nt = 0; nt < 4; ++nt) O[mt][nt] = zero4;

    constexpr int NT = S_LEN / 64;

    STAGE(0, 0);
    asm volatile("s_waitcnt vmcnt(0)" ::: "memory");
    __builtin_amdgcn_s_barrier();
    __builtin_amdgcn_sched_barrier(0);

    for (int kt = 0; kt < NT; ++kt) {
        const int cur = kt & 1;
        if (kt + 1 < NT) STAGE(kt + 1, cur ^ 1);

        const unsigned short* KH = &SM[cur][0];
        const unsigned short* KL = &SM[cur][4096];
        const unsigned short* VT = &SM[cur][8192];

        // ---- QK^T (split-bf16, scores in log2 domain) ----
        v4f sc[2][4];
#pragma unroll
        for (int mt = 0; mt < 2; ++mt)
#pragma unroll
            for (int nt = 0; nt < 4; ++nt) sc[mt][nt] = zero4;
#pragma unroll
        for (int ks = 0; ks < 2; ++ks)
#pragma unroll
            for (int nt = 0; nt < 4; ++nt) {
                v8bf kh = *reinterpret_cast<const v8bf*>(KH + (nt * 2 + ks) * 512 + lane * 8);
                v8bf kl = *reinterpret_cast<const v8bf*>(KL + (nt * 2 + ks) * 512 + lane * 8);
#pragma unroll
                for (int mt = 0; mt < 2; ++mt) {
                    sc[mt][nt] = __builtin_amdgcn_mfma_f32_16x16x32_bf16(qh[mt][ks], kh, sc[mt][nt], 0, 0, 0);
                    sc[mt][nt] = __builtin_amdgcn_mfma_f32_16x16x32_bf16(ql[mt][ks], kh, sc[mt][nt], 0, 0, 0);
                    sc[mt][nt] = __builtin_amdgcn_mfma_f32_16x16x32_bf16(qh[mt][ks], kl, sc[mt][nt], 0, 0, 0);
                }
            }

        // ---- online softmax with defer-max (T13, THR=8 in log2 units) ----
        float rm[2][4];
        bool need = false;
#pragma unroll
        for (int mt = 0; mt < 2; ++mt)
#pragma unroll
            for (int r = 0; r < 4; ++r) {
                float m4 = fmaxf(fmaxf(sc[mt][0][r], sc[mt][1][r]), fmaxf(sc[mt][2][r], sc[mt][3][r]));
                m4 = fmaxf(m4, __shfl_xor(m4, 1));
                m4 = fmaxf(m4, __shfl_xor(m4, 2));
                m4 = fmaxf(m4, __shfl_xor(m4, 4));
                m4 = fmaxf(m4, __shfl_xor(m4, 8));
                rm[mt][r] = m4;
                need = need || (m4 > m_run[mt][r] + 8.0f);
            }
        if (__any(need)) {      // wave-uniform rescale; skipped most iterations
#pragma unroll
            for (int mt = 0; mt < 2; ++mt)
#pragma unroll
                for (int r = 0; r < 4; ++r) {
                    float nm = fmaxf(m_run[mt][r], rm[mt][r]);
                    float alpha = exp2f(m_run[mt][r] - nm);
                    m_run[mt][r] = nm;
                    l_run[mt][r] *= alpha;
#pragma unroll
                    for (int nt = 0; nt < 4; ++nt) O[mt][nt][r] *= alpha;
                }
        }
#pragma unroll
        for (int mt = 0; mt < 2; ++mt)
#pragma unroll
            for (int r = 0; r < 4; ++r) {
                float rs = 0.f;
#pragma unroll
                for (int nt = 0; nt < 4; ++nt) {
                    float p = exp2f(sc[mt][nt][r] - m_run[mt][r]);   // bounded by 2^8
                    rs += p;
                    PL[w][mt * 16 + lg * 4 + r][nt * 16 + lr] = cvt_bf(p);
                }
                rs += __shfl_xor(rs, 1);
                rs += __shfl_xor(rs, 2);
                rs += __shfl_xor(rs, 4);
                rs += __shfl_xor(rs, 8);
                l_run[mt][r] += rs;
            }
        // PL[w] is wave-private: within-wave ds_write -> ds_read needs only lgkmcnt
        asm volatile("s_waitcnt lgkmcnt(0)" ::: "memory");
        __builtin_amdgcn_sched_barrier(0);

        // ---- PV ----
#pragma unroll
        for (int ks = 0; ks < 2; ++ks) {
            v8bf pa[2];
#pragma unroll
            for (int mt = 0; mt < 2; ++mt)
                pa[mt] = *reinterpret_cast<const v8bf*>(&PL[w][mt * 16 + lr][ks * 32 + lg * 8]);
#pragma unroll
            for (int nt = 0; nt < 4; ++nt) {
                v8bf vf = *reinterpret_cast<const v8bf*>(VT + (nt * 2 + ks) * 512 + lane * 8);
#pragma unroll
                for (int mt = 0; mt < 2; ++mt)
                    O[mt][nt] = __builtin_amdgcn_mfma_f32_16x16x32_bf16(pa[mt], vf, O[mt][nt], 0, 0, 0);
            }
        }

        asm volatile("s_waitcnt vmcnt(0)" ::: "memory");
        __builtin_amdgcn_s_barrier();
        __builtin_amdgcn_sched_barrier(0);
    }

    // epilogue: normalize, split hi/lo bf16 into av[(b*S+s)*1024 + h*64 + d]
#pragma unroll
    for (int mt = 0; mt < 2; ++mt)
#pragma unroll
        for (int r = 0; r < 4; ++r) {
            float inv = 1.f / l_run[mt][r];
            int s = q0 + mt * 16 + lg * 4 + r;
            size_t base = (size_t)(b * S_LEN + s) * OUT_DIM + h * HD;
#pragma unroll
            for (int nt = 0; nt < 4; ++nt) {
                float val = O[mt][nt][r] * inv;
                unsigned short hi = f2bf(val);
                avhi[base + nt * 16 + lr] = hi;
                avlo[base + nt * 16 + lr] = f2bf(val - bf2f(hi));
            }
        }
}

// ---------------- Kernel 3: output projection (split-bf16 MFMA) ----------------
__global__ __launch_bounds__(256)
void out_gemm_mfma(const unsigned short* __restrict__ Whi, const unsigned short* __restrict__ Wlo,
                   const unsigned short* __restrict__ Bhi, const unsigned short* __restrict__ Blo,
                   const float* __restrict__ bias, float* __restrict__ out)
{
    __shared__ __align__(16) unsigned short SA[2 * 8192];
    __shared__ __align__(16) unsigned short SB[2 * 8192];
    const v4f zero4 = {0.f, 0.f, 0.f, 0.f};
    v4f acc[4][4];
#pragma unroll
    for (int i = 0; i < 4; ++i)
#pragma unroll
        for (int j = 0; j < 4; ++j) acc[i][j] = zero4;

    const int bm0 = blockIdx.x * 128;
    const int an0 = blockIdx.y * 128;
    splitbf16_mainloop(Whi, Wlo, Bhi, Blo, an0, bm0, SA, SB, acc);

    const int t = threadIdx.x;
    const int lane = t & 63;
    const int w = t >> 6;
    const int wn = w >> 1, wm = w & 1;
    const int lr = lane & 15, lg = lane >> 4;
    const int nbase = an0 + wn * 64;
    const int mbase = bm0 + wm * 64;

#pragma unroll
    for (int nt = 0; nt < 4; ++nt) {
        const int n0 = nbase + nt * 16 + lg * 4;
        const float4 b4 = *reinterpret_cast<const float4*>(bias + n0);
#pragma unroll
        for (int mt = 0; mt < 4; ++mt) {
            const int m = mbase + mt * 16 + lr;
            float4 o = make_float4(acc[mt][nt][0] + b4.x, acc[mt][nt][1] + b4.y,
                                   acc[mt][nt][2] + b4.z, acc[mt][nt][3] + b4.w);
            *reinterpret_cast<float4*>(out + (size_t)m * OUT_DIM + n0) = o;
        }
    }
}

extern "C" void kernel_launch(void* const* d_in, const int* in_sizes, int n_in,
                              void* d_out, int out_size, void* d_ws, size_t ws_size,
                              hipStream_t stream)
{
    const float* x    = (const float*)d_in[0];
    const float* Wqkv = (const float*)d_in[1];
    const float* bqkv = (const float*)d_in[2];
    const float* Wo   = (const float*)d_in[3];
    const float* bo   = (const float*)d_in[4];
    float* out = (float*)d_out;

    unsigned short* p = (unsigned short*)d_ws;
    unsigned short* xhi = p;            p += BHSD;
    unsigned short* xlo = p;            p += BHSD;
    unsigned short* wqh = p;            p += 3 * OUT_DIM * C_DIM;
    unsigned short* wql = p;            p += 3 * OUT_DIM * C_DIM;
    unsigned short* woh = p;            p += OUT_DIM * OUT_DIM;
    unsigned short* wol = p;            p += OUT_DIM * OUT_DIM;
    unsigned short* qhi = p;            p += BHSD;
    unsigned short* qlo = p;            p += BHSD;
    unsigned short* khi = p;            p += BHSD;
    unsigned short* klo = p;            p += BHSD;
    unsigned short* vhi = p;            p += BHSD;
    unsigned short* avhi = xhi;         // x dead after qkv_gemm -> reuse
    unsigned short* avlo = xlo;

    cvt_hl_kernel<<<dim3((int)(BHSD / 4 / 256)), 256, 0, stream>>>(x, xhi, xlo, (int)(BHSD / 4));
    cvt_hl_kernel<<<dim3(3 * OUT_DIM * C_DIM / 4 / 256), 256, 0, stream>>>(Wqkv, wqh, wql, 3 * OUT_DIM * C_DIM / 4);
    cvt_hl_kernel<<<dim3(OUT_DIM * C_DIM / 4 / 256), 256, 0, stream>>>(Wo, woh, wol, OUT_DIM * C_DIM / 4);

    qkv_gemm_mfma<<<dim3(64, 24), 256, 0, stream>>>(wqh, wql, xhi, xlo, bqkv,
                                                    qhi, qlo, khi, klo, vhi);
    attn_kernel<<<dim3(1024), 256, 0, stream>>>(qhi, qlo, khi, klo, vhi, avhi, avlo);
    out_gemm_mfma<<<dim3(64, 8), 256, 0, stream>>>(woh, wol, avhi, avlo, bo, out);
}

// Round 6
// 467.323 us; speedup vs baseline: 4.9048x; 1.2077x over previous
//
#include <hip/hip_runtime.h>
#include <hip/hip_bf16.h>
#include <math.h>

#define S_LEN 2048
#define B_SZ 4
#define NH 16
#define HD 64
#define C_DIM 1024
#define OUT_DIM 1024

static constexpr size_t BHSD = (size_t)B_SZ * NH * S_LEN * HD; // 8,388,608
#define QSCALE 0.18033688011112042f   /* 0.125 * log2(e): scores in log2 domain */

typedef __attribute__((ext_vector_type(8))) short v8bf;
typedef __attribute__((ext_vector_type(4))) float v4f;
typedef __attribute__((ext_vector_type(4))) unsigned short v4us;

__device__ inline unsigned short f2bf(float x) {
    unsigned u = __float_as_uint(x);
    return (unsigned short)((u + 0x7fffu + ((u >> 16) & 1u)) >> 16);  // RNE
}
__device__ inline float bf2f(unsigned short h) {
    return __uint_as_float(((unsigned)h) << 16);
}
__device__ inline unsigned short cvt_bf(float x) {
    __hip_bfloat16 hb = __float2bfloat16(x);
    return reinterpret_cast<unsigned short&>(hb);
}

// ---------------- Kernel 0: f32 -> (hi,lo) bf16 split ----------------
__global__ __launch_bounds__(256)
void cvt_hl_kernel(const float* __restrict__ src, unsigned short* __restrict__ hi,
                   unsigned short* __restrict__ lo, int n4)
{
    int i = blockIdx.x * 256 + threadIdx.x;
    if (i >= n4) return;
    float4 v = reinterpret_cast<const float4*>(src)[i];
    float x[4] = {v.x, v.y, v.z, v.w};
    v4us h, l;
#pragma unroll
    for (int j = 0; j < 4; ++j) {
        unsigned short hh = f2bf(x[j]);
        h[j] = hh;
        l[j] = f2bf(x[j] - bf2f(hh));
    }
    reinterpret_cast<v4us*>(hi)[i] = h;
    reinterpret_cast<v4us*>(lo)[i] = l;
}

// ---------------- shared split-bf16 MFMA mainloop (2-phase dbuf) ----------------
__device__ __forceinline__ void splitbf16_mainloop(
    const unsigned short* __restrict__ Ahi, const unsigned short* __restrict__ Alo,
    const unsigned short* __restrict__ Bhi, const unsigned short* __restrict__ Blo,
    int an0, int bm0, unsigned short* SA, unsigned short* SB, v4f acc[4][4])
{
    constexpr int K = 1024;
    const int t = threadIdx.x;
    const int lane = t & 63;
    const int w = t >> 6;
    const int wn = w >> 1, wm = w & 1;
    const int lr = lane & 15, lg = lane >> 4;

    auto STAGE = [&](int k0, int bf) {
#pragma unroll
        for (int u = 0; u < 8; ++u) {
            int id = w * 8 + u;
            int rt = id & 7;
            int sel = id >> 3;
            const unsigned short* src;
            unsigned short* dst;
            if (sel == 0)      { src = Ahi + (size_t)(an0 + rt * 16 + lr) * K + k0 + lg * 8; dst = SA + bf * 8192 + rt * 512; }
            else if (sel == 1) { src = Alo + (size_t)(an0 + rt * 16 + lr) * K + k0 + lg * 8; dst = SA + bf * 8192 + 4096 + rt * 512; }
            else if (sel == 2) { src = Bhi + (size_t)(bm0 + rt * 16 + lr) * K + k0 + lg * 8; dst = SB + bf * 8192 + rt * 512; }
            else               { src = Blo + (size_t)(bm0 + rt * 16 + lr) * K + k0 + lg * 8; dst = SB + bf * 8192 + 4096 + rt * 512; }
            __builtin_amdgcn_global_load_lds(
                (const __attribute__((address_space(1))) unsigned int*)src,
                (__attribute__((address_space(3))) unsigned int*)dst, 16, 0, 0);
        }
    };

    STAGE(0, 0);
    asm volatile("s_waitcnt vmcnt(0)" ::: "memory");
    __builtin_amdgcn_s_barrier();
    __builtin_amdgcn_sched_barrier(0);

    for (int k0 = 0; k0 < K; k0 += 32) {
        const int bf = (k0 >> 5) & 1;
        if (k0 + 32 < K) STAGE(k0 + 32, bf ^ 1);

        v8bf ah[4], al[4], bh[4], bl[4];
#pragma unroll
        for (int i = 0; i < 4; ++i) {
            ah[i] = *reinterpret_cast<const v8bf*>(SA + bf * 8192 + (wn * 4 + i) * 512 + lane * 8);
            al[i] = *reinterpret_cast<const v8bf*>(SA + bf * 8192 + 4096 + (wn * 4 + i) * 512 + lane * 8);
            bh[i] = *reinterpret_cast<const v8bf*>(SB + bf * 8192 + (wm * 4 + i) * 512 + lane * 8);
            bl[i] = *reinterpret_cast<const v8bf*>(SB + bf * 8192 + 4096 + (wm * 4 + i) * 512 + lane * 8);
        }
        __builtin_amdgcn_s_setprio(1);
#pragma unroll
        for (int mt = 0; mt < 4; ++mt)
#pragma unroll
            for (int nt = 0; nt < 4; ++nt) {
                acc[mt][nt] = __builtin_amdgcn_mfma_f32_16x16x32_bf16(ah[nt], bh[mt], acc[mt][nt], 0, 0, 0);
                acc[mt][nt] = __builtin_amdgcn_mfma_f32_16x16x32_bf16(al[nt], bh[mt], acc[mt][nt], 0, 0, 0);
                acc[mt][nt] = __builtin_amdgcn_mfma_f32_16x16x32_bf16(ah[nt], bl[mt], acc[mt][nt], 0, 0, 0);
            }
        __builtin_amdgcn_s_setprio(0);

        asm volatile("s_waitcnt vmcnt(0)" ::: "memory");
        __builtin_amdgcn_s_barrier();
        __builtin_amdgcn_sched_barrier(0);
    }
}

// ---------------- Kernel 1: QKV projection (split-bf16 MFMA) ----------------
__global__ __launch_bounds__(256)
void qkv_gemm_mfma(const unsigned short* __restrict__ Whi, const unsigned short* __restrict__ Wlo,
                   const unsigned short* __restrict__ Xhi, const unsigned short* __restrict__ Xlo,
                   const float* __restrict__ bias,
                   unsigned short* __restrict__ qhi, unsigned short* __restrict__ qlo,
                   unsigned short* __restrict__ khi, unsigned short* __restrict__ klo,
                   unsigned short* __restrict__ vhi)
{
    __shared__ __align__(16) unsigned short SA[2 * 8192];
    __shared__ __align__(16) unsigned short SB[2 * 8192];
    const v4f zero4 = {0.f, 0.f, 0.f, 0.f};
    v4f acc[4][4];
#pragma unroll
    for (int i = 0; i < 4; ++i)
#pragma unroll
        for (int j = 0; j < 4; ++j) acc[i][j] = zero4;

    const int bm0 = blockIdx.x * 128;
    const int an0 = blockIdx.y * 128;
    splitbf16_mainloop(Whi, Wlo, Xhi, Xlo, an0, bm0, SA, SB, acc);

    const int t = threadIdx.x;
    const int lane = t & 63;
    const int w = t >> 6;
    const int wn = w >> 1, wm = w & 1;
    const int lr = lane & 15, lg = lane >> 4;
    const int nbase = an0 + wn * 64;
    const int mbase = bm0 + wm * 64;

#pragma unroll
    for (int nt = 0; nt < 4; ++nt) {
        const int n0 = nbase + nt * 16 + lg * 4;
        const float4 b4 = *reinterpret_cast<const float4*>(bias + n0);
        const float bv[4] = {b4.x, b4.y, b4.z, b4.w};
        const int tsel = n0 >> 10;
        const int np = n0 & 1023;
        const int hh = np >> 6;
        const int dd = np & 63;
#pragma unroll
        for (int mt = 0; mt < 4; ++mt) {
            const int m = mbase + mt * 16 + lr;
            const int s = m >> 2, b = m & 3;
            float vals[4];
#pragma unroll
            for (int r = 0; r < 4; ++r) vals[r] = acc[mt][nt][r] + bv[r];
            if (tsel == 0) {
                v4us h, l;
#pragma unroll
                for (int r = 0; r < 4; ++r) {
                    float x = vals[r] * QSCALE;
                    unsigned short hi = f2bf(x);
                    h[r] = hi; l[r] = f2bf(x - bf2f(hi));
                }
                size_t base = ((size_t)(b * NH + hh) * S_LEN + s) * HD + dd;
                *reinterpret_cast<v4us*>(qhi + base) = h;
                *reinterpret_cast<v4us*>(qlo + base) = l;
            } else if (tsel == 1) {
                v4us h, l;
#pragma unroll
                for (int r = 0; r < 4; ++r) {
                    unsigned short hi = f2bf(vals[r]);
                    h[r] = hi; l[r] = f2bf(vals[r] - bf2f(hi));
                }
                size_t base = ((size_t)(b * NH + hh) * S_LEN + s) * HD + dd;
                *reinterpret_cast<v4us*>(khi + base) = h;
                *reinterpret_cast<v4us*>(klo + base) = l;
            } else {
#pragma unroll
                for (int r = 0; r < 4; ++r)
                    vhi[((size_t)(b * NH + hh) * HD + dd + r) * S_LEN + s] = f2bf(vals[r]);
            }
        }
    }
}

// ---------------- Kernel 2: flash attention — swapped QK^T, lane-local softmax ----------------
// mfma(K,Q): lane holds S[kv=nt*16+lg*4+r][q=lr] -> row reductions need only
// shfl_xor(16/32); P stored as 8B vectors; PV reads unchanged (P^T == A-frag).
__global__ __launch_bounds__(256, 2)
void attn_kernel(const unsigned short* __restrict__ qhi, const unsigned short* __restrict__ qlo,
                 const unsigned short* __restrict__ khi, const unsigned short* __restrict__ klo,
                 const unsigned short* __restrict__ vhi,
                 unsigned short* __restrict__ avhi, unsigned short* __restrict__ avlo)
{
    __shared__ __align__(16) unsigned short SM[2][12288];  // KH@0 KL@4096 VT@8192
    __shared__ __align__(16) unsigned short PL[4][32][80]; // [wave][q][kv] stride 80

    const int t = threadIdx.x;
    const int lane = t & 63;
    const int w = t >> 6;
    const int lr = lane & 15;
    const int lg = lane >> 4;
    const int id = blockIdx.x;
    const int bh = id & 63;           // same-bh blocks share XCD (64 % 8 == 0)
    const int qt = id >> 6;
    const int b = bh >> 4, h = bh & 15;
    const size_t bh_sd = (size_t)bh * (S_LEN * HD);
    const int q0 = qt * 128 + w * 32;

    v8bf qh[2][2], ql[2][2];
#pragma unroll
    for (int mt = 0; mt < 2; ++mt)
#pragma unroll
        for (int ks = 0; ks < 2; ++ks) {
            size_t off = bh_sd + (size_t)(q0 + mt * 16 + lr) * HD + ks * 32 + lg * 8;
            qh[mt][ks] = *reinterpret_cast<const v8bf*>(qhi + off);
            ql[mt][ks] = *reinterpret_cast<const v8bf*>(qlo + off);
        }

    auto STAGE = [&](int kt, int bf) {
#pragma unroll
        for (int u = 0; u < 6; ++u) {
            int cid = w * 6 + u;
            int pl_ = cid >> 3;
            int n = cid & 7;
            int nt = n >> 1, kn = n & 1;
            const unsigned short* src;
            if (pl_ == 0)
                src = khi + bh_sd + (size_t)(kt * 64 + nt * 16 + lr) * HD + kn * 32 + lg * 8;
            else if (pl_ == 1)
                src = klo + bh_sd + (size_t)(kt * 64 + nt * 16 + lr) * HD + kn * 32 + lg * 8;
            else
                src = vhi + bh_sd + (size_t)(nt * 16 + lr) * S_LEN + kt * 64 + kn * 32 + lg * 8;
            unsigned short* dst = &SM[bf][pl_ * 4096 + n * 512];
            __builtin_amdgcn_global_load_lds(
                (const __attribute__((address_space(1))) unsigned int*)src,
                (__attribute__((address_space(3))) unsigned int*)dst, 16, 0, 0);
        }
    };

    const v4f zero4 = {0.f, 0.f, 0.f, 0.f};
    v4f O[2][4];                     // O[mt][ntd]: row q=mt*16+lg*4+r, col d=ntd*16+lr
    float m_run[2], l_run[2];        // per-lane state for q = mt*16 + lr
#pragma unroll
    for (int mt = 0; mt < 2; ++mt) { m_run[mt] = -1e30f; l_run[mt] = 0.f; }
#pragma unroll
    for (int mt = 0; mt < 2; ++mt)
#pragma unroll
        for (int nt = 0; nt < 4; ++nt) O[mt][nt] = zero4;

    constexpr int NT = S_LEN / 64;

    STAGE(0, 0);
    asm volatile("s_waitcnt vmcnt(0)" ::: "memory");
    __builtin_amdgcn_s_barrier();
    __builtin_amdgcn_sched_barrier(0);

    for (int kt = 0; kt < NT; ++kt) {
        const int cur = kt & 1;
        if (kt + 1 < NT) STAGE(kt + 1, cur ^ 1);

        const unsigned short* KH = &SM[cur][0];
        const unsigned short* KL = &SM[cur][4096];
        const unsigned short* VT = &SM[cur][8192];

        // ---- swapped QK^T: sc[mt][nt][r] = S[kv=nt*16+lg*4+r][q=mt*16+lr] ----
        v4f sc[2][4];
#pragma unroll
        for (int mt = 0; mt < 2; ++mt)
#pragma unroll
            for (int nt = 0; nt < 4; ++nt) sc[mt][nt] = zero4;
        __builtin_amdgcn_s_setprio(1);
#pragma unroll
        for (int ks = 0; ks < 2; ++ks)
#pragma unroll
            for (int nt = 0; nt < 4; ++nt) {
                v8bf kh = *reinterpret_cast<const v8bf*>(KH + (nt * 2 + ks) * 512 + lane * 8);
                v8bf kl = *reinterpret_cast<const v8bf*>(KL + (nt * 2 + ks) * 512 + lane * 8);
#pragma unroll
                for (int mt = 0; mt < 2; ++mt) {
                    sc[mt][nt] = __builtin_amdgcn_mfma_f32_16x16x32_bf16(kh, qh[mt][ks], sc[mt][nt], 0, 0, 0);
                    sc[mt][nt] = __builtin_amdgcn_mfma_f32_16x16x32_bf16(kh, ql[mt][ks], sc[mt][nt], 0, 0, 0);
                    sc[mt][nt] = __builtin_amdgcn_mfma_f32_16x16x32_bf16(kl, qh[mt][ks], sc[mt][nt], 0, 0, 0);
                }
            }
        __builtin_amdgcn_s_setprio(0);

        // ---- softmax: all 64 kv for q=lr live in lanes {lr, lr+16, lr+32, lr+48} ----
        float rm[2];
        bool need = false;
#pragma unroll
        for (int mt = 0; mt < 2; ++mt) {
            float lm = -1e30f;
#pragma unroll
            for (int nt = 0; nt < 4; ++nt)
#pragma unroll
                for (int r = 0; r < 4; ++r) lm = fmaxf(lm, sc[mt][nt][r]);
            lm = fmaxf(lm, __shfl_xor(lm, 16));
            lm = fmaxf(lm, __shfl_xor(lm, 32));
            rm[mt] = lm;
            need = need || (lm > m_run[mt] + 8.0f);
        }
        if (__any(need)) {           // defer-max: rescale only on real max growth
#pragma unroll
            for (int mt = 0; mt < 2; ++mt) {
                float nm = fmaxf(m_run[mt], rm[mt]);
                float alpha = __builtin_amdgcn_exp2f(m_run[mt] - nm);
                m_run[mt] = nm;
                l_run[mt] *= alpha;
                float af[4];
#pragma unroll
                for (int r = 0; r < 4; ++r) af[r] = __shfl(alpha, lg * 4 + r);
#pragma unroll
                for (int nt = 0; nt < 4; ++nt)
#pragma unroll
                    for (int r = 0; r < 4; ++r) O[mt][nt][r] *= af[r];
            }
        }
#pragma unroll
        for (int mt = 0; mt < 2; ++mt) {
            float rs = 0.f;
#pragma unroll
            for (int nt = 0; nt < 4; ++nt) {
                v4us pp;
#pragma unroll
                for (int r = 0; r < 4; ++r) {
                    float p = __builtin_amdgcn_exp2f(sc[mt][nt][r] - m_run[mt]);
                    rs += p;
                    pp[r] = cvt_bf(p);
                }
                *reinterpret_cast<v4us*>(&PL[w][mt * 16 + lr][nt * 16 + lg * 4]) = pp;
            }
            rs += __shfl_xor(rs, 16);
            rs += __shfl_xor(rs, 32);
            l_run[mt] += rs;
        }
        // PL[w] is wave-private: within-wave ds_write -> ds_read needs only lgkmcnt
        asm volatile("s_waitcnt lgkmcnt(0)" ::: "memory");
        __builtin_amdgcn_sched_barrier(0);

        // ---- PV ----
        __builtin_amdgcn_s_setprio(1);
#pragma unroll
        for (int ks = 0; ks < 2; ++ks) {
            v8bf pa[2];
#pragma unroll
            for (int mt = 0; mt < 2; ++mt)
                pa[mt] = *reinterpret_cast<const v8bf*>(&PL[w][mt * 16 + lr][ks * 32 + lg * 8]);
#pragma unroll
            for (int nt = 0; nt < 4; ++nt) {
                v8bf vf = *reinterpret_cast<const v8bf*>(VT + (nt * 2 + ks) * 512 + lane * 8);
#pragma unroll
                for (int mt = 0; mt < 2; ++mt)
                    O[mt][nt] = __builtin_amdgcn_mfma_f32_16x16x32_bf16(pa[mt], vf, O[mt][nt], 0, 0, 0);
            }
        }
        __builtin_amdgcn_s_setprio(0);

        asm volatile("s_waitcnt vmcnt(0)" ::: "memory");
        __builtin_amdgcn_s_barrier();
        __builtin_amdgcn_sched_barrier(0);
    }

    // epilogue: redistribute 1/l via shfl, normalize, split hi/lo bf16
#pragma unroll
    for (int mt = 0; mt < 2; ++mt) {
        float linv = 1.f / l_run[mt];          // valid for q = mt*16 + lr
#pragma unroll
        for (int r = 0; r < 4; ++r) {
            float inv = __shfl(linv, lg * 4 + r);   // for q = mt*16 + lg*4 + r
            int s = q0 + mt * 16 + lg * 4 + r;
            size_t base = (size_t)(b * S_LEN + s) * OUT_DIM + h * HD;
#pragma unroll
            for (int nt = 0; nt < 4; ++nt) {
                float val = O[mt][nt][r] * inv;
                unsigned short hi = f2bf(val);
                avhi[base + nt * 16 + lr] = hi;
                avlo[base + nt * 16 + lr] = f2bf(val - bf2f(hi));
            }
        }
    }
}

// ---------------- Kernel 3: output projection (split-bf16 MFMA) ----------------
__global__ __launch_bounds__(256)
void out_gemm_mfma(const unsigned short* __restrict__ Whi, const unsigned short* __restrict__ Wlo,
                   const unsigned short* __restrict__ Bhi, const unsigned short* __restrict__ Blo,
                   const float* __restrict__ bias, float* __restrict__ out)
{
    __shared__ __align__(16) unsigned short SA[2 * 8192];
    __shared__ __align__(16) unsigned short SB[2 * 8192];
    const v4f zero4 = {0.f, 0.f, 0.f, 0.f};
    v4f acc[4][4];
#pragma unroll
    for (int i = 0; i < 4; ++i)
#pragma unroll
        for (int j = 0; j < 4; ++j) acc[i][j] = zero4;

    const int bm0 = blockIdx.x * 128;
    const int an0 = blockIdx.y * 128;
    splitbf16_mainloop(Whi, Wlo, Bhi, Blo, an0, bm0, SA, SB, acc);

    const int t = threadIdx.x;
    const int lane = t & 63;
    const int w = t >> 6;
    const int wn = w >> 1, wm = w & 1;
    const int lr = lane & 15, lg = lane >> 4;
    const int nbase = an0 + wn * 64;
    const int mbase = bm0 + wm * 64;

#pragma unroll
    for (int nt = 0; nt < 4; ++nt) {
        const int n0 = nbase + nt * 16 + lg * 4;
        const float4 b4 = *reinterpret_cast<const float4*>(bias + n0);
#pragma unroll
        for (int mt = 0; mt < 4; ++mt) {
            const int m = mbase + mt * 16 + lr;
            float4 o = make_float4(acc[mt][nt][0] + b4.x, acc[mt][nt][1] + b4.y,
                                   acc[mt][nt][2] + b4.z, acc[mt][nt][3] + b4.w);
            *reinterpret_cast<float4*>(out + (size_t)m * OUT_DIM + n0) = o;
        }
    }
}

extern "C" void kernel_launch(void* const* d_in, const int* in_sizes, int n_in,
                              void* d_out, int out_size, void* d_ws, size_t ws_size,
                              hipStream_t stream)
{
    const float* x    = (const float*)d_in[0];
    const float* Wqkv = (const float*)d_in[1];
    const float* bqkv = (const float*)d_in[2];
    const float* Wo   = (const float*)d_in[3];
    const float* bo   = (const float*)d_in[4];
    float* out = (float*)d_out;

    unsigned short* p = (unsigned short*)d_ws;
    unsigned short* xhi = p;            p += BHSD;
    unsigned short* xlo = p;            p += BHSD;
    unsigned short* wqh = p;            p += 3 * OUT_DIM * C_DIM;
    unsigned short* wql = p;            p += 3 * OUT_DIM * C_DIM;
    unsigned short* woh = p;            p += OUT_DIM * OUT_DIM;
    unsigned short* wol = p;            p += OUT_DIM * OUT_DIM;
    unsigned short* qhi = p;            p += BHSD;
    unsigned short* qlo = p;            p += BHSD;
    unsigned short* khi = p;            p += BHSD;
    unsigned short* klo = p;            p += BHSD;
    unsigned short* vhi = p;            p += BHSD;
    unsigned short* avhi = xhi;         // x dead after qkv_gemm -> reuse
    unsigned short* avlo = xlo;

    cvt_hl_kernel<<<dim3((int)(BHSD / 4 / 256)), 256, 0, stream>>>(x, xhi, xlo, (int)(BHSD / 4));
    cvt_hl_kernel<<<dim3(3 * OUT_DIM * C_DIM / 4 / 256), 256, 0, stream>>>(Wqkv, wqh, wql, 3 * OUT_DIM * C_DIM / 4);
    cvt_hl_kernel<<<dim3(OUT_DIM * C_DIM / 4 / 256), 256, 0, stream>>>(Wo, woh, wol, OUT_DIM * C_DIM / 4);

    qkv_gemm_mfma<<<dim3(64, 24), 256, 0, stream>>>(wqh, wql, xhi, xlo, bqkv,
                                                    qhi, qlo, khi, klo, vhi);
    attn_kernel<<<dim3(1024), 256, 0, stream>>>(qhi, qlo, khi, klo, vhi, avhi, avlo);
    out_gemm_mfma<<<dim3(64, 8), 256, 0, stream>>>(woh, wol, avhi, avlo, bo, out);
}

// Round 7
// 414.504 us; speedup vs baseline: 5.5299x; 1.1274x over previous
//
#include <hip/hip_runtime.h>
#include <hip/hip_bf16.h>
#include <math.h>

#define S_LEN 2048
#define B_SZ 4
#define NH 16
#define HD 64
#define C_DIM 1024
#define OUT_DIM 1024

static constexpr size_t BHSD = (size_t)B_SZ * NH * S_LEN * HD; // 8,388,608
#define QSCALE 0.18033688011112042f   /* 0.125 * log2(e): scores in log2 domain */

typedef __attribute__((ext_vector_type(8))) short v8bf;
typedef __attribute__((ext_vector_type(4))) float v4f;
typedef __attribute__((ext_vector_type(4))) unsigned short v4us;

__device__ inline unsigned short f2bf(float x) {
    unsigned u = __float_as_uint(x);
    return (unsigned short)((u + 0x7fffu + ((u >> 16) & 1u)) >> 16);  // RNE
}
__device__ inline float bf2f(unsigned short h) {
    return __uint_as_float(((unsigned)h) << 16);
}
__device__ inline unsigned short cvt_bf(float x) {
    __hip_bfloat16 hb = __float2bfloat16(x);
    return reinterpret_cast<unsigned short&>(hb);
}

// ---------------- Kernel 0: f32 -> (hi,lo) bf16 split ----------------
__global__ __launch_bounds__(256)
void cvt_hl_kernel(const float* __restrict__ src, unsigned short* __restrict__ hi,
                   unsigned short* __restrict__ lo, int n4)
{
    int i = blockIdx.x * 256 + threadIdx.x;
    if (i >= n4) return;
    float4 v = reinterpret_cast<const float4*>(src)[i];
    float x[4] = {v.x, v.y, v.z, v.w};
    v4us h, l;
#pragma unroll
    for (int j = 0; j < 4; ++j) {
        unsigned short hh = f2bf(x[j]);
        h[j] = hh;
        l[j] = f2bf(x[j] - bf2f(hh));
    }
    reinterpret_cast<v4us*>(hi)[i] = h;
    reinterpret_cast<v4us*>(lo)[i] = l;
}

// ---------------- split-bf16 MFMA mainloop: 3-stage ring, counted vmcnt ----------------
// Tile: 256 m-rows (B operand) x 128 n-rows (A operand), BK=32, 8 waves (512 thr).
// Wave (wm=w>>1 in [0,4), wn=w&1 in [0,2)) owns 64m x 64n -> acc[4][4].
// LDS ring: 3 buffers. SA buf = 8192 u16 (hi|lo 4096 each); SB buf = 16384 u16.
// Per iter: vmcnt(6) [stage(k) landed, stage(k+1) in flight] -> barrier ->
// issue STAGE(k+2) -> ds_read frags -> 48 MFMA. Loads stay in flight across
// barriers (T4); prefetch distance 2 gives ~2 K-steps of latency slack.
__device__ __forceinline__ void splitbf16_mainloop_r3(
    const unsigned short* __restrict__ Ahi, const unsigned short* __restrict__ Alo,
    const unsigned short* __restrict__ Bhi, const unsigned short* __restrict__ Blo,
    int an0, int bm0, unsigned short* SA, unsigned short* SB, v4f acc[4][4])
{
    constexpr int K = 1024;
    constexpr int NT = K / 32;      // 32 K-steps
    const int t = threadIdx.x;
    const int lane = t & 63;
    const int w = t >> 6;           // 0..7
    const int wm = w >> 1;          // 0..3 (m-group)
    const int wn = w & 1;           // 0..1 (n-group)
    const int lr = lane & 15, lg = lane >> 4;

    auto STAGE = [&](int kt, int bf) {
        const int k0 = kt * 32;
#pragma unroll
        for (int u = 0; u < 6; ++u) {
            int c = w * 6 + u;      // 0..47 chunk id (wave-uniform)
            const unsigned short* src;
            unsigned short* dst;
            if (c < 16) {           // A: 8 rt-subtiles x (hi,lo)
                int rt = c >> 1, par = c & 1;
                src = (par ? Alo : Ahi) + (size_t)(an0 + rt * 16 + lr) * K + k0 + lg * 8;
                dst = SA + bf * 8192 + par * 4096 + rt * 512;
            } else {                // B: 16 rt-subtiles x (hi,lo)
                int cb = c - 16;
                int rt = cb >> 1, par = cb & 1;
                src = (par ? Blo : Bhi) + (size_t)(bm0 + rt * 16 + lr) * K + k0 + lg * 8;
                dst = SB + bf * 16384 + par * 8192 + rt * 512;
            }
            __builtin_amdgcn_global_load_lds(
                (const __attribute__((address_space(1))) unsigned int*)src,
                (__attribute__((address_space(3))) unsigned int*)dst, 16, 0, 0);
        }
    };

    STAGE(0, 0);
    STAGE(1, 1);                    // 12 loads/thread outstanding

    for (int kt = 0; kt < NT; ++kt) {
        const int bf = kt % 3;
        // secure stage(kt): everything older than stage(kt+1) must have landed
        if (kt + 1 < NT) { asm volatile("s_waitcnt vmcnt(6)" ::: "memory"); }
        else             { asm volatile("s_waitcnt vmcnt(0)" ::: "memory"); }
        __builtin_amdgcn_s_barrier();
        __builtin_amdgcn_sched_barrier(0);
        if (kt + 2 < NT) STAGE(kt + 2, (kt + 2) % 3);   // overwrites buf read at kt-1: all readers past barrier

        v8bf ah[4], al[4], bh[4], bl[4];
#pragma unroll
        for (int i = 0; i < 4; ++i) {
            ah[i] = *reinterpret_cast<const v8bf*>(SA + bf * 8192 + (wn * 4 + i) * 512 + lane * 8);
            al[i] = *reinterpret_cast<const v8bf*>(SA + bf * 8192 + 4096 + (wn * 4 + i) * 512 + lane * 8);
            bh[i] = *reinterpret_cast<const v8bf*>(SB + bf * 16384 + (wm * 4 + i) * 512 + lane * 8);
            bl[i] = *reinterpret_cast<const v8bf*>(SB + bf * 16384 + 8192 + (wm * 4 + i) * 512 + lane * 8);
        }
        __builtin_amdgcn_s_setprio(1);
#pragma unroll
        for (int mt = 0; mt < 4; ++mt)
#pragma unroll
            for (int nt = 0; nt < 4; ++nt) {
                acc[mt][nt] = __builtin_amdgcn_mfma_f32_16x16x32_bf16(ah[nt], bh[mt], acc[mt][nt], 0, 0, 0);
                acc[mt][nt] = __builtin_amdgcn_mfma_f32_16x16x32_bf16(al[nt], bh[mt], acc[mt][nt], 0, 0, 0);
                acc[mt][nt] = __builtin_amdgcn_mfma_f32_16x16x32_bf16(ah[nt], bl[mt], acc[mt][nt], 0, 0, 0);
            }
        __builtin_amdgcn_s_setprio(0);
    }
}

// ---------------- Kernel 1: QKV projection (split-bf16 MFMA, ring pipeline) ----------------
__global__ __launch_bounds__(512, 1)
void qkv_gemm_mfma(const unsigned short* __restrict__ Whi, const unsigned short* __restrict__ Wlo,
                   const unsigned short* __restrict__ Xhi, const unsigned short* __restrict__ Xlo,
                   const float* __restrict__ bias,
                   unsigned short* __restrict__ qhi, unsigned short* __restrict__ qlo,
                   unsigned short* __restrict__ khi, unsigned short* __restrict__ klo,
                   unsigned short* __restrict__ vhi)
{
    __shared__ __align__(16) unsigned short SA[3 * 8192];    // 48 KB
    __shared__ __align__(16) unsigned short SB[3 * 16384];   // 96 KB
    const v4f zero4 = {0.f, 0.f, 0.f, 0.f};
    v4f acc[4][4];
#pragma unroll
    for (int i = 0; i < 4; ++i)
#pragma unroll
        for (int j = 0; j < 4; ++j) acc[i][j] = zero4;

    const int bm0 = blockIdx.x * 256;
    const int an0 = blockIdx.y * 128;
    splitbf16_mainloop_r3(Whi, Wlo, Xhi, Xlo, an0, bm0, SA, SB, acc);

    const int t = threadIdx.x;
    const int lane = t & 63;
    const int w = t >> 6;
    const int wm = w >> 1, wn = w & 1;
    const int lr = lane & 15, lg = lane >> 4;
    const int nbase = an0 + wn * 64;
    const int mbase = bm0 + wm * 64;

#pragma unroll
    for (int nt = 0; nt < 4; ++nt) {
        const int n0 = nbase + nt * 16 + lg * 4;
        const float4 b4 = *reinterpret_cast<const float4*>(bias + n0);
        const float bv[4] = {b4.x, b4.y, b4.z, b4.w};
        const int tsel = n0 >> 10;
        const int np = n0 & 1023;
        const int hh = np >> 6;
        const int dd = np & 63;
#pragma unroll
        for (int mt = 0; mt < 4; ++mt) {
            const int m = mbase + mt * 16 + lr;
            const int s = m >> 2, b = m & 3;
            float vals[4];
#pragma unroll
            for (int r = 0; r < 4; ++r) vals[r] = acc[mt][nt][r] + bv[r];
            if (tsel == 0) {
                v4us h, l;
#pragma unroll
                for (int r = 0; r < 4; ++r) {
                    float x = vals[r] * QSCALE;
                    unsigned short hi = f2bf(x);
                    h[r] = hi; l[r] = f2bf(x - bf2f(hi));
                }
                size_t base = ((size_t)(b * NH + hh) * S_LEN + s) * HD + dd;
                *reinterpret_cast<v4us*>(qhi + base) = h;
                *reinterpret_cast<v4us*>(qlo + base) = l;
            } else if (tsel == 1) {
                v4us h, l;
#pragma unroll
                for (int r = 0; r < 4; ++r) {
                    unsigned short hi = f2bf(vals[r]);
                    h[r] = hi; l[r] = f2bf(vals[r] - bf2f(hi));
                }
                size_t base = ((size_t)(b * NH + hh) * S_LEN + s) * HD + dd;
                *reinterpret_cast<v4us*>(khi + base) = h;
                *reinterpret_cast<v4us*>(klo + base) = l;
            } else {
#pragma unroll
                for (int r = 0; r < 4; ++r)
                    vhi[((size_t)(b * NH + hh) * HD + dd + r) * S_LEN + s] = f2bf(vals[r]);
            }
        }
    }
}

// ---------------- Kernel 2: flash attention — swapped QK^T, lane-local softmax ----------------
__global__ __launch_bounds__(256, 2)
void attn_kernel(const unsigned short* __restrict__ qhi, const unsigned short* __restrict__ qlo,
                 const unsigned short* __restrict__ khi, const unsigned short* __restrict__ klo,
                 const unsigned short* __restrict__ vhi,
                 unsigned short* __restrict__ avhi, unsigned short* __restrict__ avlo)
{
    __shared__ __align__(16) unsigned short SM[2][12288];  // KH@0 KL@4096 VT@8192
    __shared__ __align__(16) unsigned short PL[4][32][80]; // [wave][q][kv] stride 80

    const int t = threadIdx.x;
    const int lane = t & 63;
    const int w = t >> 6;
    const int lr = lane & 15;
    const int lg = lane >> 4;
    const int id = blockIdx.x;
    const int bh = id & 63;           // same-bh blocks share XCD (64 % 8 == 0)
    const int qt = id >> 6;
    const int b = bh >> 4, h = bh & 15;
    const size_t bh_sd = (size_t)bh * (S_LEN * HD);
    const int q0 = qt * 128 + w * 32;

    v8bf qh[2][2], ql[2][2];
#pragma unroll
    for (int mt = 0; mt < 2; ++mt)
#pragma unroll
        for (int ks = 0; ks < 2; ++ks) {
            size_t off = bh_sd + (size_t)(q0 + mt * 16 + lr) * HD + ks * 32 + lg * 8;
            qh[mt][ks] = *reinterpret_cast<const v8bf*>(qhi + off);
            ql[mt][ks] = *reinterpret_cast<const v8bf*>(qlo + off);
        }

    auto STAGE = [&](int kt, int bf) {
#pragma unroll
        for (int u = 0; u < 6; ++u) {
            int cid = w * 6 + u;
            int pl_ = cid >> 3;
            int n = cid & 7;
            int nt = n >> 1, kn = n & 1;
            const unsigned short* src;
            if (pl_ == 0)
                src = khi + bh_sd + (size_t)(kt * 64 + nt * 16 + lr) * HD + kn * 32 + lg * 8;
            else if (pl_ == 1)
                src = klo + bh_sd + (size_t)(kt * 64 + nt * 16 + lr) * HD + kn * 32 + lg * 8;
            else
                src = vhi + bh_sd + (size_t)(nt * 16 + lr) * S_LEN + kt * 64 + kn * 32 + lg * 8;
            unsigned short* dst = &SM[bf][pl_ * 4096 + n * 512];
            __builtin_amdgcn_global_load_lds(
                (const __attribute__((address_space(1))) unsigned int*)src,
                (__attribute__((address_space(3))) unsigned int*)dst, 16, 0, 0);
        }
    };

    const v4f zero4 = {0.f, 0.f, 0.f, 0.f};
    v4f O[2][4];                     // O[mt][ntd]: row q=mt*16+lg*4+r, col d=ntd*16+lr
    float m_run[2], l_run[2];        // per-lane state for q = mt*16 + lr
#pragma unroll
    for (int mt = 0; mt < 2; ++mt) { m_run[mt] = -1e30f; l_run[mt] = 0.f; }
#pragma unroll
    for (int mt = 0; mt < 2; ++mt)
#pragma unroll
        for (int nt = 0; nt < 4; ++nt) O[mt][nt] = zero4;

    constexpr int NT = S_LEN / 64;

    STAGE(0, 0);
    asm volatile("s_waitcnt vmcnt(0)" ::: "memory");
    __builtin_amdgcn_s_barrier();
    __builtin_amdgcn_sched_barrier(0);

    for (int kt = 0; kt < NT; ++kt) {
        const int cur = kt & 1;
        if (kt + 1 < NT) STAGE(kt + 1, cur ^ 1);

        const unsigned short* KH = &SM[cur][0];
        const unsigned short* KL = &SM[cur][4096];
        const unsigned short* VT = &SM[cur][8192];

        // ---- swapped QK^T: sc[mt][nt][r] = S[kv=nt*16+lg*4+r][q=mt*16+lr] ----
        v4f sc[2][4];
#pragma unroll
        for (int mt = 0; mt < 2; ++mt)
#pragma unroll
            for (int nt = 0; nt < 4; ++nt) sc[mt][nt] = zero4;
        __builtin_amdgcn_s_setprio(1);
#pragma unroll
        for (int ks = 0; ks < 2; ++ks)
#pragma unroll
            for (int nt = 0; nt < 4; ++nt) {
                v8bf kh = *reinterpret_cast<const v8bf*>(KH + (nt * 2 + ks) * 512 + lane * 8);
                v8bf kl = *reinterpret_cast<const v8bf*>(KL + (nt * 2 + ks) * 512 + lane * 8);
#pragma unroll
                for (int mt = 0; mt < 2; ++mt) {
                    sc[mt][nt] = __builtin_amdgcn_mfma_f32_16x16x32_bf16(kh, qh[mt][ks], sc[mt][nt], 0, 0, 0);
                    sc[mt][nt] = __builtin_amdgcn_mfma_f32_16x16x32_bf16(kh, ql[mt][ks], sc[mt][nt], 0, 0, 0);
                    sc[mt][nt] = __builtin_amdgcn_mfma_f32_16x16x32_bf16(kl, qh[mt][ks], sc[mt][nt], 0, 0, 0);
                }
            }
        __builtin_amdgcn_s_setprio(0);

        // ---- softmax: all 64 kv for q=lr live in lanes {lr, lr+16, lr+32, lr+48} ----
        float rm[2];
        bool need = false;
#pragma unroll
        for (int mt = 0; mt < 2; ++mt) {
            float lm = -1e30f;
#pragma unroll
            for (int nt = 0; nt < 4; ++nt)
#pragma unroll
                for (int r = 0; r < 4; ++r) lm = fmaxf(lm, sc[mt][nt][r]);
            lm = fmaxf(lm, __shfl_xor(lm, 16));
            lm = fmaxf(lm, __shfl_xor(lm, 32));
            rm[mt] = lm;
            need = need || (lm > m_run[mt] + 8.0f);
        }
        if (__any(need)) {           // defer-max: rescale only on real max growth
#pragma unroll
            for (int mt = 0; mt < 2; ++mt) {
                float nm = fmaxf(m_run[mt], rm[mt]);
                float alpha = __builtin_amdgcn_exp2f(m_run[mt] - nm);
                m_run[mt] = nm;
                l_run[mt] *= alpha;
                float af[4];
#pragma unroll
                for (int r = 0; r < 4; ++r) af[r] = __shfl(alpha, lg * 4 + r);
#pragma unroll
                for (int nt = 0; nt < 4; ++nt)
#pragma unroll
                    for (int r = 0; r < 4; ++r) O[mt][nt][r] *= af[r];
            }
        }
#pragma unroll
        for (int mt = 0; mt < 2; ++mt) {
            float rs = 0.f;
#pragma unroll
            for (int nt = 0; nt < 4; ++nt) {
                v4us pp;
#pragma unroll
                for (int r = 0; r < 4; ++r) {
                    float p = __builtin_amdgcn_exp2f(sc[mt][nt][r] - m_run[mt]);
                    rs += p;
                    pp[r] = cvt_bf(p);
                }
                *reinterpret_cast<v4us*>(&PL[w][mt * 16 + lr][nt * 16 + lg * 4]) = pp;
            }
            rs += __shfl_xor(rs, 16);
            rs += __shfl_xor(rs, 32);
            l_run[mt] += rs;
        }
        // PL[w] is wave-private: within-wave ds_write -> ds_read needs only lgkmcnt
        asm volatile("s_waitcnt lgkmcnt(0)" ::: "memory");
        __builtin_amdgcn_sched_barrier(0);

        // ---- PV ----
        __builtin_amdgcn_s_setprio(1);
#pragma unroll
        for (int ks = 0; ks < 2; ++ks) {
            v8bf pa[2];
#pragma unroll
            for (int mt = 0; mt < 2; ++mt)
                pa[mt] = *reinterpret_cast<const v8bf*>(&PL[w][mt * 16 + lr][ks * 32 + lg * 8]);
#pragma unroll
            for (int nt = 0; nt < 4; ++nt) {
                v8bf vf = *reinterpret_cast<const v8bf*>(VT + (nt * 2 + ks) * 512 + lane * 8);
#pragma unroll
                for (int mt = 0; mt < 2; ++mt)
                    O[mt][nt] = __builtin_amdgcn_mfma_f32_16x16x32_bf16(pa[mt], vf, O[mt][nt], 0, 0, 0);
            }
        }
        __builtin_amdgcn_s_setprio(0);

        asm volatile("s_waitcnt vmcnt(0)" ::: "memory");
        __builtin_amdgcn_s_barrier();
        __builtin_amdgcn_sched_barrier(0);
    }

    // epilogue: redistribute 1/l via shfl, normalize, split hi/lo bf16
#pragma unroll
    for (int mt = 0; mt < 2; ++mt) {
        float linv = 1.f / l_run[mt];          // valid for q = mt*16 + lr
#pragma unroll
        for (int r = 0; r < 4; ++r) {
            float inv = __shfl(linv, lg * 4 + r);   // for q = mt*16 + lg*4 + r
            int s = q0 + mt * 16 + lg * 4 + r;
            size_t base = (size_t)(b * S_LEN + s) * OUT_DIM + h * HD;
#pragma unroll
            for (int nt = 0; nt < 4; ++nt) {
                float val = O[mt][nt][r] * inv;
                unsigned short hi = f2bf(val);
                avhi[base + nt * 16 + lr] = hi;
                avlo[base + nt * 16 + lr] = f2bf(val - bf2f(hi));
            }
        }
    }
}

// ---------------- Kernel 3: output projection (split-bf16 MFMA, ring pipeline) ----------------
__global__ __launch_bounds__(512, 1)
void out_gemm_mfma(const unsigned short* __restrict__ Whi, const unsigned short* __restrict__ Wlo,
                   const unsigned short* __restrict__ Bhi, const unsigned short* __restrict__ Blo,
                   const float* __restrict__ bias, float* __restrict__ out)
{
    __shared__ __align__(16) unsigned short SA[3 * 8192];
    __shared__ __align__(16) unsigned short SB[3 * 16384];
    const v4f zero4 = {0.f, 0.f, 0.f, 0.f};
    v4f acc[4][4];
#pragma unroll
    for (int i = 0; i < 4; ++i)
#pragma unroll
        for (int j = 0; j < 4; ++j) acc[i][j] = zero4;

    const int bm0 = blockIdx.x * 256;
    const int an0 = blockIdx.y * 128;
    splitbf16_mainloop_r3(Whi, Wlo, Bhi, Blo, an0, bm0, SA, SB, acc);

    const int t = threadIdx.x;
    const int lane = t & 63;
    const int w = t >> 6;
    const int wm = w >> 1, wn = w & 1;
    const int lr = lane & 15, lg = lane >> 4;
    const int nbase = an0 + wn * 64;
    const int mbase = bm0 + wm * 64;

#pragma unroll
    for (int nt = 0; nt < 4; ++nt) {
        const int n0 = nbase + nt * 16 + lg * 4;
        const float4 b4 = *reinterpret_cast<const float4*>(bias + n0);
#pragma unroll
        for (int mt = 0; mt < 4; ++mt) {
            const int m = mbase + mt * 16 + lr;
            float4 o = make_float4(acc[mt][nt][0] + b4.x, acc[mt][nt][1] + b4.y,
                                   acc[mt][nt][2] + b4.z, acc[mt][nt][3] + b4.w);
            *reinterpret_cast<float4*>(out + (size_t)m * OUT_DIM + n0) = o;
        }
    }
}

extern "C" void kernel_launch(void* const* d_in, const int* in_sizes, int n_in,
                              void* d_out, int out_size, void* d_ws, size_t ws_size,
                              hipStream_t stream)
{
    const float* x    = (const float*)d_in[0];
    const float* Wqkv = (const float*)d_in[1];
    const float* bqkv = (const float*)d_in[2];
    const float* Wo   = (const float*)d_in[3];
    const float* bo   = (const float*)d_in[4];
    float* out = (float*)d_out;

    unsigned short* p = (unsigned short*)d_ws;
    unsigned short* xhi = p;            p += BHSD;
    unsigned short* xlo = p;            p += BHSD;
    unsigned short* wqh = p;            p += 3 * OUT_DIM * C_DIM;
    unsigned short* wql = p;            p += 3 * OUT_DIM * C_DIM;
    unsigned short* woh = p;            p += OUT_DIM * OUT_DIM;
    unsigned short* wol = p;            p += OUT_DIM * OUT_DIM;
    unsigned short* qhi = p;            p += BHSD;
    unsigned short* qlo = p;            p += BHSD;
    unsigned short* khi = p;            p += BHSD;
    unsigned short* klo = p;            p += BHSD;
    unsigned short* vhi = p;            p += BHSD;
    unsigned short* avhi = xhi;         // x dead after qkv_gemm -> reuse
    unsigned short* avlo = xlo;

    cvt_hl_kernel<<<dim3((int)(BHSD / 4 / 256)), 256, 0, stream>>>(x, xhi, xlo, (int)(BHSD / 4));
    cvt_hl_kernel<<<dim3(3 * OUT_DIM * C_DIM / 4 / 256), 256, 0, stream>>>(Wqkv, wqh, wql, 3 * OUT_DIM * C_DIM / 4);
    cvt_hl_kernel<<<dim3(OUT_DIM * C_DIM / 4 / 256), 256, 0, stream>>>(Wo, woh, wol, OUT_DIM * C_DIM / 4);

    qkv_gemm_mfma<<<dim3(32, 24), 512, 0, stream>>>(wqh, wql, xhi, xlo, bqkv,
                                                    qhi, qlo, khi, klo, vhi);
    attn_kernel<<<dim3(1024), 256, 0, stream>>>(qhi, qlo, khi, klo, vhi, avhi, avlo);
    out_gemm_mfma<<<dim3(32, 8), 512, 0, stream>>>(woh, wol, avhi, avlo, bo, out);
}

// Round 8
// 403.911 us; speedup vs baseline: 5.6749x; 1.0262x over previous
//
#include <hip/hip_runtime.h>
#include <hip/hip_bf16.h>
#include <math.h>

#define S_LEN 2048
#define B_SZ 4
#define NH 16
#define HD 64
#define C_DIM 1024
#define OUT_DIM 1024

static constexpr size_t BHSD = (size_t)B_SZ * NH * S_LEN * HD; // 8,388,608
#define QSCALE 0.18033688011112042f   /* 0.125 * log2(e): scores in log2 domain */

typedef __attribute__((ext_vector_type(8))) short v8bf;
typedef __attribute__((ext_vector_type(4))) float v4f;
typedef __attribute__((ext_vector_type(4))) unsigned short v4us;

__device__ inline unsigned short f2bf(float x) {
    unsigned u = __float_as_uint(x);
    return (unsigned short)((u + 0x7fffu + ((u >> 16) & 1u)) >> 16);  // RNE
}
__device__ inline float bf2f(unsigned short h) {
    return __uint_as_float(((unsigned)h) << 16);
}
__device__ inline unsigned short cvt_bf(float x) {
    __hip_bfloat16 hb = __float2bfloat16(x);
    return reinterpret_cast<unsigned short&>(hb);
}

// ---------------- Kernel 0: f32 -> (hi,lo) bf16 split ----------------
__global__ __launch_bounds__(256)
void cvt_hl_kernel(const float* __restrict__ src, unsigned short* __restrict__ hi,
                   unsigned short* __restrict__ lo, int n4)
{
    int i = blockIdx.x * 256 + threadIdx.x;
    if (i >= n4) return;
    float4 v = reinterpret_cast<const float4*>(src)[i];
    float x[4] = {v.x, v.y, v.z, v.w};
    v4us h, l;
#pragma unroll
    for (int j = 0; j < 4; ++j) {
        unsigned short hh = f2bf(x[j]);
        h[j] = hh;
        l[j] = f2bf(x[j] - bf2f(hh));
    }
    reinterpret_cast<v4us*>(hi)[i] = h;
    reinterpret_cast<v4us*>(lo)[i] = l;
}

// ---------------- split-bf16 MFMA mainloop: ring-3, counted vmcnt, 4-quadrant interleave ----------------
// Tile 256m x 128n, BK=32, 8 waves, wave = 64m x 64n (wm=w>>1, wn=w&1), acc[4][4].
// TERMS=3: hh+lh+hl (full split).  TERMS=2: hh+lh (B-lo never staged/read) — for V.
// Per K-step: one {vmcnt(N); barrier} then 4 quadrant phases, each {read next B-frags
// || issue staging chunks || setprio+12(or 8) MFMA}. Reads for q+1 hide under q's MFMA;
// single barrier lets the 2 waves/SIMD skew so reads overlap the other wave's MFMA.
template <int TERMS>
__device__ __forceinline__ void splitbf16_mainloop_r3(
    const unsigned short* __restrict__ Ahi, const unsigned short* __restrict__ Alo,
    const unsigned short* __restrict__ Bhi, const unsigned short* __restrict__ Blo,
    int an0, int bm0, unsigned short* SA, unsigned short* SB, v4f acc[4][4])
{
    constexpr int K = 1024;
    constexpr int NT = K / 32;           // 32 K-steps
    constexpr int NS = (TERMS == 3) ? 6 : 4;   // staged 1KB chunks per wave per K-step
    const int t = threadIdx.x;
    const int lane = t & 63;
    const int w = t >> 6;                // 0..7
    const int wm = w >> 1;               // 0..3
    const int wn = w & 1;                // 0..1
    const int lr = lane & 15, lg = lane >> 4;

    auto CHUNK = [&](int kt, int bf, int u) {
        const int k0 = kt * 32;
        const int c = w * NS + u;        // wave-uniform chunk id
        const unsigned short* src;
        unsigned short* dst;
        if (c < 16) {                    // A: 8 rt-subtiles x (hi,lo)
            int rt = c >> 1, par = c & 1;
            src = (par ? Alo : Ahi) + (size_t)(an0 + rt * 16 + lr) * K + k0 + lg * 8;
            dst = SA + bf * 8192 + par * 4096 + rt * 512;
        } else if (TERMS == 3) {         // B: 16 rt-subtiles x (hi,lo)
            int cb = c - 16, rt = cb >> 1, par = cb & 1;
            src = (par ? Blo : Bhi) + (size_t)(bm0 + rt * 16 + lr) * K + k0 + lg * 8;
            dst = SB + bf * 16384 + par * 8192 + rt * 512;
        } else {                         // B: 16 rt-subtiles, hi only
            int rt = c - 16;
            src = Bhi + (size_t)(bm0 + rt * 16 + lr) * K + k0 + lg * 8;
            dst = SB + bf * 16384 + rt * 512;
        }
        __builtin_amdgcn_global_load_lds(
            (const __attribute__((address_space(1))) unsigned int*)src,
            (__attribute__((address_space(3))) unsigned int*)dst, 16, 0, 0);
    };
    auto STAGE_ALL = [&](int kt, int bf) {
#pragma unroll
        for (int u = 0; u < NS; ++u) CHUNK(kt, bf, u);
    };

    STAGE_ALL(0, 0);
    STAGE_ALL(1, 1);

    for (int kt = 0; kt < NT; ++kt) {
        const int bf = kt % 3;
        if (kt + 1 < NT) {
            if (TERMS == 3) { asm volatile("s_waitcnt vmcnt(6)" ::: "memory"); }
            else            { asm volatile("s_waitcnt vmcnt(4)" ::: "memory"); }
        } else {
            asm volatile("s_waitcnt vmcnt(0)" ::: "memory");
        }
        __builtin_amdgcn_s_barrier();
        __builtin_amdgcn_sched_barrier(0);

        const unsigned short* sa = SA + bf * 8192;
        const unsigned short* sb = SB + bf * 16384;
        const bool pf = (kt + 2 < NT);
        const int bf2 = (kt + 2) % 3;

        v8bf ah[4], al[4], bh[4], bl[4];
#pragma unroll
        for (int i = 0; i < 4; ++i) {
            ah[i] = *reinterpret_cast<const v8bf*>(sa + (wn * 4 + i) * 512 + lane * 8);
            al[i] = *reinterpret_cast<const v8bf*>(sa + 4096 + (wn * 4 + i) * 512 + lane * 8);
        }
        bh[0] = *reinterpret_cast<const v8bf*>(sb + (wm * 4) * 512 + lane * 8);
        if (TERMS == 3)
            bl[0] = *reinterpret_cast<const v8bf*>(sb + 8192 + (wm * 4) * 512 + lane * 8);

#pragma unroll
        for (int q = 0; q < 4; ++q) {
            if (q < 3) {                 // read-ahead next quadrant's B-frags
                bh[q + 1] = *reinterpret_cast<const v8bf*>(sb + (wm * 4 + q + 1) * 512 + lane * 8);
                if (TERMS == 3)
                    bl[q + 1] = *reinterpret_cast<const v8bf*>(sb + 8192 + (wm * 4 + q + 1) * 512 + lane * 8);
            }
            if (q > 0 && pf) {           // spread staging issues across quadrants
                if (TERMS == 3) { CHUNK(kt + 2, bf2, 2 * (q - 1)); CHUNK(kt + 2, bf2, 2 * (q - 1) + 1); }
                else {
                    if (q == 1) { CHUNK(kt + 2, bf2, 0); CHUNK(kt + 2, bf2, 1); }
                    else        { CHUNK(kt + 2, bf2, q); }
                }
            }
            __builtin_amdgcn_s_setprio(1);
#pragma unroll
            for (int nt = 0; nt < 4; ++nt)
                acc[q][nt] = __builtin_amdgcn_mfma_f32_16x16x32_bf16(ah[nt], bh[q], acc[q][nt], 0, 0, 0);
#pragma unroll
            for (int nt = 0; nt < 4; ++nt)
                acc[q][nt] = __builtin_amdgcn_mfma_f32_16x16x32_bf16(al[nt], bh[q], acc[q][nt], 0, 0, 0);
            if (TERMS == 3) {
#pragma unroll
                for (int nt = 0; nt < 4; ++nt)
                    acc[q][nt] = __builtin_amdgcn_mfma_f32_16x16x32_bf16(ah[nt], bl[q], acc[q][nt], 0, 0, 0);
            }
            __builtin_amdgcn_s_setprio(0);
        }
    }
}

// ---------------- Kernel 1: QKV projection (split-bf16 MFMA, ring pipeline) ----------------
template <int TERMS>
__global__ __launch_bounds__(512, 2)
void qkv_gemm_mfma(const unsigned short* __restrict__ Whi, const unsigned short* __restrict__ Wlo,
                   const unsigned short* __restrict__ Xhi, const unsigned short* __restrict__ Xlo,
                   const float* __restrict__ bias,
                   unsigned short* __restrict__ qhi, unsigned short* __restrict__ qlo,
                   unsigned short* __restrict__ khi, unsigned short* __restrict__ klo,
                   unsigned short* __restrict__ vhi, int an_base)
{
    __shared__ __align__(16) unsigned short SA[3 * 8192];    // 48 KB
    __shared__ __align__(16) unsigned short SB[3 * 16384];   // 96 KB
    const v4f zero4 = {0.f, 0.f, 0.f, 0.f};
    v4f acc[4][4];
#pragma unroll
    for (int i = 0; i < 4; ++i)
#pragma unroll
        for (int j = 0; j < 4; ++j) acc[i][j] = zero4;

    const int bm0 = blockIdx.x * 256;
    const int an0 = an_base + blockIdx.y * 128;
    splitbf16_mainloop_r3<TERMS>(Whi, Wlo, Xhi, Xlo, an0, bm0, SA, SB, acc);

    const int t = threadIdx.x;
    const int lane = t & 63;
    const int w = t >> 6;
    const int wm = w >> 1, wn = w & 1;
    const int lr = lane & 15, lg = lane >> 4;
    const int nbase = an0 + wn * 64;
    const int mbase = bm0 + wm * 64;

#pragma unroll
    for (int nt = 0; nt < 4; ++nt) {
        const int n0 = nbase + nt * 16 + lg * 4;
        const float4 b4 = *reinterpret_cast<const float4*>(bias + n0);
        const float bv[4] = {b4.x, b4.y, b4.z, b4.w};
        const int tsel = n0 >> 10;
        const int np = n0 & 1023;
        const int hh = np >> 6;
        const int dd = np & 63;
#pragma unroll
        for (int mt = 0; mt < 4; ++mt) {
            const int m = mbase + mt * 16 + lr;
            const int s = m >> 2, b = m & 3;
            float vals[4];
#pragma unroll
            for (int r = 0; r < 4; ++r) vals[r] = acc[mt][nt][r] + bv[r];
            if (tsel == 0) {
                v4us h, l;
#pragma unroll
                for (int r = 0; r < 4; ++r) {
                    float x = vals[r] * QSCALE;
                    unsigned short hi = f2bf(x);
                    h[r] = hi; l[r] = f2bf(x - bf2f(hi));
                }
                size_t base = ((size_t)(b * NH + hh) * S_LEN + s) * HD + dd;
                *reinterpret_cast<v4us*>(qhi + base) = h;
                *reinterpret_cast<v4us*>(qlo + base) = l;
            } else if (tsel == 1) {
                v4us h, l;
#pragma unroll
                for (int r = 0; r < 4; ++r) {
                    unsigned short hi = f2bf(vals[r]);
                    h[r] = hi; l[r] = f2bf(vals[r] - bf2f(hi));
                }
                size_t base = ((size_t)(b * NH + hh) * S_LEN + s) * HD + dd;
                *reinterpret_cast<v4us*>(khi + base) = h;
                *reinterpret_cast<v4us*>(klo + base) = l;
            } else {
#pragma unroll
                for (int r = 0; r < 4; ++r)
                    vhi[((size_t)(b * NH + hh) * HD + dd + r) * S_LEN + s] = f2bf(vals[r]);
            }
        }
    }
}

// ---------------- Kernel 2: flash attention — swapped QK^T, lane-local softmax ----------------
__global__ __launch_bounds__(256, 2)
void attn_kernel(const unsigned short* __restrict__ qhi, const unsigned short* __restrict__ qlo,
                 const unsigned short* __restrict__ khi, const unsigned short* __restrict__ klo,
                 const unsigned short* __restrict__ vhi,
                 unsigned short* __restrict__ avhi, unsigned short* __restrict__ avlo)
{
    __shared__ __align__(16) unsigned short SM[2][12288];  // KH@0 KL@4096 VT@8192
    __shared__ __align__(16) unsigned short PL[4][32][80]; // [wave][q][kv] stride 80

    const int t = threadIdx.x;
    const int lane = t & 63;
    const int w = t >> 6;
    const int lr = lane & 15;
    const int lg = lane >> 4;
    const int id = blockIdx.x;
    const int bh = id & 63;           // same-bh blocks share XCD (64 % 8 == 0)
    const int qt = id >> 6;
    const int b = bh >> 4, h = bh & 15;
    const size_t bh_sd = (size_t)bh * (S_LEN * HD);
    const int q0 = qt * 128 + w * 32;

    v8bf qh[2][2], ql[2][2];
#pragma unroll
    for (int mt = 0; mt < 2; ++mt)
#pragma unroll
        for (int ks = 0; ks < 2; ++ks) {
            size_t off = bh_sd + (size_t)(q0 + mt * 16 + lr) * HD + ks * 32 + lg * 8;
            qh[mt][ks] = *reinterpret_cast<const v8bf*>(qhi + off);
            ql[mt][ks] = *reinterpret_cast<const v8bf*>(qlo + off);
        }

    auto STAGE = [&](int kt, int bf) {
#pragma unroll
        for (int u = 0; u < 6; ++u) {
            int cid = w * 6 + u;
            int pl_ = cid >> 3;
            int n = cid & 7;
            int nt = n >> 1, kn = n & 1;
            const unsigned short* src;
            if (pl_ == 0)
                src = khi + bh_sd + (size_t)(kt * 64 + nt * 16 + lr) * HD + kn * 32 + lg * 8;
            else if (pl_ == 1)
                src = klo + bh_sd + (size_t)(kt * 64 + nt * 16 + lr) * HD + kn * 32 + lg * 8;
            else
                src = vhi + bh_sd + (size_t)(nt * 16 + lr) * S_LEN + kt * 64 + kn * 32 + lg * 8;
            unsigned short* dst = &SM[bf][pl_ * 4096 + n * 512];
            __builtin_amdgcn_global_load_lds(
                (const __attribute__((address_space(1))) unsigned int*)src,
                (__attribute__((address_space(3))) unsigned int*)dst, 16, 0, 0);
        }
    };

    const v4f zero4 = {0.f, 0.f, 0.f, 0.f};
    v4f O[2][4];                     // O[mt][ntd]: row q=mt*16+lg*4+r, col d=ntd*16+lr
    float m_run[2], l_run[2];        // per-lane state for q = mt*16 + lr
#pragma unroll
    for (int mt = 0; mt < 2; ++mt) { m_run[mt] = -1e30f; l_run[mt] = 0.f; }
#pragma unroll
    for (int mt = 0; mt < 2; ++mt)
#pragma unroll
        for (int nt = 0; nt < 4; ++nt) O[mt][nt] = zero4;

    constexpr int NT = S_LEN / 64;

    STAGE(0, 0);
    asm volatile("s_waitcnt vmcnt(0)" ::: "memory");
    __builtin_amdgcn_s_barrier();
    __builtin_amdgcn_sched_barrier(0);

    for (int kt = 0; kt < NT; ++kt) {
        const int cur = kt & 1;
        if (kt + 1 < NT) STAGE(kt + 1, cur ^ 1);

        const unsigned short* KH = &SM[cur][0];
        const unsigned short* KL = &SM[cur][4096];
        const unsigned short* VT = &SM[cur][8192];

        // ---- swapped QK^T: sc[mt][nt][r] = S[kv=nt*16+lg*4+r][q=mt*16+lr] ----
        v4f sc[2][4];
#pragma unroll
        for (int mt = 0; mt < 2; ++mt)
#pragma unroll
            for (int nt = 0; nt < 4; ++nt) sc[mt][nt] = zero4;
        __builtin_amdgcn_s_setprio(1);
#pragma unroll
        for (int ks = 0; ks < 2; ++ks)
#pragma unroll
            for (int nt = 0; nt < 4; ++nt) {
                v8bf kh = *reinterpret_cast<const v8bf*>(KH + (nt * 2 + ks) * 512 + lane * 8);
                v8bf kl = *reinterpret_cast<const v8bf*>(KL + (nt * 2 + ks) * 512 + lane * 8);
#pragma unroll
                for (int mt = 0; mt < 2; ++mt) {
                    sc[mt][nt] = __builtin_amdgcn_mfma_f32_16x16x32_bf16(kh, qh[mt][ks], sc[mt][nt], 0, 0, 0);
                    sc[mt][nt] = __builtin_amdgcn_mfma_f32_16x16x32_bf16(kh, ql[mt][ks], sc[mt][nt], 0, 0, 0);
                    sc[mt][nt] = __builtin_amdgcn_mfma_f32_16x16x32_bf16(kl, qh[mt][ks], sc[mt][nt], 0, 0, 0);
                }
            }
        __builtin_amdgcn_s_setprio(0);

        // ---- softmax: all 64 kv for q=lr live in lanes {lr, lr+16, lr+32, lr+48} ----
        float rm[2];
        bool need = false;
#pragma unroll
        for (int mt = 0; mt < 2; ++mt) {
            float lm = -1e30f;
#pragma unroll
            for (int nt = 0; nt < 4; ++nt)
#pragma unroll
                for (int r = 0; r < 4; ++r) lm = fmaxf(lm, sc[mt][nt][r]);
            lm = fmaxf(lm, __shfl_xor(lm, 16));
            lm = fmaxf(lm, __shfl_xor(lm, 32));
            rm[mt] = lm;
            need = need || (lm > m_run[mt] + 8.0f);
        }
        if (__any(need)) {           // defer-max: rescale only on real max growth
#pragma unroll
            for (int mt = 0; mt < 2; ++mt) {
                float nm = fmaxf(m_run[mt], rm[mt]);
                float alpha = __builtin_amdgcn_exp2f(m_run[mt] - nm);
                m_run[mt] = nm;
                l_run[mt] *= alpha;
                float af[4];
#pragma unroll
                for (int r = 0; r < 4; ++r) af[r] = __shfl(alpha, lg * 4 + r);
#pragma unroll
                for (int nt = 0; nt < 4; ++nt)
#pragma unroll
                    for (int r = 0; r < 4; ++r) O[mt][nt][r] *= af[r];
            }
        }
#pragma unroll
        for (int mt = 0; mt < 2; ++mt) {
            float rs = 0.f;
#pragma unroll
            for (int nt = 0; nt < 4; ++nt) {
                v4us pp;
#pragma unroll
                for (int r = 0; r < 4; ++r) {
                    float p = __builtin_amdgcn_exp2f(sc[mt][nt][r] - m_run[mt]);
                    rs += p;
                    pp[r] = cvt_bf(p);
                }
                *reinterpret_cast<v4us*>(&PL[w][mt * 16 + lr][nt * 16 + lg * 4]) = pp;
            }
            rs += __shfl_xor(rs, 16);
            rs += __shfl_xor(rs, 32);
            l_run[mt] += rs;
        }
        // PL[w] is wave-private: within-wave ds_write -> ds_read needs only lgkmcnt
        asm volatile("s_waitcnt lgkmcnt(0)" ::: "memory");
        __builtin_amdgcn_sched_barrier(0);

        // ---- PV ----
        __builtin_amdgcn_s_setprio(1);
#pragma unroll
        for (int ks = 0; ks < 2; ++ks) {
            v8bf pa[2];
#pragma unroll
            for (int mt = 0; mt < 2; ++mt)
                pa[mt] = *reinterpret_cast<const v8bf*>(&PL[w][mt * 16 + lr][ks * 32 + lg * 8]);
#pragma unroll
            for (int nt = 0; nt < 4; ++nt) {
                v8bf vf = *reinterpret_cast<const v8bf*>(VT + (nt * 2 + ks) * 512 + lane * 8);
#pragma unroll
                for (int mt = 0; mt < 2; ++mt)
                    O[mt][nt] = __builtin_amdgcn_mfma_f32_16x16x32_bf16(pa[mt], vf, O[mt][nt], 0, 0, 0);
            }
        }
        __builtin_amdgcn_s_setprio(0);

        asm volatile("s_waitcnt vmcnt(0)" ::: "memory");
        __builtin_amdgcn_s_barrier();
        __builtin_amdgcn_sched_barrier(0);
    }

    // epilogue: redistribute 1/l via shfl, normalize, split hi/lo bf16
#pragma unroll
    for (int mt = 0; mt < 2; ++mt) {
        float linv = 1.f / l_run[mt];          // valid for q = mt*16 + lr
#pragma unroll
        for (int r = 0; r < 4; ++r) {
            float inv = __shfl(linv, lg * 4 + r);   // for q = mt*16 + lg*4 + r
            int s = q0 + mt * 16 + lg * 4 + r;
            size_t base = (size_t)(b * S_LEN + s) * OUT_DIM + h * HD;
#pragma unroll
            for (int nt = 0; nt < 4; ++nt) {
                float val = O[mt][nt][r] * inv;
                unsigned short hi = f2bf(val);
                avhi[base + nt * 16 + lr] = hi;
                avlo[base + nt * 16 + lr] = f2bf(val - bf2f(hi));
            }
        }
    }
}

// ---------------- Kernel 3: output projection (split-bf16 MFMA, ring pipeline) ----------------
__global__ __launch_bounds__(512, 2)
void out_gemm_mfma(const unsigned short* __restrict__ Whi, const unsigned short* __restrict__ Wlo,
                   const unsigned short* __restrict__ Bhi, const unsigned short* __restrict__ Blo,
                   const float* __restrict__ bias, float* __restrict__ out)
{
    __shared__ __align__(16) unsigned short SA[3 * 8192];
    __shared__ __align__(16) unsigned short SB[3 * 16384];
    const v4f zero4 = {0.f, 0.f, 0.f, 0.f};
    v4f acc[4][4];
#pragma unroll
    for (int i = 0; i < 4; ++i)
#pragma unroll
        for (int j = 0; j < 4; ++j) acc[i][j] = zero4;

    const int bm0 = blockIdx.x * 256;
    const int an0 = blockIdx.y * 128;
    splitbf16_mainloop_r3<3>(Whi, Wlo, Bhi, Blo, an0, bm0, SA, SB, acc);

    const int t = threadIdx.x;
    const int lane = t & 63;
    const int w = t >> 6;
    const int wm = w >> 1, wn = w & 1;
    const int lr = lane & 15, lg = lane >> 4;
    const int nbase = an0 + wn * 64;
    const int mbase = bm0 + wm * 64;

#pragma unroll
    for (int nt = 0; nt < 4; ++nt) {
        const int n0 = nbase + nt * 16 + lg * 4;
        const float4 b4 = *reinterpret_cast<const float4*>(bias + n0);
#pragma unroll
        for (int mt = 0; mt < 4; ++mt) {
            const int m = mbase + mt * 16 + lr;
            float4 o = make_float4(acc[mt][nt][0] + b4.x, acc[mt][nt][1] + b4.y,
                                   acc[mt][nt][2] + b4.z, acc[mt][nt][3] + b4.w);
            *reinterpret_cast<float4*>(out + (size_t)m * OUT_DIM + n0) = o;
        }
    }
}

extern "C" void kernel_launch(void* const* d_in, const int* in_sizes, int n_in,
                              void* d_out, int out_size, void* d_ws, size_t ws_size,
                              hipStream_t stream)
{
    const float* x    = (const float*)d_in[0];
    const float* Wqkv = (const float*)d_in[1];
    const float* bqkv = (const float*)d_in[2];
    const float* Wo   = (const float*)d_in[3];
    const float* bo   = (const float*)d_in[4];
    float* out = (float*)d_out;

    unsigned short* p = (unsigned short*)d_ws;
    unsigned short* xhi = p;            p += BHSD;
    unsigned short* xlo = p;            p += BHSD;
    unsigned short* wqh = p;            p += 3 * OUT_DIM * C_DIM;
    unsigned short* wql = p;            p += 3 * OUT_DIM * C_DIM;
    unsigned short* woh = p;            p += OUT_DIM * OUT_DIM;
    unsigned short* wol = p;            p += OUT_DIM * OUT_DIM;
    unsigned short* qhi = p;            p += BHSD;
    unsigned short* qlo = p;            p += BHSD;
    unsigned short* khi = p;            p += BHSD;
    unsigned short* klo = p;            p += BHSD;
    unsigned short* vhi = p;            p += BHSD;
    unsigned short* avhi = xhi;         // x dead after qkv_gemm -> reuse
    unsigned short* avlo = xlo;

    cvt_hl_kernel<<<dim3((int)(BHSD / 4 / 256)), 256, 0, stream>>>(x, xhi, xlo, (int)(BHSD / 4));
    cvt_hl_kernel<<<dim3(3 * OUT_DIM * C_DIM / 4 / 256), 256, 0, stream>>>(Wqkv, wqh, wql, 3 * OUT_DIM * C_DIM / 4);
    cvt_hl_kernel<<<dim3(OUT_DIM * C_DIM / 4 / 256), 256, 0, stream>>>(Wo, woh, wol, OUT_DIM * C_DIM / 4);

    // Q,K features [0,2048): full 3-term split. V features [2048,3072): 2-term
    // (V only consumed as bf16; dropped hi*lo term ~ its own rounding error).
    qkv_gemm_mfma<3><<<dim3(32, 16), 512, 0, stream>>>(wqh, wql, xhi, xlo, bqkv,
                                                       qhi, qlo, khi, klo, vhi, 0);
    qkv_gemm_mfma<2><<<dim3(32, 8), 512, 0, stream>>>(wqh, wql, xhi, xlo, bqkv,
                                                      qhi, qlo, khi, klo, vhi, 2048);
    attn_kernel<<<dim3(1024), 256, 0, stream>>>(qhi, qlo, khi, klo, vhi, avhi, avlo);
    out_gemm_mfma<<<dim3(32, 8), 512, 0, stream>>>(woh, wol, avhi, avlo, bo, out);
}

// Round 9
// 403.501 us; speedup vs baseline: 5.6806x; 1.0010x over previous
//
#include <hip/hip_runtime.h>
#include <hip/hip_bf16.h>
#include <math.h>

#define S_LEN 2048
#define B_SZ 4
#define NH 16
#define HD 64
#define C_DIM 1024
#define OUT_DIM 1024

static constexpr size_t BHSD = (size_t)B_SZ * NH * S_LEN * HD; // 8,388,608
#define QSCALE 0.18033688011112042f   /* 0.125 * log2(e): scores in log2 domain */

typedef __attribute__((ext_vector_type(8))) short v8bf;
typedef __attribute__((ext_vector_type(4))) float v4f;
typedef __attribute__((ext_vector_type(4))) unsigned short v4us;

__device__ inline unsigned short f2bf(float x) {
    unsigned u = __float_as_uint(x);
    return (unsigned short)((u + 0x7fffu + ((u >> 16) & 1u)) >> 16);  // RNE
}
__device__ inline float bf2f(unsigned short h) {
    return __uint_as_float(((unsigned)h) << 16);
}
__device__ inline unsigned short cvt_bf(float x) {
    __hip_bfloat16 hb = __float2bfloat16(x);
    return reinterpret_cast<unsigned short&>(hb);
}

// ---------------- Kernel 0: f32 -> (hi,lo) bf16 split ----------------
__global__ __launch_bounds__(256)
void cvt_hl_kernel(const float* __restrict__ src, unsigned short* __restrict__ hi,
                   unsigned short* __restrict__ lo, int n4)
{
    int i = blockIdx.x * 256 + threadIdx.x;
    if (i >= n4) return;
    float4 v = reinterpret_cast<const float4*>(src)[i];
    float x[4] = {v.x, v.y, v.z, v.w};
    v4us h, l;
#pragma unroll
    for (int j = 0; j < 4; ++j) {
        unsigned short hh = f2bf(x[j]);
        h[j] = hh;
        l[j] = f2bf(x[j] - bf2f(hh));
    }
    reinterpret_cast<v4us*>(hi)[i] = h;
    reinterpret_cast<v4us*>(lo)[i] = l;
}

// ---------------- split-bf16 MFMA mainloop: ring-3 + 2-phase barrier schedule ----------------
// Tile 256m x 128n, BK=32, 8 waves, wave = 64m x 64n (wm=w>>1, wn=w&1), acc[4][4].
// TERMS=3: hh+lh+hl.  TERMS=2: hh+lh (B-lo never staged/read) — for V features.
// Ring-3 LDS, prefetch distance 2, counted vmcnt gate (never drains in-loop).
// Each K-step = 2 phases of {ds_reads || stage issues -> barrier -> lgkmcnt(0) ->
// setprio + MFMA cluster -> barrier}  (m201 template shape, 4 barriers / K-step).
template <int TERMS>
__device__ __forceinline__ void splitbf16_mainloop_r3(
    const unsigned short* __restrict__ Ahi, const unsigned short* __restrict__ Alo,
    const unsigned short* __restrict__ Bhi, const unsigned short* __restrict__ Blo,
    int an0, int bm0, unsigned short* SA, unsigned short* SB, v4f acc[4][4])
{
    constexpr int K = 1024;
    constexpr int NT = K / 32;           // 32 K-steps
    constexpr int NS = (TERMS == 3) ? 6 : 4;   // staged 1KB chunks per wave per K-step
    const int t = threadIdx.x;
    const int lane = t & 63;
    const int w = t >> 6;                // 0..7
    const int wm = w >> 1;               // 0..3
    const int wn = w & 1;                // 0..1
    const int lr = lane & 15, lg = lane >> 4;

    auto CHUNK = [&](int kt, int bf, int u) {
        const int k0 = kt * 32;
        const int c = w * NS + u;        // wave-uniform chunk id
        const unsigned short* src;
        unsigned short* dst;
        if (c < 16) {                    // A: 8 rt-subtiles x (hi,lo)
            int rt = c >> 1, par = c & 1;
            src = (par ? Alo : Ahi) + (size_t)(an0 + rt * 16 + lr) * K + k0 + lg * 8;
            dst = SA + bf * 8192 + par * 4096 + rt * 512;
        } else if (TERMS == 3) {         // B: 16 rt-subtiles x (hi,lo)
            int cb = c - 16, rt = cb >> 1, par = cb & 1;
            src = (par ? Blo : Bhi) + (size_t)(bm0 + rt * 16 + lr) * K + k0 + lg * 8;
            dst = SB + bf * 16384 + par * 8192 + rt * 512;
        } else {                         // B: 16 rt-subtiles, hi only
            int rt = c - 16;
            src = Bhi + (size_t)(bm0 + rt * 16 + lr) * K + k0 + lg * 8;
            dst = SB + bf * 16384 + rt * 512;
        }
        __builtin_amdgcn_global_load_lds(
            (const __attribute__((address_space(1))) unsigned int*)src,
            (__attribute__((address_space(3))) unsigned int*)dst, 16, 0, 0);
    };
    auto STAGE_ALL = [&](int kt, int bf) {
#pragma unroll
        for (int u = 0; u < NS; ++u) CHUNK(kt, bf, u);
    };

    STAGE_ALL(0, 0);
    STAGE_ALL(1, 1);

    for (int kt = 0; kt < NT; ++kt) {
        const int bf = kt % 3;
        // ring gate: stage(kt) landed (stage(kt+1)'s NS loads may stay in flight)
        if (kt + 1 < NT) {
            if (TERMS == 3) { asm volatile("s_waitcnt vmcnt(6)" ::: "memory"); }
            else            { asm volatile("s_waitcnt vmcnt(4)" ::: "memory"); }
        } else {
            asm volatile("s_waitcnt vmcnt(0)" ::: "memory");
        }
        __builtin_amdgcn_s_barrier();
        __builtin_amdgcn_sched_barrier(0);

        const unsigned short* sa = SA + bf * 8192;
        const unsigned short* sb = SB + bf * 16384;
        const bool pf = (kt + 2 < NT);
        const int bf2 = (kt + 2) % 3;

        v8bf ah[4], al[4], bh[4], bl[4];

        // ======== phase 1: A-frags + B0/B1 reads || stage issues ========
#pragma unroll
        for (int i = 0; i < 4; ++i) {
            ah[i] = *reinterpret_cast<const v8bf*>(sa + (wn * 4 + i) * 512 + lane * 8);
            al[i] = *reinterpret_cast<const v8bf*>(sa + 4096 + (wn * 4 + i) * 512 + lane * 8);
        }
#pragma unroll
        for (int q = 0; q < 2; ++q) {
            bh[q] = *reinterpret_cast<const v8bf*>(sb + (wm * 4 + q) * 512 + lane * 8);
            if (TERMS == 3)
                bl[q] = *reinterpret_cast<const v8bf*>(sb + 8192 + (wm * 4 + q) * 512 + lane * 8);
        }
        if (pf) {
            CHUNK(kt + 2, bf2, 0); CHUNK(kt + 2, bf2, 1);
            if (TERMS == 3) CHUNK(kt + 2, bf2, 2);
        }
        __builtin_amdgcn_s_barrier();
        asm volatile("s_waitcnt lgkmcnt(0)" ::: "memory");
        __builtin_amdgcn_sched_barrier(0);
        __builtin_amdgcn_s_setprio(1);
#pragma unroll
        for (int q = 0; q < 2; ++q) {
#pragma unroll
            for (int nt = 0; nt < 4; ++nt)
                acc[q][nt] = __builtin_amdgcn_mfma_f32_16x16x32_bf16(ah[nt], bh[q], acc[q][nt], 0, 0, 0);
#pragma unroll
            for (int nt = 0; nt < 4; ++nt)
                acc[q][nt] = __builtin_amdgcn_mfma_f32_16x16x32_bf16(al[nt], bh[q], acc[q][nt], 0, 0, 0);
            if (TERMS == 3) {
#pragma unroll
                for (int nt = 0; nt < 4; ++nt)
                    acc[q][nt] = __builtin_amdgcn_mfma_f32_16x16x32_bf16(ah[nt], bl[q], acc[q][nt], 0, 0, 0);
            }
        }
        __builtin_amdgcn_s_setprio(0);
        __builtin_amdgcn_s_barrier();
        __builtin_amdgcn_sched_barrier(0);

        // ======== phase 2: B2/B3 reads || stage issues ========
#pragma unroll
        for (int q = 2; q < 4; ++q) {
            bh[q] = *reinterpret_cast<const v8bf*>(sb + (wm * 4 + q) * 512 + lane * 8);
            if (TERMS == 3)
                bl[q] = *reinterpret_cast<const v8bf*>(sb + 8192 + (wm * 4 + q) * 512 + lane * 8);
        }
        if (pf) {
            if (TERMS == 3) { CHUNK(kt + 2, bf2, 3); CHUNK(kt + 2, bf2, 4); CHUNK(kt + 2, bf2, 5); }
            else            { CHUNK(kt + 2, bf2, 2); CHUNK(kt + 2, bf2, 3); }
        }
        __builtin_amdgcn_s_barrier();
        asm volatile("s_waitcnt lgkmcnt(0)" ::: "memory");
        __builtin_amdgcn_sched_barrier(0);
        __builtin_amdgcn_s_setprio(1);
#pragma unroll
        for (int q = 2; q < 4; ++q) {
#pragma unroll
            for (int nt = 0; nt < 4; ++nt)
                acc[q][nt] = __builtin_amdgcn_mfma_f32_16x16x32_bf16(ah[nt], bh[q], acc[q][nt], 0, 0, 0);
#pragma unroll
            for (int nt = 0; nt < 4; ++nt)
                acc[q][nt] = __builtin_amdgcn_mfma_f32_16x16x32_bf16(al[nt], bh[q], acc[q][nt], 0, 0, 0);
            if (TERMS == 3) {
#pragma unroll
                for (int nt = 0; nt < 4; ++nt)
                    acc[q][nt] = __builtin_amdgcn_mfma_f32_16x16x32_bf16(ah[nt], bl[q], acc[q][nt], 0, 0, 0);
            }
        }
        __builtin_amdgcn_s_setprio(0);
        // no trailing barrier: next iteration opens with vmcnt gate + barrier
    }
}

// ---------------- Kernel 1: QKV projection (split-bf16 MFMA, ring pipeline) ----------------
template <int TERMS>
__global__ __launch_bounds__(512, 2)
void qkv_gemm_mfma(const unsigned short* __restrict__ Whi, const unsigned short* __restrict__ Wlo,
                   const unsigned short* __restrict__ Xhi, const unsigned short* __restrict__ Xlo,
                   const float* __restrict__ bias,
                   unsigned short* __restrict__ qhi, unsigned short* __restrict__ qlo,
                   unsigned short* __restrict__ khi, unsigned short* __restrict__ klo,
                   unsigned short* __restrict__ vhi, int an_base)
{
    __shared__ __align__(16) unsigned short SA[3 * 8192];    // 48 KB
    __shared__ __align__(16) unsigned short SB[3 * 16384];   // 96 KB
    const v4f zero4 = {0.f, 0.f, 0.f, 0.f};
    v4f acc[4][4];
#pragma unroll
    for (int i = 0; i < 4; ++i)
#pragma unroll
        for (int j = 0; j < 4; ++j) acc[i][j] = zero4;

    const int bm0 = blockIdx.x * 256;
    const int an0 = an_base + blockIdx.y * 128;
    splitbf16_mainloop_r3<TERMS>(Whi, Wlo, Xhi, Xlo, an0, bm0, SA, SB, acc);

    const int t = threadIdx.x;
    const int lane = t & 63;
    const int w = t >> 6;
    const int wm = w >> 1, wn = w & 1;
    const int lr = lane & 15, lg = lane >> 4;
    const int nbase = an0 + wn * 64;
    const int mbase = bm0 + wm * 64;

#pragma unroll
    for (int nt = 0; nt < 4; ++nt) {
        const int n0 = nbase + nt * 16 + lg * 4;
        const float4 b4 = *reinterpret_cast<const float4*>(bias + n0);
        const float bv[4] = {b4.x, b4.y, b4.z, b4.w};
        const int tsel = n0 >> 10;
        const int np = n0 & 1023;
        const int hh = np >> 6;
        const int dd = np & 63;
#pragma unroll
        for (int mt = 0; mt < 4; ++mt) {
            const int m = mbase + mt * 16 + lr;
            const int s = m >> 2, b = m & 3;
            float vals[4];
#pragma unroll
            for (int r = 0; r < 4; ++r) vals[r] = acc[mt][nt][r] + bv[r];
            if (tsel == 0) {
                v4us h, l;
#pragma unroll
                for (int r = 0; r < 4; ++r) {
                    float x = vals[r] * QSCALE;
                    unsigned short hi = f2bf(x);
                    h[r] = hi; l[r] = f2bf(x - bf2f(hi));
                }
                size_t base = ((size_t)(b * NH + hh) * S_LEN + s) * HD + dd;
                *reinterpret_cast<v4us*>(qhi + base) = h;
                *reinterpret_cast<v4us*>(qlo + base) = l;
            } else if (tsel == 1) {
                v4us h, l;
#pragma unroll
                for (int r = 0; r < 4; ++r) {
                    unsigned short hi = f2bf(vals[r]);
                    h[r] = hi; l[r] = f2bf(vals[r] - bf2f(hi));
                }
                size_t base = ((size_t)(b * NH + hh) * S_LEN + s) * HD + dd;
                *reinterpret_cast<v4us*>(khi + base) = h;
                *reinterpret_cast<v4us*>(klo + base) = l;
            } else {
#pragma unroll
                for (int r = 0; r < 4; ++r)
                    vhi[((size_t)(b * NH + hh) * HD + dd + r) * S_LEN + s] = f2bf(vals[r]);
            }
        }
    }
}

// ---------------- Kernel 2: flash attention — swapped QK^T, XOR-swizzled P ----------------
__global__ __launch_bounds__(256, 2)
void attn_kernel(const unsigned short* __restrict__ qhi, const unsigned short* __restrict__ qlo,
                 const unsigned short* __restrict__ khi, const unsigned short* __restrict__ klo,
                 const unsigned short* __restrict__ vhi,
                 unsigned short* __restrict__ avhi, unsigned short* __restrict__ avlo)
{
    __shared__ __align__(16) unsigned short SM[2][12288];  // KH@0 KL@4096 VT@8192
    // P per wave: [32 rows q][64 kv] u16, stride 128B; bank-conflict-free via
    // byte ^= (row&7)<<4 on BOTH write (8B) and read (16B) (G4/T2 recipe).
    __shared__ __align__(16) unsigned short PL[4][32 * 64];

    const int t = threadIdx.x;
    const int lane = t & 63;
    const int w = t >> 6;
    const int lr = lane & 15;
    const int lg = lane >> 4;
    const int id = blockIdx.x;
    const int bh = id & 63;           // same-bh blocks share XCD (64 % 8 == 0)
    const int qt = id >> 6;
    const int b = bh >> 4, h = bh & 15;
    const size_t bh_sd = (size_t)bh * (S_LEN * HD);
    const int q0 = qt * 128 + w * 32;
    char* const plw = (char*)&PL[w][0];
    const unsigned swz = (unsigned)((lr & 7) << 4);

    v8bf qh[2][2], ql[2][2];
#pragma unroll
    for (int mt = 0; mt < 2; ++mt)
#pragma unroll
        for (int ks = 0; ks < 2; ++ks) {
            size_t off = bh_sd + (size_t)(q0 + mt * 16 + lr) * HD + ks * 32 + lg * 8;
            qh[mt][ks] = *reinterpret_cast<const v8bf*>(qhi + off);
            ql[mt][ks] = *reinterpret_cast<const v8bf*>(qlo + off);
        }

    auto STAGE = [&](int kt, int bf) {
#pragma unroll
        for (int u = 0; u < 6; ++u) {
            int cid = w * 6 + u;
            int pl_ = cid >> 3;
            int n = cid & 7;
            int nt = n >> 1, kn = n & 1;
            const unsigned short* src;
            if (pl_ == 0)
                src = khi + bh_sd + (size_t)(kt * 64 + nt * 16 + lr) * HD + kn * 32 + lg * 8;
            else if (pl_ == 1)
                src = klo + bh_sd + (size_t)(kt * 64 + nt * 16 + lr) * HD + kn * 32 + lg * 8;
            else
                src = vhi + bh_sd + (size_t)(nt * 16 + lr) * S_LEN + kt * 64 + kn * 32 + lg * 8;
            unsigned short* dst = &SM[bf][pl_ * 4096 + n * 512];
            __builtin_amdgcn_global_load_lds(
                (const __attribute__((address_space(1))) unsigned int*)src,
                (__attribute__((address_space(3))) unsigned int*)dst, 16, 0, 0);
        }
    };

    const v4f zero4 = {0.f, 0.f, 0.f, 0.f};
    v4f O[2][4];                     // O[mt][ntd]: row q=mt*16+lg*4+r, col d=ntd*16+lr
    float m_run[2], l_run[2];        // per-lane state for q = mt*16 + lr
#pragma unroll
    for (int mt = 0; mt < 2; ++mt) { m_run[mt] = -1e30f; l_run[mt] = 0.f; }
#pragma unroll
    for (int mt = 0; mt < 2; ++mt)
#pragma unroll
        for (int nt = 0; nt < 4; ++nt) O[mt][nt] = zero4;

    constexpr int NT = S_LEN / 64;

    STAGE(0, 0);
    asm volatile("s_waitcnt vmcnt(0)" ::: "memory");
    __builtin_amdgcn_s_barrier();
    __builtin_amdgcn_sched_barrier(0);

    for (int kt = 0; kt < NT; ++kt) {
        const int cur = kt & 1;
        if (kt + 1 < NT) STAGE(kt + 1, cur ^ 1);

        const unsigned short* KH = &SM[cur][0];
        const unsigned short* KL = &SM[cur][4096];
        const unsigned short* VT = &SM[cur][8192];

        // ---- swapped QK^T: sc[mt][nt][r] = S[kv=nt*16+lg*4+r][q=mt*16+lr] ----
        v4f sc[2][4];
#pragma unroll
        for (int mt = 0; mt < 2; ++mt)
#pragma unroll
            for (int nt = 0; nt < 4; ++nt) sc[mt][nt] = zero4;
        __builtin_amdgcn_s_setprio(1);
#pragma unroll
        for (int ks = 0; ks < 2; ++ks)
#pragma unroll
            for (int nt = 0; nt < 4; ++nt) {
                v8bf kh = *reinterpret_cast<const v8bf*>(KH + (nt * 2 + ks) * 512 + lane * 8);
                v8bf kl = *reinterpret_cast<const v8bf*>(KL + (nt * 2 + ks) * 512 + lane * 8);
#pragma unroll
                for (int mt = 0; mt < 2; ++mt) {
                    sc[mt][nt] = __builtin_amdgcn_mfma_f32_16x16x32_bf16(kh, qh[mt][ks], sc[mt][nt], 0, 0, 0);
                    sc[mt][nt] = __builtin_amdgcn_mfma_f32_16x16x32_bf16(kh, ql[mt][ks], sc[mt][nt], 0, 0, 0);
                    sc[mt][nt] = __builtin_amdgcn_mfma_f32_16x16x32_bf16(kl, qh[mt][ks], sc[mt][nt], 0, 0, 0);
                }
            }
        __builtin_amdgcn_s_setprio(0);

        // ---- softmax: all 64 kv for q=lr live in lanes {lr, lr+16, lr+32, lr+48} ----
        float rm[2];
        bool need = false;
#pragma unroll
        for (int mt = 0; mt < 2; ++mt) {
            float lm = -1e30f;
#pragma unroll
            for (int nt = 0; nt < 4; ++nt)
#pragma unroll
                for (int r = 0; r < 4; ++r) lm = fmaxf(lm, sc[mt][nt][r]);
            lm = fmaxf(lm, __shfl_xor(lm, 16));
            lm = fmaxf(lm, __shfl_xor(lm, 32));
            rm[mt] = lm;
            need = need || (lm > m_run[mt] + 8.0f);
        }
        if (__any(need)) {           // defer-max: rescale only on real max growth
#pragma unroll
            for (int mt = 0; mt < 2; ++mt) {
                float nm = fmaxf(m_run[mt], rm[mt]);
                float alpha = __builtin_amdgcn_exp2f(m_run[mt] - nm);
                m_run[mt] = nm;
                l_run[mt] *= alpha;
                float af[4];
#pragma unroll
                for (int r = 0; r < 4; ++r) af[r] = __shfl(alpha, lg * 4 + r);
#pragma unroll
                for (int nt = 0; nt < 4; ++nt)
#pragma unroll
                    for (int r = 0; r < 4; ++r) O[mt][nt][r] *= af[r];
            }
        }
#pragma unroll
        for (int mt = 0; mt < 2; ++mt) {
            float rs = 0.f;
#pragma unroll
            for (int nt = 0; nt < 4; ++nt) {
                v4us pp;
#pragma unroll
                for (int r = 0; r < 4; ++r) {
                    float p = __builtin_amdgcn_exp2f(sc[mt][nt][r] - m_run[mt]);
                    rs += p;
                    pp[r] = cvt_bf(p);
                }
                unsigned wb = (unsigned)((mt * 16 + lr) * 128 + (nt * 16 + lg * 4) * 2) ^ swz;
                *reinterpret_cast<v4us*>(plw + wb) = pp;
            }
            rs += __shfl_xor(rs, 16);
            rs += __shfl_xor(rs, 32);
            l_run[mt] += rs;
        }
        // PL[w] is wave-private: within-wave ds_write -> ds_read needs only lgkmcnt
        asm volatile("s_waitcnt lgkmcnt(0)" ::: "memory");
        __builtin_amdgcn_sched_barrier(0);

        // ---- PV ----
        __builtin_amdgcn_s_setprio(1);
#pragma unroll
        for (int ks = 0; ks < 2; ++ks) {
            v8bf pa[2];
#pragma unroll
            for (int mt = 0; mt < 2; ++mt) {
                unsigned rb = (unsigned)((mt * 16 + lr) * 128 + (ks * 32 + lg * 8) * 2) ^ swz;
                pa[mt] = *reinterpret_cast<const v8bf*>(plw + rb);
            }
#pragma unroll
            for (int nt = 0; nt < 4; ++nt) {
                v8bf vf = *reinterpret_cast<const v8bf*>(VT + (nt * 2 + ks) * 512 + lane * 8);
#pragma unroll
                for (int mt = 0; mt < 2; ++mt)
                    O[mt][nt] = __builtin_amdgcn_mfma_f32_16x16x32_bf16(pa[mt], vf, O[mt][nt], 0, 0, 0);
            }
        }
        __builtin_amdgcn_s_setprio(0);

        asm volatile("s_waitcnt vmcnt(0)" ::: "memory");
        __builtin_amdgcn_s_barrier();
        __builtin_amdgcn_sched_barrier(0);
    }

    // epilogue: redistribute 1/l via shfl, normalize, split hi/lo bf16
#pragma unroll
    for (int mt = 0; mt < 2; ++mt) {
        float linv = 1.f / l_run[mt];          // valid for q = mt*16 + lr
#pragma unroll
        for (int r = 0; r < 4; ++r) {
            float inv = __shfl(linv, lg * 4 + r);   // for q = mt*16 + lg*4 + r
            int s = q0 + mt * 16 + lg * 4 + r;
            size_t base = (size_t)(b * S_LEN + s) * OUT_DIM + h * HD;
#pragma unroll
            for (int nt = 0; nt < 4; ++nt) {
                float val = O[mt][nt][r] * inv;
                unsigned short hi = f2bf(val);
                avhi[base + nt * 16 + lr] = hi;
                avlo[base + nt * 16 + lr] = f2bf(val - bf2f(hi));
            }
        }
    }
}

// ---------------- Kernel 3: output projection (split-bf16 MFMA, ring pipeline) ----------------
__global__ __launch_bounds__(512, 2)
void out_gemm_mfma(const unsigned short* __restrict__ Whi, const unsigned short* __restrict__ Wlo,
                   const unsigned short* __restrict__ Bhi, const unsigned short* __restrict__ Blo,
                   const float* __restrict__ bias, float* __restrict__ out)
{
    __shared__ __align__(16) unsigned short SA[3 * 8192];
    __shared__ __align__(16) unsigned short SB[3 * 16384];
    const v4f zero4 = {0.f, 0.f, 0.f, 0.f};
    v4f acc[4][4];
#pragma unroll
    for (int i = 0; i < 4; ++i)
#pragma unroll
        for (int j = 0; j < 4; ++j) acc[i][j] = zero4;

    const int bm0 = blockIdx.x * 256;
    const int an0 = blockIdx.y * 128;
    splitbf16_mainloop_r3<3>(Whi, Wlo, Bhi, Blo, an0, bm0, SA, SB, acc);

    const int t = threadIdx.x;
    const int lane = t & 63;
    const int w = t >> 6;
    const int wm = w >> 1, wn = w & 1;
    const int lr = lane & 15, lg = lane >> 4;
    const int nbase = an0 + wn * 64;
    const int mbase = bm0 + wm * 64;

#pragma unroll
    for (int nt = 0; nt < 4; ++nt) {
        const int n0 = nbase + nt * 16 + lg * 4;
        const float4 b4 = *reinterpret_cast<const float4*>(bias + n0);
#pragma unroll
        for (int mt = 0; mt < 4; ++mt) {
            const int m = mbase + mt * 16 + lr;
            float4 o = make_float4(acc[mt][nt][0] + b4.x, acc[mt][nt][1] + b4.y,
                                   acc[mt][nt][2] + b4.z, acc[mt][nt][3] + b4.w);
            *reinterpret_cast<float4*>(out + (size_t)m * OUT_DIM + n0) = o;
        }
    }
}

extern "C" void kernel_launch(void* const* d_in, const int* in_sizes, int n_in,
                              void* d_out, int out_size, void* d_ws, size_t ws_size,
                              hipStream_t stream)
{
    const float* x    = (const float*)d_in[0];
    const float* Wqkv = (const float*)d_in[1];
    const float* bqkv = (const float*)d_in[2];
    const float* Wo   = (const float*)d_in[3];
    const float* bo   = (const float*)d_in[4];
    float* out = (float*)d_out;

    unsigned short* p = (unsigned short*)d_ws;
    unsigned short* xhi = p;            p += BHSD;
    unsigned short* xlo = p;            p += BHSD;
    unsigned short* wqh = p;            p += 3 * OUT_DIM * C_DIM;
    unsigned short* wql = p;            p += 3 * OUT_DIM * C_DIM;
    unsigned short* woh = p;            p += OUT_DIM * OUT_DIM;
    unsigned short* wol = p;            p += OUT_DIM * OUT_DIM;
    unsigned short* qhi = p;            p += BHSD;
    unsigned short* qlo = p;            p += BHSD;
    unsigned short* khi = p;            p += BHSD;
    unsigned short* klo = p;            p += BHSD;
    unsigned short* vhi = p;            p += BHSD;
    unsigned short* avhi = xhi;         // x dead after qkv_gemm -> reuse
    unsigned short* avlo = xlo;

    cvt_hl_kernel<<<dim3((int)(BHSD / 4 / 256)), 256, 0, stream>>>(x, xhi, xlo, (int)(BHSD / 4));
    cvt_hl_kernel<<<dim3(3 * OUT_DIM * C_DIM / 4 / 256), 256, 0, stream>>>(Wqkv, wqh, wql, 3 * OUT_DIM * C_DIM / 4);
    cvt_hl_kernel<<<dim3(OUT_DIM * C_DIM / 4 / 256), 256, 0, stream>>>(Wo, woh, wol, OUT_DIM * C_DIM / 4);

    // Q,K features [0,2048): full 3-term split. V features [2048,3072): 2-term.
    qkv_gemm_mfma<3><<<dim3(32, 16), 512, 0, stream>>>(wqh, wql, xhi, xlo, bqkv,
                                                       qhi, qlo, khi, klo, vhi, 0);
    qkv_gemm_mfma<2><<<dim3(32, 8), 512, 0, stream>>>(wqh, wql, xhi, xlo, bqkv,
                                                      qhi, qlo, khi, klo, vhi, 2048);
    attn_kernel<<<dim3(1024), 256, 0, stream>>>(qhi, qlo, khi, klo, vhi, avhi, avlo);
    out_gemm_mfma<<<dim3(32, 8), 512, 0, stream>>>(woh, wol, avhi, avlo, bo, out);
}

// Round 10
// 273.699 us; speedup vs baseline: 8.3747x; 1.4743x over previous
//
#include <hip/hip_runtime.h>
#include <hip/hip_bf16.h>
#include <math.h>

#define S_LEN 2048
#define B_SZ 4
#define NH 16
#define HD 64
#define C_DIM 1024
#define OUT_DIM 1024

static constexpr size_t BHSD = (size_t)B_SZ * NH * S_LEN * HD; // 8,388,608
#define QSCALE 0.18033688011112042f   /* 0.125 * log2(e): scores in log2 domain */

typedef __attribute__((ext_vector_type(8))) short v8bf;
typedef __attribute__((ext_vector_type(4))) float v4f;
typedef __attribute__((ext_vector_type(4))) unsigned short v4us;

__device__ inline unsigned short f2bf(float x) {
    unsigned u = __float_as_uint(x);
    return (unsigned short)((u + 0x7fffu + ((u >> 16) & 1u)) >> 16);  // RNE
}
__device__ inline float bf2f(unsigned short h) {
    return __uint_as_float(((unsigned)h) << 16);
}
__device__ inline unsigned short cvt_bf(float x) {
    __hip_bfloat16 hb = __float2bfloat16(x);
    return reinterpret_cast<unsigned short&>(hb);
}

// ---------------- Kernel 0a: f32 -> (hi,lo) bf16 split (weights) ----------------
__global__ __launch_bounds__(256)
void cvt_hl_kernel(const float* __restrict__ src, unsigned short* __restrict__ hi,
                   unsigned short* __restrict__ lo, int n4)
{
    int i = blockIdx.x * 256 + threadIdx.x;
    if (i >= n4) return;
    float4 v = reinterpret_cast<const float4*>(src)[i];
    float x[4] = {v.x, v.y, v.z, v.w};
    v4us h, l;
#pragma unroll
    for (int j = 0; j < 4; ++j) {
        unsigned short hh = f2bf(x[j]);
        h[j] = hh;
        l[j] = f2bf(x[j] - bf2f(hh));
    }
    reinterpret_cast<v4us*>(hi)[i] = h;
    reinterpret_cast<v4us*>(lo)[i] = l;
}

// ---------------- Kernel 0b: f32 -> bf16 (activations; lo-part not needed) ----------------
__global__ __launch_bounds__(256)
void cvt_hi_kernel(const float* __restrict__ src, unsigned short* __restrict__ hi, int n4)
{
    int i = blockIdx.x * 256 + threadIdx.x;
    if (i >= n4) return;
    float4 v = reinterpret_cast<const float4*>(src)[i];
    float x[4] = {v.x, v.y, v.z, v.w};
    v4us h;
#pragma unroll
    for (int j = 0; j < 4; ++j) h[j] = f2bf(x[j]);
    reinterpret_cast<v4us*>(hi)[i] = h;
}

// ---------------- 2-term split-bf16 MFMA mainloop: ring-3, counted vmcnt, 2-phase ----------------
// C = A^T-ish: A = weights (hi+lo, 128 n-rows), B = activations (hi only, 256 m-rows).
// 2-term: ah*bh + al*bh  (== W_f32-ish x act_bf16; act-lo dropped — error ~ output rounding).
// BK=32, 8 waves, wave = 64m x 64n, acc[4][4]. Ring-3 LDS, prefetch distance 2,
// counted vmcnt(4) gate (loads never drain in-loop). 2 phases per K-step (m201 shape).
__device__ __forceinline__ void split2_mainloop_r3(
    const unsigned short* __restrict__ Ahi, const unsigned short* __restrict__ Alo,
    const unsigned short* __restrict__ Bhi,
    int an0, int bm0, unsigned short* SA, unsigned short* SB, v4f acc[4][4])
{
    constexpr int K = 1024;
    constexpr int NT = K / 32;
    const int t = threadIdx.x;
    const int lane = t & 63;
    const int w = t >> 6;
    const int wm = w >> 1;
    const int wn = w & 1;
    const int lr = lane & 15, lg = lane >> 4;

    auto CHUNK = [&](int kt, int bf, int u) {
        const int k0 = kt * 32;
        const int c = w * 4 + u;         // 0..31 wave-uniform chunk id
        const unsigned short* src;
        unsigned short* dst;
        if (c < 16) {                    // A: 8 rt-subtiles x (hi,lo)
            int rt = c >> 1, par = c & 1;
            src = (par ? Alo : Ahi) + (size_t)(an0 + rt * 16 + lr) * K + k0 + lg * 8;
            dst = SA + bf * 8192 + par * 4096 + rt * 512;
        } else {                         // B: 16 rt-subtiles, hi only
            int rt = c - 16;
            src = Bhi + (size_t)(bm0 + rt * 16 + lr) * K + k0 + lg * 8;
            dst = SB + bf * 8192 + rt * 512;
        }
        __builtin_amdgcn_global_load_lds(
            (const __attribute__((address_space(1))) unsigned int*)src,
            (__attribute__((address_space(3))) unsigned int*)dst, 16, 0, 0);
    };
    auto STAGE_ALL = [&](int kt, int bf) {
#pragma unroll
        for (int u = 0; u < 4; ++u) CHUNK(kt, bf, u);
    };

    STAGE_ALL(0, 0);
    STAGE_ALL(1, 1);

    for (int kt = 0; kt < NT; ++kt) {
        const int bf = kt % 3;
        if (kt + 1 < NT) { asm volatile("s_waitcnt vmcnt(4)" ::: "memory"); }
        else             { asm volatile("s_waitcnt vmcnt(0)" ::: "memory"); }
        __builtin_amdgcn_s_barrier();
        __builtin_amdgcn_sched_barrier(0);

        const unsigned short* sa = SA + bf * 8192;
        const unsigned short* sb = SB + bf * 8192;
        const bool pf = (kt + 2 < NT);
        const int bf2 = (kt + 2) % 3;

        v8bf ah[4], al[4], bh[4];

        // ======== phase 1: A-frags + B0/B1 reads || stage issues ========
#pragma unroll
        for (int i = 0; i < 4; ++i) {
            ah[i] = *reinterpret_cast<const v8bf*>(sa + (wn * 4 + i) * 512 + lane * 8);
            al[i] = *reinterpret_cast<const v8bf*>(sa + 4096 + (wn * 4 + i) * 512 + lane * 8);
        }
#pragma unroll
        for (int q = 0; q < 2; ++q)
            bh[q] = *reinterpret_cast<const v8bf*>(sb + (wm * 4 + q) * 512 + lane * 8);
        if (pf) { CHUNK(kt + 2, bf2, 0); CHUNK(kt + 2, bf2, 1); }
        __builtin_amdgcn_s_barrier();
        asm volatile("s_waitcnt lgkmcnt(0)" ::: "memory");
        __builtin_amdgcn_sched_barrier(0);
        __builtin_amdgcn_s_setprio(1);
#pragma unroll
        for (int q = 0; q < 2; ++q) {
#pragma unroll
            for (int nt = 0; nt < 4; ++nt)
                acc[q][nt] = __builtin_amdgcn_mfma_f32_16x16x32_bf16(ah[nt], bh[q], acc[q][nt], 0, 0, 0);
#pragma unroll
            for (int nt = 0; nt < 4; ++nt)
                acc[q][nt] = __builtin_amdgcn_mfma_f32_16x16x32_bf16(al[nt], bh[q], acc[q][nt], 0, 0, 0);
        }
        __builtin_amdgcn_s_setprio(0);
        __builtin_amdgcn_s_barrier();
        __builtin_amdgcn_sched_barrier(0);

        // ======== phase 2: B2/B3 reads || stage issues ========
#pragma unroll
        for (int q = 2; q < 4; ++q)
            bh[q] = *reinterpret_cast<const v8bf*>(sb + (wm * 4 + q) * 512 + lane * 8);
        if (pf) { CHUNK(kt + 2, bf2, 2); CHUNK(kt + 2, bf2, 3); }
        __builtin_amdgcn_s_barrier();
        asm volatile("s_waitcnt lgkmcnt(0)" ::: "memory");
        __builtin_amdgcn_sched_barrier(0);
        __builtin_amdgcn_s_setprio(1);
#pragma unroll
        for (int q = 2; q < 4; ++q) {
#pragma unroll
            for (int nt = 0; nt < 4; ++nt)
                acc[q][nt] = __builtin_amdgcn_mfma_f32_16x16x32_bf16(ah[nt], bh[q], acc[q][nt], 0, 0, 0);
#pragma unroll
            for (int nt = 0; nt < 4; ++nt)
                acc[q][nt] = __builtin_amdgcn_mfma_f32_16x16x32_bf16(al[nt], bh[q], acc[q][nt], 0, 0, 0);
        }
        __builtin_amdgcn_s_setprio(0);
    }
}

// ---------------- Kernel 1: QKV projection ----------------
// Outputs all plain bf16: Q (x QSCALE) -> qb[b][h][s][d]; K -> kb; V -> vb[b][h][d][s].
__global__ __launch_bounds__(512, 2)
void qkv_gemm_mfma(const unsigned short* __restrict__ Whi, const unsigned short* __restrict__ Wlo,
                   const unsigned short* __restrict__ Xhi, const float* __restrict__ bias,
                   unsigned short* __restrict__ qb, unsigned short* __restrict__ kb,
                   unsigned short* __restrict__ vb)
{
    __shared__ __align__(16) unsigned short SA[3 * 8192];    // 48 KB
    __shared__ __align__(16) unsigned short SB[3 * 8192];    // 48 KB
    const v4f zero4 = {0.f, 0.f, 0.f, 0.f};
    v4f acc[4][4];
#pragma unroll
    for (int i = 0; i < 4; ++i)
#pragma unroll
        for (int j = 0; j < 4; ++j) acc[i][j] = zero4;

    const int bm0 = blockIdx.x * 256;
    const int an0 = blockIdx.y * 128;
    split2_mainloop_r3(Whi, Wlo, Xhi, an0, bm0, SA, SB, acc);

    const int t = threadIdx.x;
    const int lane = t & 63;
    const int w = t >> 6;
    const int wm = w >> 1, wn = w & 1;
    const int lr = lane & 15, lg = lane >> 4;
    const int nbase = an0 + wn * 64;
    const int mbase = bm0 + wm * 64;

#pragma unroll
    for (int nt = 0; nt < 4; ++nt) {
        const int n0 = nbase + nt * 16 + lg * 4;
        const float4 b4 = *reinterpret_cast<const float4*>(bias + n0);
        const float bv[4] = {b4.x, b4.y, b4.z, b4.w};
        const int tsel = n0 >> 10;
        const int np = n0 & 1023;
        const int hh = np >> 6;
        const int dd = np & 63;
#pragma unroll
        for (int mt = 0; mt < 4; ++mt) {
            const int m = mbase + mt * 16 + lr;
            const int s = m >> 2, b = m & 3;
            float vals[4];
#pragma unroll
            for (int r = 0; r < 4; ++r) vals[r] = acc[mt][nt][r] + bv[r];
            if (tsel == 0) {
                v4us h;
#pragma unroll
                for (int r = 0; r < 4; ++r) h[r] = f2bf(vals[r] * QSCALE);
                *reinterpret_cast<v4us*>(qb + ((size_t)(b * NH + hh) * S_LEN + s) * HD + dd) = h;
            } else if (tsel == 1) {
                v4us h;
#pragma unroll
                for (int r = 0; r < 4; ++r) h[r] = f2bf(vals[r]);
                *reinterpret_cast<v4us*>(kb + ((size_t)(b * NH + hh) * S_LEN + s) * HD + dd) = h;
            } else {
#pragma unroll
                for (int r = 0; r < 4; ++r)
                    vb[((size_t)(b * NH + hh) * HD + dd + r) * S_LEN + s] = f2bf(vals[r]);
            }
        }
    }
}

// ---------------- Kernel 2: flash attention — bf16 QK^T (1-term), swapped operands ----------------
// LDS 48 KB -> 3 blocks/CU (12 waves/CU) for this latency-bound kernel.
__global__ __launch_bounds__(256, 3)
void attn_kernel(const unsigned short* __restrict__ qb, const unsigned short* __restrict__ kb,
                 const unsigned short* __restrict__ vb, unsigned short* __restrict__ avh)
{
    __shared__ __align__(16) unsigned short SM[2][8192];   // KB@0 (8x512), VT@4096 (8x512)
    __shared__ __align__(16) unsigned short PL[4][32 * 64];  // per-wave P, XOR-swizzled

    const int t = threadIdx.x;
    const int lane = t & 63;
    const int w = t >> 6;
    const int lr = lane & 15;
    const int lg = lane >> 4;
    const int id = blockIdx.x;
    const int bh = id & 63;           // same-bh blocks share XCD (64 % 8 == 0)
    const int qt = id >> 6;
    const int b = bh >> 4, h = bh & 15;
    const size_t bh_sd = (size_t)bh * (S_LEN * HD);
    const int q0 = qt * 128 + w * 32;
    char* const plw = (char*)&PL[w][0];
    const unsigned swz = (unsigned)((lr & 7) << 4);

    v8bf qh[2][2];
#pragma unroll
    for (int mt = 0; mt < 2; ++mt)
#pragma unroll
        for (int ks = 0; ks < 2; ++ks)
            qh[mt][ks] = *reinterpret_cast<const v8bf*>(
                qb + bh_sd + (size_t)(q0 + mt * 16 + lr) * HD + ks * 32 + lg * 8);

    auto STAGE = [&](int kt, int bf) {
#pragma unroll
        for (int u = 0; u < 4; ++u) {
            int cid = w * 4 + u;          // 0..15
            const unsigned short* src;
            unsigned short* dst;
            if (cid < 8) {                // K tile: subtile cid = (nt,kn)
                int nt = cid >> 1, kn = cid & 1;
                src = kb + bh_sd + (size_t)(kt * 64 + nt * 16 + lr) * HD + kn * 32 + lg * 8;
                dst = &SM[bf][cid * 512];
            } else {                      // V^T tile
                int n = cid - 8;
                int nt = n >> 1, kn = n & 1;
                src = vb + bh_sd + (size_t)(nt * 16 + lr) * S_LEN + kt * 64 + kn * 32 + lg * 8;
                dst = &SM[bf][4096 + n * 512];
            }
            __builtin_amdgcn_global_load_lds(
                (const __attribute__((address_space(1))) unsigned int*)src,
                (__attribute__((address_space(3))) unsigned int*)dst, 16, 0, 0);
        }
    };

    const v4f zero4 = {0.f, 0.f, 0.f, 0.f};
    v4f O[2][4];                     // O[mt][ntd]: row q=mt*16+lg*4+r, col d=ntd*16+lr
    float m_run[2], l_run[2];        // per-lane state for q = mt*16 + lr
#pragma unroll
    for (int mt = 0; mt < 2; ++mt) { m_run[mt] = -1e30f; l_run[mt] = 0.f; }
#pragma unroll
    for (int mt = 0; mt < 2; ++mt)
#pragma unroll
        for (int nt = 0; nt < 4; ++nt) O[mt][nt] = zero4;

    constexpr int NT = S_LEN / 64;

    STAGE(0, 0);
    asm volatile("s_waitcnt vmcnt(0)" ::: "memory");
    __builtin_amdgcn_s_barrier();
    __builtin_amdgcn_sched_barrier(0);

    for (int kt = 0; kt < NT; ++kt) {
        const int cur = kt & 1;
        if (kt + 1 < NT) STAGE(kt + 1, cur ^ 1);

        const unsigned short* KB = &SM[cur][0];
        const unsigned short* VT = &SM[cur][4096];

        // ---- swapped QK^T (1 term): sc[mt][nt][r] = S[kv=nt*16+lg*4+r][q=mt*16+lr] ----
        v4f sc[2][4];
#pragma unroll
        for (int mt = 0; mt < 2; ++mt)
#pragma unroll
            for (int nt = 0; nt < 4; ++nt) sc[mt][nt] = zero4;
        __builtin_amdgcn_s_setprio(1);
#pragma unroll
        for (int ks = 0; ks < 2; ++ks)
#pragma unroll
            for (int nt = 0; nt < 4; ++nt) {
                v8bf kh = *reinterpret_cast<const v8bf*>(KB + (nt * 2 + ks) * 512 + lane * 8);
#pragma unroll
                for (int mt = 0; mt < 2; ++mt)
                    sc[mt][nt] = __builtin_amdgcn_mfma_f32_16x16x32_bf16(kh, qh[mt][ks], sc[mt][nt], 0, 0, 0);
            }
        __builtin_amdgcn_s_setprio(0);

        // ---- softmax: 64 kv for q=lr live in lanes {lr, lr+16, lr+32, lr+48} ----
        float rm[2];
        bool need = false;
#pragma unroll
        for (int mt = 0; mt < 2; ++mt) {
            float lm = -1e30f;
#pragma unroll
            for (int nt = 0; nt < 4; ++nt)
#pragma unroll
                for (int r = 0; r < 4; ++r) lm = fmaxf(lm, sc[mt][nt][r]);
            lm = fmaxf(lm, __shfl_xor(lm, 16));
            lm = fmaxf(lm, __shfl_xor(lm, 32));
            rm[mt] = lm;
            need = need || (lm > m_run[mt] + 8.0f);
        }
        if (__any(need)) {           // defer-max (T13)
#pragma unroll
            for (int mt = 0; mt < 2; ++mt) {
                float nm = fmaxf(m_run[mt], rm[mt]);
                float alpha = __builtin_amdgcn_exp2f(m_run[mt] - nm);
                m_run[mt] = nm;
                l_run[mt] *= alpha;
                float af[4];
#pragma unroll
                for (int r = 0; r < 4; ++r) af[r] = __shfl(alpha, lg * 4 + r);
#pragma unroll
                for (int nt = 0; nt < 4; ++nt)
#pragma unroll
                    for (int r = 0; r < 4; ++r) O[mt][nt][r] *= af[r];
            }
        }
#pragma unroll
        for (int mt = 0; mt < 2; ++mt) {
            float rs = 0.f;
#pragma unroll
            for (int nt = 0; nt < 4; ++nt) {
                v4us pp;
#pragma unroll
                for (int r = 0; r < 4; ++r) {
                    float p = __builtin_amdgcn_exp2f(sc[mt][nt][r] - m_run[mt]);
                    rs += p;
                    pp[r] = cvt_bf(p);
                }
                unsigned wb = (unsigned)((mt * 16 + lr) * 128 + (nt * 16 + lg * 4) * 2) ^ swz;
                *reinterpret_cast<v4us*>(plw + wb) = pp;
            }
            rs += __shfl_xor(rs, 16);
            rs += __shfl_xor(rs, 32);
            l_run[mt] += rs;
        }
        asm volatile("s_waitcnt lgkmcnt(0)" ::: "memory");
        __builtin_amdgcn_sched_barrier(0);

        // ---- PV ----
        __builtin_amdgcn_s_setprio(1);
#pragma unroll
        for (int ks = 0; ks < 2; ++ks) {
            v8bf pa[2];
#pragma unroll
            for (int mt = 0; mt < 2; ++mt) {
                unsigned rb = (unsigned)((mt * 16 + lr) * 128 + (ks * 32 + lg * 8) * 2) ^ swz;
                pa[mt] = *reinterpret_cast<const v8bf*>(plw + rb);
            }
#pragma unroll
            for (int nt = 0; nt < 4; ++nt) {
                v8bf vf = *reinterpret_cast<const v8bf*>(VT + (nt * 2 + ks) * 512 + lane * 8);
#pragma unroll
                for (int mt = 0; mt < 2; ++mt)
                    O[mt][nt] = __builtin_amdgcn_mfma_f32_16x16x32_bf16(pa[mt], vf, O[mt][nt], 0, 0, 0);
            }
        }
        __builtin_amdgcn_s_setprio(0);

        asm volatile("s_waitcnt vmcnt(0)" ::: "memory");
        __builtin_amdgcn_s_barrier();
        __builtin_amdgcn_sched_barrier(0);
    }

    // epilogue: redistribute 1/l via shfl, normalize, store av bf16
#pragma unroll
    for (int mt = 0; mt < 2; ++mt) {
        float linv = 1.f / l_run[mt];
#pragma unroll
        for (int r = 0; r < 4; ++r) {
            float inv = __shfl(linv, lg * 4 + r);
            int s = q0 + mt * 16 + lg * 4 + r;
            size_t base = (size_t)(b * S_LEN + s) * OUT_DIM + h * HD;
#pragma unroll
            for (int nt = 0; nt < 4; ++nt)
                avh[base + nt * 16 + lr] = cvt_bf(O[mt][nt][r] * inv);
        }
    }
}

// ---------------- Kernel 3: output projection (2-term, ring pipeline) ----------------
__global__ __launch_bounds__(512, 2)
void out_gemm_mfma(const unsigned short* __restrict__ Whi, const unsigned short* __restrict__ Wlo,
                   const unsigned short* __restrict__ Bhi, const float* __restrict__ bias,
                   float* __restrict__ out)
{
    __shared__ __align__(16) unsigned short SA[3 * 8192];
    __shared__ __align__(16) unsigned short SB[3 * 8192];
    const v4f zero4 = {0.f, 0.f, 0.f, 0.f};
    v4f acc[4][4];
#pragma unroll
    for (int i = 0; i < 4; ++i)
#pragma unroll
        for (int j = 0; j < 4; ++j) acc[i][j] = zero4;

    const int bm0 = blockIdx.x * 256;
    const int an0 = blockIdx.y * 128;
    split2_mainloop_r3(Whi, Wlo, Bhi, an0, bm0, SA, SB, acc);

    const int t = threadIdx.x;
    const int lane = t & 63;
    const int w = t >> 6;
    const int wm = w >> 1, wn = w & 1;
    const int lr = lane & 15, lg = lane >> 4;
    const int nbase = an0 + wn * 64;
    const int mbase = bm0 + wm * 64;

#pragma unroll
    for (int nt = 0; nt < 4; ++nt) {
        const int n0 = nbase + nt * 16 + lg * 4;
        const float4 b4 = *reinterpret_cast<const float4*>(bias + n0);
#pragma unroll
        for (int mt = 0; mt < 4; ++mt) {
            const int m = mbase + mt * 16 + lr;
            float4 o = make_float4(acc[mt][nt][0] + b4.x, acc[mt][nt][1] + b4.y,
                                   acc[mt][nt][2] + b4.z, acc[mt][nt][3] + b4.w);
            *reinterpret_cast<float4*>(out + (size_t)m * OUT_DIM + n0) = o;
        }
    }
}

extern "C" void kernel_launch(void* const* d_in, const int* in_sizes, int n_in,
                              void* d_out, int out_size, void* d_ws, size_t ws_size,
                              hipStream_t stream)
{
    const float* x    = (const float*)d_in[0];
    const float* Wqkv = (const float*)d_in[1];
    const float* bqkv = (const float*)d_in[2];
    const float* Wo   = (const float*)d_in[3];
    const float* bo   = (const float*)d_in[4];
    float* out = (float*)d_out;

    unsigned short* p = (unsigned short*)d_ws;
    unsigned short* xhi = p;            p += BHSD;                 // 8192x1024 bf16
    unsigned short* wqh = p;            p += 3 * OUT_DIM * C_DIM;
    unsigned short* wql = p;            p += 3 * OUT_DIM * C_DIM;
    unsigned short* woh = p;            p += OUT_DIM * OUT_DIM;
    unsigned short* wol = p;            p += OUT_DIM * OUT_DIM;
    unsigned short* qb = p;             p += BHSD;
    unsigned short* kb = p;             p += BHSD;
    unsigned short* vb = p;             p += BHSD;
    unsigned short* avh = xhi;          // x dead after qkv_gemm -> reuse
    // total ~83 MB

    cvt_hi_kernel<<<dim3((int)(BHSD / 4 / 256)), 256, 0, stream>>>(x, xhi, (int)(BHSD / 4));
    cvt_hl_kernel<<<dim3(3 * OUT_DIM * C_DIM / 4 / 256), 256, 0, stream>>>(Wqkv, wqh, wql, 3 * OUT_DIM * C_DIM / 4);
    cvt_hl_kernel<<<dim3(OUT_DIM * C_DIM / 4 / 256), 256, 0, stream>>>(Wo, woh, wol, OUT_DIM * C_DIM / 4);

    qkv_gemm_mfma<<<dim3(32, 24), 512, 0, stream>>>(wqh, wql, xhi, bqkv, qb, kb, vb);
    attn_kernel<<<dim3(1024), 256, 0, stream>>>(qb, kb, vb, avh);
    out_gemm_mfma<<<dim3(32, 8), 512, 0, stream>>>(woh, wol, avh, bo, out);
}